// Round 1
// baseline (1734.100 us; speedup 1.0000x reference)
//
#include <hip/hip_runtime.h>
#include <stdint.h>
#include <stddef.h>

#define BN   8
#define HN   128
#define WN   128
#define HP   130
#define CLOW 128
#define CMID 256
#define KO   49

typedef __attribute__((ext_vector_type(4))) float f32x4;
typedef __attribute__((ext_vector_type(8))) short bf16x8;

typedef __attribute__((address_space(1))) const uint8_t ga_u8;
typedef __attribute__((address_space(3))) uint8_t lds_u8;

__device__ __forceinline__ short f2bf(float f) {
    uint32_t u = __float_as_uint(f);
    u += 0x7fffu + ((u >> 16) & 1u);
    return (short)(u >> 16);
}
__device__ __forceinline__ float bf2f(short s) {
    return __uint_as_float(((uint32_t)(uint16_t)s) << 16);
}
__device__ __forceinline__ void gload16(const void* g, void* l) {
    __builtin_amdgcn_global_load_lds((ga_u8*)g, (lds_u8*)l, 16, 0, 0);
}

// ---------------------------------------------------------------------------
// Convert NCHW fp32 -> zero-padded NHWC bf16 ([b][130][130][128], border from
// memset). One block per (b,y) row; LDS transpose so both global read (along x)
// and global write (along c) are coalesced.
// ---------------------------------------------------------------------------
__global__ __launch_bounds__(256) void convert_pad_kernel(
    const float* __restrict__ src0, const float* __restrict__ src1,
    short* __restrict__ dst0, short* __restrict__ dst1) {
    __shared__ short t[128 * 132];
    const int tid = threadIdx.x;
    const int by = blockIdx.x;
    const int b = by >> 7, y = by & 127;
    const float* src = blockIdx.y ? src1 : src0;
    short* dst = blockIdx.y ? dst1 : dst0;
    for (int k = 0; k < 64; ++k) {
        int i = (k << 8) + tid;
        int c = i >> 7, x = i & 127;
        t[x * 132 + c] = f2bf(src[(((size_t)b * CLOW + c) * HN + y) * WN + x]);
    }
    __syncthreads();
    short* drow = dst + (((size_t)b * HP + (y + 1)) * HP + 1) * CLOW;
    for (int k = 0; k < 64; ++k) {
        int i = (k << 8) + tid;
        int x = i >> 7, c = i & 127;
        drow[x * CLOW + c] = t[x * 132 + c];
    }
}

// ---------------------------------------------------------------------------
// Pack conv weights OIHW fp32 -> [cout][tap*CIN+cin] bf16 (tap-major K).
// ---------------------------------------------------------------------------
template <int CIN>
__global__ __launch_bounds__(256) void pack_w_kernel(
    const float* __restrict__ w, short* __restrict__ wp) {
    constexpr int K = 9 * CIN;
    int i = blockIdx.x * 256 + threadIdx.x;
    if (i >= 256 * K) return;
    int cout = i / K;
    int kk = i - cout * K;
    int tap = kk / CIN;            // compile-time shift (CIN pow2)
    int cin = kk & (CIN - 1);
    wp[i] = f2bf(w[((size_t)cout * CIN + cin) * 9 + tap]);
}

// ---------------------------------------------------------------------------
// Implicit-GEMM 3x3 conv, bf16 MFMA. M=128 pixels (one image row), N=128 couts,
// K-step 32. 4 waves in 2x2; each wave 64x64 via 4x4 16x16x32 fragments.
// global_load_lds staging (linear dest) with source chunk-XOR swizzle so the
// ds_read_b128 fragment reads are 2-way (free).
// ---------------------------------------------------------------------------
template <int CINT, bool DUAL, bool OPAD>
__global__ __launch_bounds__(256) void conv_gemm_kernel(
    const short* __restrict__ in0, const short* __restrict__ in1,
    const short* __restrict__ wp, const float* __restrict__ bias,
    short* __restrict__ out) {
    constexpr int K = 9 * CINT;
    constexpr int NK = K / 32;
    constexpr int PST = DUAL ? 256 : CINT;   // per-source pixel channel stride
    __shared__ short Xs[128 * 32];
    __shared__ short Ws[128 * 32];
    const int tid = threadIdx.x;
    int bx = blockIdx.x;
    bx = (bx & 7) * 128 + (bx >> 3);         // XCD-aware swizzle (1024 % 8 == 0)
    const int b = bx >> 7, y = bx & 127;
    const int cout0 = blockIdx.y * 128;
    const int lane = tid & 63, wv = tid >> 6;
    const int wm = wv >> 1, wn = wv & 1;
    const int lr = lane & 15, lk = lane >> 4;

    f32x4 zero = {0.f, 0.f, 0.f, 0.f};
    f32x4 acc[4][4];
    #pragma unroll
    for (int i = 0; i < 4; ++i)
        #pragma unroll
        for (int j = 0; j < 4; ++j) acc[i][j] = zero;

    // staging slots: s in [0,512): row = s>>2 (pixel or cout), chunk = s&3.
    const int s0 = tid, s1 = tid + 256;
    const int xr0 = s0 >> 2, xr1 = s1 >> 2;
    const int xo0 = ((s0 & 3) ^ ((xr0 >> 1) & 3)) << 3;  // swizzled src elem off
    const int xo1 = ((s1 & 3) ^ ((xr1 >> 1) & 3)) << 3;
    const short* wrow0 = wp + (size_t)(cout0 + xr0) * K + xo0;
    const short* wrow1 = wp + (size_t)(cout0 + xr1) * K + xo1;

    for (int kk = 0; kk < NK; ++kk) {
        const int kg = kk * 32;
        const int tap = kg / CINT;           // compile-time shift
        const int cin0 = kg & (CINT - 1);
        const int ky = (tap * 11) >> 5;      // tap/3 for tap<9
        const int kx = tap - ky * 3;
        const short* xb;
        int ch0;
        if (DUAL) {
            if (cin0 < 256) { xb = in0; ch0 = cin0; }
            else            { xb = in1; ch0 = cin0 - 256; }
        } else { xb = in0; ch0 = cin0; }
        const short* xrow = xb + ((size_t)(b * HP + (y + ky)) * HP + kx) * PST + ch0;

        __syncthreads();
        gload16(xrow + xr0 * PST + xo0, &Xs[s0 * 8]);
        gload16(xrow + xr1 * PST + xo1, &Xs[s1 * 8]);
        gload16(wrow0 + kg, &Ws[s0 * 8]);
        gload16(wrow1 + kg, &Ws[s1 * 8]);
        __syncthreads();

        bf16x8 af[4], bg[4];
        #pragma unroll
        for (int mf = 0; mf < 4; ++mf) {
            int pix = wm * 64 + mf * 16 + lr;
            af[mf] = *(const bf16x8*)&Xs[pix * 32 + ((lk ^ ((pix >> 1) & 3)) << 3)];
        }
        #pragma unroll
        for (int nf = 0; nf < 4; ++nf) {
            int co = wn * 64 + nf * 16 + lr;
            bg[nf] = *(const bf16x8*)&Ws[co * 32 + ((lk ^ ((co >> 1) & 3)) << 3)];
        }
        #pragma unroll
        for (int mf = 0; mf < 4; ++mf)
            #pragma unroll
            for (int nf = 0; nf < 4; ++nf)
                acc[mf][nf] = __builtin_amdgcn_mfma_f32_16x16x32_bf16(
                    af[mf], bg[nf], acc[mf][nf], 0, 0, 0);
    }

    // epilogue: D row=(lane>>4)*4+r -> pixel, col=lane&15 -> cout (m89 layout)
    const int prow = lk * 4;
    #pragma unroll
    for (int nf = 0; nf < 4; ++nf) {
        const int co = cout0 + wn * 64 + nf * 16 + lr;
        const float bv = bias[co];
        #pragma unroll
        for (int mf = 0; mf < 4; ++mf) {
            #pragma unroll
            for (int r = 0; r < 4; ++r) {
                const int pix = wm * 64 + mf * 16 + prow + r;
                float v = fmaxf(acc[mf][nf][r] + bv, 0.f);
                size_t o;
                if (OPAD) o = ((size_t)(b * HP + (y + 1)) * HP + (pix + 1)) * CMID + co;
                else      o = ((size_t)(b * HN + y) * WN + pix) * CMID + co;
                out[o] = f2bf(v);
            }
        }
    }
}

// ---------------------------------------------------------------------------
// 1x1 conv (256 -> 49) + ReLU + softmax over the 49 logits.
// One thread per pixel; x2 is NHWC bf16 so channel reads vectorize; w3 reads
// are wave-uniform (scalarize to s_load). Output attn is [b][49][h*w] fp32.
// ---------------------------------------------------------------------------
__global__ __launch_bounds__(256) void conv3_softmax_kernel(
    const short* __restrict__ x2, const float* __restrict__ w3,
    const float* __restrict__ b3, float* __restrict__ attn) {
    const int p = blockIdx.x * 256 + threadIdx.x;   // 131072 pixels
    const int b = p >> 14, hw = p & 16383;
    float acc[KO];
    #pragma unroll
    for (int o = 0; o < KO; ++o) acc[o] = b3[o];
    const short* xp = x2 + (size_t)p * 256;
    #pragma unroll 1
    for (int c0 = 0; c0 < 256; c0 += 8) {
        bf16x8 xv = *(const bf16x8*)&xp[c0];
        float xf[8];
        #pragma unroll
        for (int j = 0; j < 8; ++j) xf[j] = bf2f(xv[j]);
        #pragma unroll
        for (int o = 0; o < KO; ++o) {
            const float* wr = w3 + o * 256 + c0;
            float s = acc[o];
            #pragma unroll
            for (int j = 0; j < 8; ++j) s = fmaf(xf[j], wr[j], s);
            acc[o] = s;
        }
    }
    #pragma unroll
    for (int o = 0; o < KO; ++o) acc[o] = fmaxf(acc[o], 0.f);
    float m = acc[0];
    #pragma unroll
    for (int o = 1; o < KO; ++o) m = fmaxf(m, acc[o]);
    float s = 0.f;
    #pragma unroll
    for (int o = 0; o < KO; ++o) { float e = __expf(acc[o] - m); acc[o] = e; s += e; }
    const float inv = 1.f / s;
    float* ap = attn + (size_t)b * KO * 16384 + hw;
    #pragma unroll
    for (int o = 0; o < KO; ++o) ap[(size_t)o * 16384] = acc[o] * inv;
}

// ---------------------------------------------------------------------------
// Spatially-variant 7x7 conv. Block = (b, y, 64-pixel x segment) over all 256
// channels in 16 chunks of 16. attn tile [49][64] staged once; key_high chunk
// [16][7][70] staged per chunk (row pad 73 -> 2-way banks). Thread = (ci, pg):
// channel ci of chunk, 4 consecutive pixels; per-dy 10-wide register window.
// ---------------------------------------------------------------------------
__global__ __launch_bounds__(256) void svc_kernel(
    const float* __restrict__ kh, const float* __restrict__ attn,
    float* __restrict__ out) {
    __shared__ float a_s[KO * 64];
    __shared__ float kh_s[16 * 7 * 73];
    const int tid = threadIdx.x;
    int by = blockIdx.y;
    by = (by & 7) * 128 + (by >> 3);       // XCD-aware swizzle
    const int b = by >> 7, y = by & 127;
    const int x0 = blockIdx.x * 64;

    for (int i = tid; i < KO * 64; i += 256) {
        int o = i >> 6, px = i & 63;
        a_s[i] = attn[((size_t)b * KO + o) * 16384 + y * WN + x0 + px];
    }
    const int ci = tid >> 4, pg = tid & 15;
    const int pxb = pg * 4;
    for (int ch = 0; ch < 16; ++ch) {
        const int cbase = ch * 16;
        __syncthreads();                   // prev chunk readers done (+attn stage)
        for (int i = tid; i < 16 * 7 * 70; i += 256) {
            int lci = i / 490;
            int r = i - lci * 490;
            int dy = r / 70;
            int cc = r - dy * 70;
            int yy = y + dy - 3;
            int xx = x0 + cc - 3;
            float v = 0.f;
            if ((unsigned)yy < 128u && (unsigned)xx < 128u)
                v = kh[(((size_t)b * 256 + cbase + lci) * HN + yy) * WN + xx];
            kh_s[(lci * 7 + dy) * 73 + cc] = v;
        }
        __syncthreads();
        const int c = cbase + ci;
        float a0 = 0.f, a1 = 0.f, a2 = 0.f, a3 = 0.f;
        #pragma unroll
        for (int dy = 0; dy < 7; ++dy) {
            float kro[10];
            #pragma unroll
            for (int w = 0; w < 10; ++w) kro[w] = kh_s[(ci * 7 + dy) * 73 + pxb + w];
            #pragma unroll
            for (int dx = 0; dx < 7; ++dx) {
                f32x4 av = *(const f32x4*)&a_s[(dy * 7 + dx) * 64 + pxb];
                a0 = fmaf(kro[dx + 0], av[0], a0);
                a1 = fmaf(kro[dx + 1], av[1], a1);
                a2 = fmaf(kro[dx + 2], av[2], a2);
                a3 = fmaf(kro[dx + 3], av[3], a3);
            }
        }
        f32x4 res = {a0, a1, a2, a3};
        *(f32x4*)&out[(((size_t)b * 256 + c) * HN + y) * WN + x0 + pxb] = res;
    }
}

// ---------------------------------------------------------------------------
extern "C" void kernel_launch(void* const* d_in, const int* in_sizes, int n_in,
                              void* d_out, int out_size, void* d_ws, size_t ws_size,
                              hipStream_t stream) {
    (void)in_sizes; (void)n_in; (void)out_size; (void)ws_size;
    const float* cur_low  = (const float*)d_in[0];
    const float* key_low  = (const float*)d_in[1];
    const float* key_high = (const float*)d_in[2];
    const float* w_red    = (const float*)d_in[3];
    const float* b_red    = (const float*)d_in[4];
    const float* w2       = (const float*)d_in[5];
    const float* b2       = (const float*)d_in[6];
    const float* w3       = (const float*)d_in[7];
    const float* b3       = (const float*)d_in[8];
    float* out = (float*)d_out;
    char* ws = (char*)d_ws;

    const size_t SZ_YPAD = (size_t)BN * HP * HP * CMID * 2;  // 69,222,400
    const size_t SZ_XPAD = (size_t)BN * HP * HP * CLOW * 2;  // 34,611,200
    const size_t SZ_ATTN = (size_t)BN * KO * HN * WN * 4;    // 25,690,112
    short* ypadc = (short*)(ws);
    short* ypadk = (short*)(ws + SZ_YPAD);
    short* xpadc = (short*)(ws + 2 * SZ_YPAD);
    short* xpadk = (short*)(ws + 2 * SZ_YPAD + SZ_XPAD);
    // x2 (conv2 output, NHWC bf16, 64 MiB) reuses the xpad region: xpads are
    // dead once both conv1 launches complete (stream-ordered).
    short* x2    = (short*)(ws + 2 * SZ_YPAD);
    float* attn  = (float*)(ws + 2 * SZ_YPAD + 2 * SZ_XPAD);
    short* w1p   = (short*)(ws + 2 * SZ_YPAD + 2 * SZ_XPAD + SZ_ATTN);
    short* w2p   = (short*)((char*)w1p + (size_t)256 * 1152 * 2);

    // zero pad borders (interiors are fully rewritten each call)
    hipMemsetAsync(ws, 0, 2 * SZ_YPAD + 2 * SZ_XPAD, stream);

    convert_pad_kernel<<<dim3(1024, 2), 256, 0, stream>>>(cur_low, key_low, xpadc, xpadk);
    pack_w_kernel<128><<<(256 * 1152) / 256, 256, 0, stream>>>(w_red, w1p);
    pack_w_kernel<512><<<(256 * 4608) / 256, 256, 0, stream>>>(w2, w2p);

    conv_gemm_kernel<128, false, true><<<dim3(1024, 2), 256, 0, stream>>>(
        xpadc, nullptr, w1p, b_red, ypadc);
    conv_gemm_kernel<128, false, true><<<dim3(1024, 2), 256, 0, stream>>>(
        xpadk, nullptr, w1p, b_red, ypadk);
    conv_gemm_kernel<512, true, false><<<dim3(1024, 2), 256, 0, stream>>>(
        ypadc, ypadk, w2p, b2, x2);

    conv3_softmax_kernel<<<512, 256, 0, stream>>>(x2, w3, b3, attn);
    svc_kernel<<<dim3(2, 1024), 256, 0, stream>>>(key_high, attn, out);
}

// Round 2
// 1360.578 us; speedup vs baseline: 1.2745x; 1.2745x over previous
//
#include <hip/hip_runtime.h>
#include <stdint.h>
#include <stddef.h>

#define BN   8
#define HN   128
#define WN   128
#define HP   130
#define CLOW 128
#define CMID 256
#define KO   49

// padded key_high: [b][c][134][140] fp32, khp[b][c][y+3][x+4] = kh[b][c][y][x]
#define KHP_H 134
#define KHP_W 140
#define KHP_PLANE (KHP_H * KHP_W)   // 18760 floats

typedef __attribute__((ext_vector_type(4))) float f32x4;
typedef __attribute__((ext_vector_type(8))) short bf16x8;

typedef __attribute__((address_space(1))) const uint8_t ga_u8;
typedef __attribute__((address_space(3))) uint8_t lds_u8;

__device__ __forceinline__ short f2bf(float f) {
    uint32_t u = __float_as_uint(f);
    u += 0x7fffu + ((u >> 16) & 1u);
    return (short)(u >> 16);
}
__device__ __forceinline__ float bf2f(short s) {
    return __uint_as_float(((uint32_t)(uint16_t)s) << 16);
}
__device__ __forceinline__ void gload16(const void* g, void* l) {
    __builtin_amdgcn_global_load_lds((ga_u8*)g, (lds_u8*)l, 16, 0, 0);
}

// ---------------------------------------------------------------------------
// Zero only the halo cells of a padded [b][130][130][C] bf16 buffer.
// Thread = (border cell, 8-short group); 16B stores, idempotent every call.
// ---------------------------------------------------------------------------
template <int C>
__global__ __launch_bounds__(256) void zero_border_kernel(short* __restrict__ buf) {
    constexpr int GP = C / 8;
    int t = blockIdx.x * 256 + threadIdx.x;
    int cell = t / GP, g = t - cell * GP;
    if (cell >= 8 * 516) return;
    int b = cell / 516, r = cell - b * 516;
    int y, x;
    if (r < 260) { y = (r >= 130) ? 129 : 0; x = (r >= 130) ? (r - 130) : r; }
    else { int j = r - 260; y = 1 + (j >> 1); x = (j & 1) ? 129 : 0; }
    uint4 z = {0u, 0u, 0u, 0u};
    *(uint4*)&buf[(((size_t)b * HP + y) * HP + x) * C + g * 8] = z;
}

// ---------------------------------------------------------------------------
// Convert NCHW fp32 -> zero-padded NHWC bf16 ([b][130][130][128]).
// ---------------------------------------------------------------------------
__global__ __launch_bounds__(256) void convert_pad_kernel(
    const float* __restrict__ src0, const float* __restrict__ src1,
    short* __restrict__ dst0, short* __restrict__ dst1) {
    __shared__ short t[128 * 132];
    const int tid = threadIdx.x;
    const int by = blockIdx.x;
    const int b = by >> 7, y = by & 127;
    const float* src = blockIdx.y ? src1 : src0;
    short* dst = blockIdx.y ? dst1 : dst0;
    for (int k = 0; k < 64; ++k) {
        int i = (k << 8) + tid;
        int c = i >> 7, x = i & 127;
        t[x * 132 + c] = f2bf(src[(((size_t)b * CLOW + c) * HN + y) * WN + x]);
    }
    __syncthreads();
    short* drow = dst + (((size_t)b * HP + (y + 1)) * HP + 1) * CLOW;
    for (int k = 0; k < 64; ++k) {
        int i = (k << 8) + tid;
        int x = i >> 7, c = i & 127;
        drow[x * CLOW + c] = t[x * 132 + c];
    }
}

// ---------------------------------------------------------------------------
// Pack conv weights OIHW fp32 -> [cout][tap*CIN+cin] bf16 (tap-major K).
// ---------------------------------------------------------------------------
template <int CIN>
__global__ __launch_bounds__(256) void pack_w_kernel(
    const float* __restrict__ w, short* __restrict__ wp) {
    constexpr int K = 9 * CIN;
    int i = blockIdx.x * 256 + threadIdx.x;
    if (i >= 256 * K) return;
    int cout = i / K;
    int kk = i - cout * K;
    int tap = kk / CIN;
    int cin = kk & (CIN - 1);
    wp[i] = f2bf(w[((size_t)cout * CIN + cin) * 9 + tap]);
}

// ---------------------------------------------------------------------------
// Implicit-GEMM 3x3 conv, bf16 MFMA (unchanged from round 1).
// ---------------------------------------------------------------------------
template <int CINT, bool DUAL, bool OPAD>
__global__ __launch_bounds__(256) void conv_gemm_kernel(
    const short* __restrict__ in0, const short* __restrict__ in1,
    const short* __restrict__ wp, const float* __restrict__ bias,
    short* __restrict__ out) {
    constexpr int K = 9 * CINT;
    constexpr int NK = K / 32;
    constexpr int PST = DUAL ? 256 : CINT;
    __shared__ short Xs[128 * 32];
    __shared__ short Ws[128 * 32];
    const int tid = threadIdx.x;
    int bx = blockIdx.x;
    bx = (bx & 7) * 128 + (bx >> 3);
    const int b = bx >> 7, y = bx & 127;
    const int cout0 = blockIdx.y * 128;
    const int lane = tid & 63, wv = tid >> 6;
    const int wm = wv >> 1, wn = wv & 1;
    const int lr = lane & 15, lk = lane >> 4;

    f32x4 zero = {0.f, 0.f, 0.f, 0.f};
    f32x4 acc[4][4];
    #pragma unroll
    for (int i = 0; i < 4; ++i)
        #pragma unroll
        for (int j = 0; j < 4; ++j) acc[i][j] = zero;

    const int s0 = tid, s1 = tid + 256;
    const int xr0 = s0 >> 2, xr1 = s1 >> 2;
    const int xo0 = ((s0 & 3) ^ ((xr0 >> 1) & 3)) << 3;
    const int xo1 = ((s1 & 3) ^ ((xr1 >> 1) & 3)) << 3;
    const short* wrow0 = wp + (size_t)(cout0 + xr0) * K + xo0;
    const short* wrow1 = wp + (size_t)(cout0 + xr1) * K + xo1;

    for (int kk = 0; kk < NK; ++kk) {
        const int kg = kk * 32;
        const int tap = kg / CINT;
        const int cin0 = kg & (CINT - 1);
        const int ky = (tap * 11) >> 5;
        const int kx = tap - ky * 3;
        const short* xb;
        int ch0;
        if (DUAL) {
            if (cin0 < 256) { xb = in0; ch0 = cin0; }
            else            { xb = in1; ch0 = cin0 - 256; }
        } else { xb = in0; ch0 = cin0; }
        const short* xrow = xb + ((size_t)(b * HP + (y + ky)) * HP + kx) * PST + ch0;

        __syncthreads();
        gload16(xrow + xr0 * PST + xo0, &Xs[s0 * 8]);
        gload16(xrow + xr1 * PST + xo1, &Xs[s1 * 8]);
        gload16(wrow0 + kg, &Ws[s0 * 8]);
        gload16(wrow1 + kg, &Ws[s1 * 8]);
        __syncthreads();

        bf16x8 af[4], bg[4];
        #pragma unroll
        for (int mf = 0; mf < 4; ++mf) {
            int pix = wm * 64 + mf * 16 + lr;
            af[mf] = *(const bf16x8*)&Xs[pix * 32 + ((lk ^ ((pix >> 1) & 3)) << 3)];
        }
        #pragma unroll
        for (int nf = 0; nf < 4; ++nf) {
            int co = wn * 64 + nf * 16 + lr;
            bg[nf] = *(const bf16x8*)&Ws[co * 32 + ((lk ^ ((co >> 1) & 3)) << 3)];
        }
        #pragma unroll
        for (int mf = 0; mf < 4; ++mf)
            #pragma unroll
            for (int nf = 0; nf < 4; ++nf)
                acc[mf][nf] = __builtin_amdgcn_mfma_f32_16x16x32_bf16(
                    af[mf], bg[nf], acc[mf][nf], 0, 0, 0);
    }

    const int prow = lk * 4;
    #pragma unroll
    for (int nf = 0; nf < 4; ++nf) {
        const int co = cout0 + wn * 64 + nf * 16 + lr;
        const float bv = bias[co];
        #pragma unroll
        for (int mf = 0; mf < 4; ++mf) {
            #pragma unroll
            for (int r = 0; r < 4; ++r) {
                const int pix = wm * 64 + mf * 16 + prow + r;
                float v = fmaxf(acc[mf][nf][r] + bv, 0.f);
                size_t o;
                if (OPAD) o = ((size_t)(b * HP + (y + 1)) * HP + (pix + 1)) * CMID + co;
                else      o = ((size_t)(b * HN + y) * WN + pix) * CMID + co;
                out[o] = f2bf(v);
            }
        }
    }
}

// ---------------------------------------------------------------------------
// 1x1 conv (256 -> 49) + ReLU + softmax (unchanged).
// ---------------------------------------------------------------------------
__global__ __launch_bounds__(256) void conv3_softmax_kernel(
    const short* __restrict__ x2, const float* __restrict__ w3,
    const float* __restrict__ b3, float* __restrict__ attn) {
    const int p = blockIdx.x * 256 + threadIdx.x;
    const int b = p >> 14, hw = p & 16383;
    float acc[KO];
    #pragma unroll
    for (int o = 0; o < KO; ++o) acc[o] = b3[o];
    const short* xp = x2 + (size_t)p * 256;
    #pragma unroll 1
    for (int c0 = 0; c0 < 256; c0 += 8) {
        bf16x8 xv = *(const bf16x8*)&xp[c0];
        float xf[8];
        #pragma unroll
        for (int j = 0; j < 8; ++j) xf[j] = bf2f(xv[j]);
        #pragma unroll
        for (int o = 0; o < KO; ++o) {
            const float* wr = w3 + o * 256 + c0;
            float s = acc[o];
            #pragma unroll
            for (int j = 0; j < 8; ++j) s = fmaf(xf[j], wr[j], s);
            acc[o] = s;
        }
    }
    #pragma unroll
    for (int o = 0; o < KO; ++o) acc[o] = fmaxf(acc[o], 0.f);
    float m = acc[0];
    #pragma unroll
    for (int o = 1; o < KO; ++o) m = fmaxf(m, acc[o]);
    float s = 0.f;
    #pragma unroll
    for (int o = 0; o < KO; ++o) { float e = __expf(acc[o] - m); acc[o] = e; s += e; }
    const float inv = 1.f / s;
    float* ap = attn + (size_t)b * KO * 16384 + hw;
    #pragma unroll
    for (int o = 0; o < KO; ++o) ap[(size_t)o * 16384] = acc[o] * inv;
}

// ---------------------------------------------------------------------------
// Pad key_high NCHW fp32 -> [b][c][134][140] with zero halo (y+3, x+4 shift).
// One block per (b,c) plane; writes coalesced.
// ---------------------------------------------------------------------------
__global__ __launch_bounds__(256) void pad_kh_kernel(
    const float* __restrict__ kh, float* __restrict__ khp) {
    const int bc = blockIdx.x;
    const float* src = kh + (size_t)bc * (HN * WN);
    float* dst = khp + (size_t)bc * KHP_PLANE;
    for (int i = threadIdx.x; i < KHP_PLANE; i += 256) {
        int yy = i / KHP_W;
        int xx = i - yy * KHP_W;
        int ys = yy - 3, xs = xx - 4;
        float v = 0.f;
        if ((unsigned)ys < 128u && (unsigned)xs < 128u) v = src[(ys << 7) + xs];
        dst[i] = v;
    }
}

// ---------------------------------------------------------------------------
// SVC v2: block = (b, y, 64-px xseg). attn tile (49x64) in LDS (sole LDS use,
// one barrier); kh windows global-direct from padded khp into a 12-float
// register window. Thread = (ci 0..15, pg 0..15): 4 px, 16 channels as
// 4 groups x 4 (attn reads amortized 4-deep inside the dy loop).
// ---------------------------------------------------------------------------
__global__ __launch_bounds__(256) void svc2_kernel(
    const float* __restrict__ khp, const float* __restrict__ attn,
    float* __restrict__ out) {
    __shared__ float a_s[KO * 64];
    const int tid = threadIdx.x;
    int by = blockIdx.y;
    by = (by & 7) * 128 + (by >> 3);       // XCD swizzle: XCD i -> batch i
    const int b = by >> 7, y = by & 127;
    const int x0 = blockIdx.x * 64;

    for (int i = tid; i < KO * 64; i += 256) {
        int o = i >> 6, px = i & 63;
        a_s[i] = attn[(((size_t)b * KO + o) << 14) + (y << 7) + x0 + px];
    }
    __syncthreads();

    const int ci = tid >> 4, pxb = (tid & 15) << 2;
    // khp row y covers kh row y-3 (dy=0); khp x (x0+pxb+i) covers kh x0+pxb-4+i
    const float* kb = khp + ((size_t)(b * 256 + ci) * KHP_H + y) * KHP_W + x0 + pxb;
    float* ob = out + (((size_t)b * 256 + ci) << 14) + (y << 7) + x0 + pxb;

    for (int grp = 0; grp < 4; ++grp) {
        f32x4 acc[4];
        f32x4 zero = {0.f, 0.f, 0.f, 0.f};
        #pragma unroll
        for (int k = 0; k < 4; ++k) acc[k] = zero;
        #pragma unroll
        for (int dy = 0; dy < 7; ++dy) {
            f32x4 av[7];
            #pragma unroll
            for (int dx = 0; dx < 7; ++dx)
                av[dx] = *(const f32x4*)&a_s[(dy * 7 + dx) * 64 + pxb];
            #pragma unroll
            for (int k = 0; k < 4; ++k) {
                const float* kr = kb + (size_t)(grp * 64 + k * 16) * KHP_PLANE + dy * KHP_W;
                f32x4 w0 = *(const f32x4*)(kr);
                f32x4 w1 = *(const f32x4*)(kr + 4);
                f32x4 w2 = *(const f32x4*)(kr + 8);
                float w[12] = {w0[0], w0[1], w0[2], w0[3],
                               w1[0], w1[1], w1[2], w1[3],
                               w2[0], w2[1], w2[2], w2[3]};
                // out px = x0+pxb+j; kh x = px+dx-3 -> khp x = base + dx+j+1
                #pragma unroll
                for (int dx = 0; dx < 7; ++dx) {
                    #pragma unroll
                    for (int j = 0; j < 4; ++j)
                        acc[k][j] = fmaf(w[dx + j + 1], av[dx][j], acc[k][j]);
                }
            }
        }
        #pragma unroll
        for (int k = 0; k < 4; ++k)
            *(f32x4*)&ob[(size_t)(grp * 64 + k * 16) << 14] = acc[k];
    }
}

// ---------------------------------------------------------------------------
extern "C" void kernel_launch(void* const* d_in, const int* in_sizes, int n_in,
                              void* d_out, int out_size, void* d_ws, size_t ws_size,
                              hipStream_t stream) {
    (void)in_sizes; (void)n_in; (void)out_size; (void)ws_size;
    const float* cur_low  = (const float*)d_in[0];
    const float* key_low  = (const float*)d_in[1];
    const float* key_high = (const float*)d_in[2];
    const float* w_red    = (const float*)d_in[3];
    const float* b_red    = (const float*)d_in[4];
    const float* w2       = (const float*)d_in[5];
    const float* b2       = (const float*)d_in[6];
    const float* w3       = (const float*)d_in[7];
    const float* b3       = (const float*)d_in[8];
    float* out = (float*)d_out;
    char* ws = (char*)d_ws;

    // Workspace layout (lifetime-overlapped, total 236.3 MB as in round 1):
    //   [0, 25.69M)        attn                    (conv3 -> svc2)
    //   [25.69M, 94.91M)   xpadc+xpadk             (convert -> conv1)
    //   [25.69M, 92.80M)   x2                      (conv2 -> conv3)
    //   [25.69M, 179.37M)  khp  153.68M            (pad_kh -> svc2; after x2 dead)
    //   [94.91M, 233.36M)  ypadc+ypadk             (conv1 -> conv2)
    //   [233.36M, 236.31M) packed weights
    const size_t SZ_ATTN = (size_t)BN * KO * HN * WN * 4;
    const size_t SZ_XPAD = (size_t)BN * HP * HP * CLOW * 2;
    const size_t SZ_YPAD = (size_t)BN * HP * HP * CMID * 2;
    float* attn  = (float*)(ws);
    short* xpadc = (short*)(ws + SZ_ATTN);
    short* xpadk = (short*)(ws + SZ_ATTN + SZ_XPAD);
    short* x2    = (short*)(ws + SZ_ATTN);
    float* khp   = (float*)(ws + SZ_ATTN);
    short* ypadc = (short*)(ws + SZ_ATTN + 2 * SZ_XPAD);
    short* ypadk = (short*)(ws + SZ_ATTN + 2 * SZ_XPAD + SZ_YPAD);
    short* w1p   = (short*)(ws + SZ_ATTN + 2 * SZ_XPAD + 2 * SZ_YPAD);
    short* w2p   = (short*)((char*)w1p + (size_t)256 * 1152 * 2);

    // zero pad halos only (idempotent; replaces 207 MB memset)
    zero_border_kernel<128><<<(8 * 516 * 16 + 255) / 256, 256, 0, stream>>>(xpadc);
    zero_border_kernel<128><<<(8 * 516 * 16 + 255) / 256, 256, 0, stream>>>(xpadk);
    zero_border_kernel<256><<<(8 * 516 * 32 + 255) / 256, 256, 0, stream>>>(ypadc);
    zero_border_kernel<256><<<(8 * 516 * 32 + 255) / 256, 256, 0, stream>>>(ypadk);

    convert_pad_kernel<<<dim3(1024, 2), 256, 0, stream>>>(cur_low, key_low, xpadc, xpadk);
    pack_w_kernel<128><<<(256 * 1152) / 256, 256, 0, stream>>>(w_red, w1p);
    pack_w_kernel<512><<<(256 * 4608) / 256, 256, 0, stream>>>(w2, w2p);

    conv_gemm_kernel<128, false, true><<<dim3(1024, 2), 256, 0, stream>>>(
        xpadc, nullptr, w1p, b_red, ypadc);
    conv_gemm_kernel<128, false, true><<<dim3(1024, 2), 256, 0, stream>>>(
        xpadk, nullptr, w1p, b_red, ypadk);
    conv_gemm_kernel<512, true, false><<<dim3(1024, 2), 256, 0, stream>>>(
        ypadc, ypadk, w2p, b2, x2);

    conv3_softmax_kernel<<<512, 256, 0, stream>>>(x2, w3, b3, attn);

    pad_kh_kernel<<<2048, 256, 0, stream>>>(key_high, khp);
    svc2_kernel<<<dim3(2, 1024), 256, 0, stream>>>(khp, attn, out);
}

// Round 3
// 1227.999 us; speedup vs baseline: 1.4121x; 1.1080x over previous
//
#include <hip/hip_runtime.h>
#include <stdint.h>
#include <stddef.h>

#define BN   8
#define HN   128
#define WN   128
#define HP   130
#define CLOW 128
#define CMID 256
#define KO   49

// padded key_high: [b][c][134][140] fp32, khp[b][c][y+3][x+4] = kh[b][c][y][x]
#define KHP_H 134
#define KHP_W 140
#define KHP_PLANE (KHP_H * KHP_W)   // 18760 floats

typedef __attribute__((ext_vector_type(4))) float f32x4;
typedef __attribute__((ext_vector_type(8))) short bf16x8;

typedef __attribute__((address_space(1))) const uint8_t ga_u8;
typedef __attribute__((address_space(3))) uint8_t lds_u8;

__device__ __forceinline__ short f2bf(float f) {
    uint32_t u = __float_as_uint(f);
    u += 0x7fffu + ((u >> 16) & 1u);
    return (short)(u >> 16);
}
__device__ __forceinline__ float bf2f(short s) {
    return __uint_as_float(((uint32_t)(uint16_t)s) << 16);
}
__device__ __forceinline__ void gload16(const void* g, void* l) {
    __builtin_amdgcn_global_load_lds((ga_u8*)g, (lds_u8*)l, 16, 0, 0);
}

// ---------------------------------------------------------------------------
// Zero only the halo cells of a padded [b][130][130][C] bf16 buffer.
// ---------------------------------------------------------------------------
template <int C>
__global__ __launch_bounds__(256) void zero_border_kernel(short* __restrict__ buf) {
    constexpr int GP = C / 8;
    int t = blockIdx.x * 256 + threadIdx.x;
    int cell = t / GP, g = t - cell * GP;
    if (cell >= 8 * 516) return;
    int b = cell / 516, r = cell - b * 516;
    int y, x;
    if (r < 260) { y = (r >= 130) ? 129 : 0; x = (r >= 130) ? (r - 130) : r; }
    else { int j = r - 260; y = 1 + (j >> 1); x = (j & 1) ? 129 : 0; }
    uint4 z = {0u, 0u, 0u, 0u};
    *(uint4*)&buf[(((size_t)b * HP + y) * HP + x) * C + g * 8] = z;
}

// ---------------------------------------------------------------------------
// Convert NCHW fp32 -> zero-padded NHWC bf16 ([b][130][130][128]).
// ---------------------------------------------------------------------------
__global__ __launch_bounds__(256) void convert_pad_kernel(
    const float* __restrict__ src0, const float* __restrict__ src1,
    short* __restrict__ dst0, short* __restrict__ dst1) {
    __shared__ short t[128 * 132];
    const int tid = threadIdx.x;
    const int by = blockIdx.x;
    const int b = by >> 7, y = by & 127;
    const float* src = blockIdx.y ? src1 : src0;
    short* dst = blockIdx.y ? dst1 : dst0;
    for (int k = 0; k < 64; ++k) {
        int i = (k << 8) + tid;
        int c = i >> 7, x = i & 127;
        t[x * 132 + c] = f2bf(src[(((size_t)b * CLOW + c) * HN + y) * WN + x]);
    }
    __syncthreads();
    short* drow = dst + (((size_t)b * HP + (y + 1)) * HP + 1) * CLOW;
    for (int k = 0; k < 64; ++k) {
        int i = (k << 8) + tid;
        int x = i >> 7, c = i & 127;
        drow[x * CLOW + c] = t[x * 132 + c];
    }
}

// ---------------------------------------------------------------------------
// Pack conv weights OIHW fp32 -> [cout][tap*CIN+cin] bf16 (tap-major K).
// ---------------------------------------------------------------------------
template <int CIN>
__global__ __launch_bounds__(256) void pack_w_kernel(
    const float* __restrict__ w, short* __restrict__ wp) {
    constexpr int K = 9 * CIN;
    int i = blockIdx.x * 256 + threadIdx.x;
    if (i >= 256 * K) return;
    int cout = i / K;
    int kk = i - cout * K;
    int tap = kk / CIN;
    int cin = kk & (CIN - 1);
    wp[i] = f2bf(w[((size_t)cout * CIN + cin) * 9 + tap]);
}

// ---------------------------------------------------------------------------
// Conv1 implicit-GEMM (m97-style, unchanged). Only CINT=128 instantiated.
// ---------------------------------------------------------------------------
template <int CINT, bool DUAL, bool OPAD>
__global__ __launch_bounds__(256) void conv_gemm_kernel(
    const short* __restrict__ in0, const short* __restrict__ in1,
    const short* __restrict__ wp, const float* __restrict__ bias,
    short* __restrict__ out) {
    constexpr int K = 9 * CINT;
    constexpr int NK = K / 32;
    constexpr int PST = DUAL ? 256 : CINT;
    __shared__ short Xs[128 * 32];
    __shared__ short Ws[128 * 32];
    const int tid = threadIdx.x;
    int bx = blockIdx.x;
    bx = (bx & 7) * 128 + (bx >> 3);
    const int b = bx >> 7, y = bx & 127;
    const int cout0 = blockIdx.y * 128;
    const int lane = tid & 63, wv = tid >> 6;
    const int wm = wv >> 1, wn = wv & 1;
    const int lr = lane & 15, lk = lane >> 4;

    f32x4 zero = {0.f, 0.f, 0.f, 0.f};
    f32x4 acc[4][4];
    #pragma unroll
    for (int i = 0; i < 4; ++i)
        #pragma unroll
        for (int j = 0; j < 4; ++j) acc[i][j] = zero;

    const int s0 = tid, s1 = tid + 256;
    const int xr0 = s0 >> 2, xr1 = s1 >> 2;
    const int xo0 = ((s0 & 3) ^ ((xr0 >> 1) & 3)) << 3;
    const int xo1 = ((s1 & 3) ^ ((xr1 >> 1) & 3)) << 3;
    const short* wrow0 = wp + (size_t)(cout0 + xr0) * K + xo0;
    const short* wrow1 = wp + (size_t)(cout0 + xr1) * K + xo1;

    for (int kk = 0; kk < NK; ++kk) {
        const int kg = kk * 32;
        const int tap = kg / CINT;
        const int cin0 = kg & (CINT - 1);
        const int ky = (tap * 11) >> 5;
        const int kx = tap - ky * 3;
        const short* xb;
        int ch0;
        if (DUAL) {
            if (cin0 < 256) { xb = in0; ch0 = cin0; }
            else            { xb = in1; ch0 = cin0 - 256; }
        } else { xb = in0; ch0 = cin0; }
        const short* xrow = xb + ((size_t)(b * HP + (y + ky)) * HP + kx) * PST + ch0;

        __syncthreads();
        gload16(xrow + xr0 * PST + xo0, &Xs[s0 * 8]);
        gload16(xrow + xr1 * PST + xo1, &Xs[s1 * 8]);
        gload16(wrow0 + kg, &Ws[s0 * 8]);
        gload16(wrow1 + kg, &Ws[s1 * 8]);
        __syncthreads();

        bf16x8 af[4], bg[4];
        #pragma unroll
        for (int mf = 0; mf < 4; ++mf) {
            int pix = wm * 64 + mf * 16 + lr;
            af[mf] = *(const bf16x8*)&Xs[pix * 32 + ((lk ^ ((pix >> 1) & 3)) << 3)];
        }
        #pragma unroll
        for (int nf = 0; nf < 4; ++nf) {
            int co = wn * 64 + nf * 16 + lr;
            bg[nf] = *(const bf16x8*)&Ws[co * 32 + ((lk ^ ((co >> 1) & 3)) << 3)];
        }
        #pragma unroll
        for (int mf = 0; mf < 4; ++mf)
            #pragma unroll
            for (int nf = 0; nf < 4; ++nf)
                acc[mf][nf] = __builtin_amdgcn_mfma_f32_16x16x32_bf16(
                    af[mf], bg[nf], acc[mf][nf], 0, 0, 0);
    }

    const int prow = lk * 4;
    #pragma unroll
    for (int nf = 0; nf < 4; ++nf) {
        const int co = cout0 + wn * 64 + nf * 16 + lr;
        const float bv = bias[co];
        #pragma unroll
        for (int mf = 0; mf < 4; ++mf) {
            #pragma unroll
            for (int r = 0; r < 4; ++r) {
                const int pix = wm * 64 + mf * 16 + prow + r;
                float v = fmaxf(acc[mf][nf][r] + bv, 0.f);
                size_t o;
                if (OPAD) o = ((size_t)(b * HP + (y + 1)) * HP + (pix + 1)) * CMID + co;
                else      o = ((size_t)(b * HN + y) * WN + pix) * CMID + co;
                out[o] = f2bf(v);
            }
        }
    }
}

// ---------------------------------------------------------------------------
// Conv2 as 256x256x(BK=64) 8-phase kernel (T2+T3+T4+T5 template, m201).
// M-tile = 2 image rows (256 px), N = all 256 couts, K = 4608 = 72 K-tiles.
// 8 waves (2M x 4N), per-wave 128x64 out. LDS 128 KB: 2 dbuf x (A 32K + B 32K).
// Per tile: 4 quadrant phases; stage tile t+2 (lead-2) into parity buffer,
// one region pair per phase ordered so current-tile reads of that region
// complete at/before the issue phase. vmcnt(8) once per tile boundary.
// ---------------------------------------------------------------------------
__global__ __launch_bounds__(512, 2) void conv2_8ph_kernel(
    const short* __restrict__ in0, const short* __restrict__ in1,
    const short* __restrict__ wp, const float* __restrict__ bias,
    short* __restrict__ out) {
    constexpr int NT = 72;               // 4608 / 64
    extern __shared__ __align__(16) short lds[];   // 131072 B
    const int tid = threadIdx.x;
    int bx = blockIdx.x;
    bx = (bx & 7) * 64 + (bx >> 3);      // XCD swizzle (512 blocks, 8 XCDs)
    const int b = bx >> 6, y0 = (bx & 63) << 1;

    const int lane = tid & 63, wv = tid >> 6;
    const int wm = wv >> 2, wn = wv & 3;
    const int lr = lane & 15, lk = lane >> 4;

    // staging per-thread geometry: rows rA and rA+64 of each half, chunk cc
    const int rA = tid >> 3, cc = tid & 7;
    const int cs = cc ^ (rA & 7);                 // swizzled source chunk
    const int pthrA0 = rA * 256 + cs * 8;         // A src offset, row rA
    const int pthrA1 = (rA + 64) * 256 + cs * 8;  // A src offset, row rA+64
    const int pthrB0 = rA * 4608 + cs * 8;
    const int pthrB1 = (rA + 64) * 4608 + cs * 8;
    const int dA0 = rA * 64 + cc * 8;             // LDS dest (shorts), half0
    const int dB0 = rA * 64 + cc * 8;

    // fragment-read LDS offsets (shorts)
    const int arow = (wm * 128 + lr) * 64;
    const int brow = (wn * 64 + lr) * 64;
    const int cof0 = ((lk) ^ (lr & 7)) * 8;
    const int cof1 = ((4 + lk) ^ (lr & 7)) * 8;

    f32x4 acc[8][4];
    f32x4 zero = {0.f, 0.f, 0.f, 0.f};
    #pragma unroll
    for (int i = 0; i < 8; ++i)
        #pragma unroll
        for (int j = 0; j < 4; ++j) acc[i][j] = zero;

    // which: 0 = A rows {rA, 128+rA}; 1 = B.h0; 2 = A rows {64+rA, 192+rA}; 3 = B.h1
    auto STAGE2 = [&](int t2, int which, short* bufA, short* bufB) {
        const int tap = t2 >> 3;
        const int cin0v = (t2 & 7) << 6;
        const short* src = (cin0v < 256) ? in0 : in1;
        const int ch0 = cin0v & 255;
        const int ky = (tap * 11) >> 5;
        const int kx = tap - ky * 3;
        if (which == 0 || which == 2) {
            const int po = (which == 0) ? pthrA0 : pthrA1;
            const int doff = (which == 0) ? 0 : 64 * 64;
            const short* s0 = src + ((size_t)(b * HP + (y0 + ky)) * HP + kx) * 256 + ch0;
            gload16(s0 + po, bufA + doff + dA0);                       // half 0
            gload16(s0 + (HP * 256) + po, bufA + 128 * 64 + doff + dA0); // half 1
        } else {
            const int h2 = (which == 1) ? 0 : 1;
            const short* sb = wp + (size_t)(h2 * 128) * 4608 + t2 * 64;
            short* d = bufB + h2 * 128 * 64 + dB0;
            gload16(sb + pthrB0, d);
            gload16(sb + pthrB1, d + 64 * 64);
        }
    };

    auto LDA = [&](const short* bufA, int mh, bf16x8 (&a)[4][2]) {
        #pragma unroll
        for (int i = 0; i < 4; ++i) {
            const int ro = arow + (mh * 64 + i * 16) * 64;
            a[i][0] = *(const bf16x8*)(bufA + ro + cof0);
            a[i][1] = *(const bf16x8*)(bufA + ro + cof1);
        }
    };
    auto LDB = [&](const short* bufB, int nh, bf16x8 (&bb)[2][2]) {
        #pragma unroll
        for (int j = 0; j < 2; ++j) {
            const int ro = brow + (nh * 32 + j * 16) * 64;
            bb[j][0] = *(const bf16x8*)(bufB + ro + cof0);
            bb[j][1] = *(const bf16x8*)(bufB + ro + cof1);
        }
    };

#define PH_PRE() do { __builtin_amdgcn_sched_barrier(0); \
                      __builtin_amdgcn_s_barrier(); \
                      asm volatile("s_waitcnt lgkmcnt(0)" ::: "memory"); \
                      __builtin_amdgcn_sched_barrier(0); \
                      __builtin_amdgcn_s_setprio(1); } while (0)
#define PH_POST() do { __builtin_amdgcn_s_setprio(0); \
                       __builtin_amdgcn_sched_barrier(0); \
                       __builtin_amdgcn_s_barrier(); } while (0)
#define MFMA_Q(A_, B_, MH, NH) do { \
    _Pragma("unroll") \
    for (int i_ = 0; i_ < 4; ++i_) { \
        _Pragma("unroll") \
        for (int j_ = 0; j_ < 2; ++j_) { \
            acc[(MH)*4+i_][(NH)*2+j_] = __builtin_amdgcn_mfma_f32_16x16x32_bf16( \
                A_[i_][0], B_[j_][0], acc[(MH)*4+i_][(NH)*2+j_], 0, 0, 0); \
            acc[(MH)*4+i_][(NH)*2+j_] = __builtin_amdgcn_mfma_f32_16x16x32_bf16( \
                A_[i_][1], B_[j_][1], acc[(MH)*4+i_][(NH)*2+j_], 0, 0, 0); \
        } \
    } } while (0)

    short* const A0 = lds;
    short* const A1 = lds + 16384;
    short* const B0 = lds + 32768;
    short* const B1 = lds + 49152;

    // prologue: stage tiles 0 and 1; wait tile 0 landed (tile 1 in flight)
    STAGE2(0, 0, A0, B0); STAGE2(0, 1, A0, B0);
    STAGE2(0, 2, A0, B0); STAGE2(0, 3, A0, B0);
    STAGE2(1, 0, A1, B1); STAGE2(1, 1, A1, B1);
    STAGE2(1, 2, A1, B1); STAGE2(1, 3, A1, B1);
    asm volatile("s_waitcnt vmcnt(8)" ::: "memory");
    __builtin_amdgcn_sched_barrier(0);
    __builtin_amdgcn_s_barrier();

    auto TILE = [&](int t, short* bufA, short* bufB) {
        const int t2 = t + 2;
        const bool st = (t2 < NT);
        bf16x8 ar[4][2], br0[2][2], br1[2][2];
        // phase 0 (mh=0, nh=0)
        LDA(bufA, 0, ar);
        LDB(bufB, 0, br0);
        if (st) STAGE2(t2, 0, bufA, bufB);
        PH_PRE();
        MFMA_Q(ar, br0, 0, 0);
        PH_POST();
        // phase 1 (mh=0, nh=1)
        LDB(bufB, 1, br1);
        if (st) STAGE2(t2, 1, bufA, bufB);
        PH_PRE();
        MFMA_Q(ar, br1, 0, 1);
        PH_POST();
        // phase 2 (mh=1, nh=0)
        LDA(bufA, 1, ar);
        if (st) STAGE2(t2, 2, bufA, bufB);
        PH_PRE();
        MFMA_Q(ar, br0, 1, 0);
        PH_POST();
        // phase 3 (mh=1, nh=1)
        if (st) STAGE2(t2, 3, bufA, bufB);
        PH_PRE();
        MFMA_Q(ar, br1, 1, 1);
        __builtin_amdgcn_s_setprio(0);
        __builtin_amdgcn_sched_barrier(0);
        if (st)                asm volatile("s_waitcnt vmcnt(8)" ::: "memory");
        else if (t == NT - 2)  asm volatile("s_waitcnt vmcnt(0)" ::: "memory");
        __builtin_amdgcn_sched_barrier(0);
        __builtin_amdgcn_s_barrier();
    };

    for (int t = 0; t < NT; t += 2) {
        TILE(t,     A0, B0);
        TILE(t + 1, A1, B1);
    }
#undef PH_PRE
#undef PH_POST
#undef MFMA_Q

    // epilogue: bias + ReLU -> NHWC bf16
    #pragma unroll
    for (int nf = 0; nf < 4; ++nf) {
        const int co = wn * 64 + nf * 16 + lr;
        const float bv = bias[co];
        #pragma unroll
        for (int mf = 0; mf < 8; ++mf) {
            #pragma unroll
            for (int rr = 0; rr < 4; ++rr) {
                const int p = wm * 128 + mf * 16 + lk * 4 + rr;
                const int y = y0 + (p >> 7), x = p & 127;
                float v = fmaxf(acc[mf][nf][rr] + bv, 0.f);
                out[((size_t)((b * HN + y) * WN + x)) * 256 + co] = f2bf(v);
            }
        }
    }
}

// ---------------------------------------------------------------------------
// 1x1 conv (256 -> 49) + ReLU + softmax (unchanged).
// ---------------------------------------------------------------------------
__global__ __launch_bounds__(256) void conv3_softmax_kernel(
    const short* __restrict__ x2, const float* __restrict__ w3,
    const float* __restrict__ b3, float* __restrict__ attn) {
    const int p = blockIdx.x * 256 + threadIdx.x;
    const int b = p >> 14, hw = p & 16383;
    float acc[KO];
    #pragma unroll
    for (int o = 0; o < KO; ++o) acc[o] = b3[o];
    const short* xp = x2 + (size_t)p * 256;
    #pragma unroll 1
    for (int c0 = 0; c0 < 256; c0 += 8) {
        bf16x8 xv = *(const bf16x8*)&xp[c0];
        float xf[8];
        #pragma unroll
        for (int j = 0; j < 8; ++j) xf[j] = bf2f(xv[j]);
        #pragma unroll
        for (int o = 0; o < KO; ++o) {
            const float* wr = w3 + o * 256 + c0;
            float s = acc[o];
            #pragma unroll
            for (int j = 0; j < 8; ++j) s = fmaf(xf[j], wr[j], s);
            acc[o] = s;
        }
    }
    #pragma unroll
    for (int o = 0; o < KO; ++o) acc[o] = fmaxf(acc[o], 0.f);
    float m = acc[0];
    #pragma unroll
    for (int o = 1; o < KO; ++o) m = fmaxf(m, acc[o]);
    float s = 0.f;
    #pragma unroll
    for (int o = 0; o < KO; ++o) { float e = __expf(acc[o] - m); acc[o] = e; s += e; }
    const float inv = 1.f / s;
    float* ap = attn + (size_t)b * KO * 16384 + hw;
    #pragma unroll
    for (int o = 0; o < KO; ++o) ap[(size_t)o * 16384] = acc[o] * inv;
}

// ---------------------------------------------------------------------------
// Pad key_high NCHW fp32 -> [b][c][134][140] with zero halo.
// ---------------------------------------------------------------------------
__global__ __launch_bounds__(256) void pad_kh_kernel(
    const float* __restrict__ kh, float* __restrict__ khp) {
    const int bc = blockIdx.x;
    const float* src = kh + (size_t)bc * (HN * WN);
    float* dst = khp + (size_t)bc * KHP_PLANE;
    for (int i = threadIdx.x; i < KHP_PLANE; i += 256) {
        int yy = i / KHP_W;
        int xx = i - yy * KHP_W;
        int ys = yy - 3, xs = xx - 4;
        float v = 0.f;
        if ((unsigned)ys < 128u && (unsigned)xs < 128u) v = src[(ys << 7) + xs];
        dst[i] = v;
    }
}

// ---------------------------------------------------------------------------
// SVC v2 (unchanged from round 2).
// ---------------------------------------------------------------------------
__global__ __launch_bounds__(256) void svc2_kernel(
    const float* __restrict__ khp, const float* __restrict__ attn,
    float* __restrict__ out) {
    __shared__ float a_s[KO * 64];
    const int tid = threadIdx.x;
    int by = blockIdx.y;
    by = (by & 7) * 128 + (by >> 3);
    const int b = by >> 7, y = by & 127;
    const int x0 = blockIdx.x * 64;

    for (int i = tid; i < KO * 64; i += 256) {
        int o = i >> 6, px = i & 63;
        a_s[i] = attn[(((size_t)b * KO + o) << 14) + (y << 7) + x0 + px];
    }
    __syncthreads();

    const int ci = tid >> 4, pxb = (tid & 15) << 2;
    const float* kb = khp + ((size_t)(b * 256 + ci) * KHP_H + y) * KHP_W + x0 + pxb;
    float* ob = out + (((size_t)b * 256 + ci) << 14) + (y << 7) + x0 + pxb;

    for (int grp = 0; grp < 4; ++grp) {
        f32x4 acc[4];
        f32x4 zero = {0.f, 0.f, 0.f, 0.f};
        #pragma unroll
        for (int k = 0; k < 4; ++k) acc[k] = zero;
        #pragma unroll
        for (int dy = 0; dy < 7; ++dy) {
            f32x4 av[7];
            #pragma unroll
            for (int dx = 0; dx < 7; ++dx)
                av[dx] = *(const f32x4*)&a_s[(dy * 7 + dx) * 64 + pxb];
            #pragma unroll
            for (int k = 0; k < 4; ++k) {
                const float* kr = kb + (size_t)(grp * 64 + k * 16) * KHP_PLANE + dy * KHP_W;
                f32x4 w0 = *(const f32x4*)(kr);
                f32x4 w1 = *(const f32x4*)(kr + 4);
                f32x4 w2 = *(const f32x4*)(kr + 8);
                float w[12] = {w0[0], w0[1], w0[2], w0[3],
                               w1[0], w1[1], w1[2], w1[3],
                               w2[0], w2[1], w2[2], w2[3]};
                #pragma unroll
                for (int dx = 0; dx < 7; ++dx) {
                    #pragma unroll
                    for (int j = 0; j < 4; ++j)
                        acc[k][j] = fmaf(w[dx + j + 1], av[dx][j], acc[k][j]);
                }
            }
        }
        #pragma unroll
        for (int k = 0; k < 4; ++k)
            *(f32x4*)&ob[(size_t)(grp * 64 + k * 16) << 14] = acc[k];
    }
}

// ---------------------------------------------------------------------------
extern "C" void kernel_launch(void* const* d_in, const int* in_sizes, int n_in,
                              void* d_out, int out_size, void* d_ws, size_t ws_size,
                              hipStream_t stream) {
    (void)in_sizes; (void)n_in; (void)out_size; (void)ws_size;
    const float* cur_low  = (const float*)d_in[0];
    const float* key_low  = (const float*)d_in[1];
    const float* key_high = (const float*)d_in[2];
    const float* w_red    = (const float*)d_in[3];
    const float* b_red    = (const float*)d_in[4];
    const float* w2       = (const float*)d_in[5];
    const float* b2       = (const float*)d_in[6];
    const float* w3       = (const float*)d_in[7];
    const float* b3       = (const float*)d_in[8];
    float* out = (float*)d_out;
    char* ws = (char*)d_ws;

    const size_t SZ_ATTN = (size_t)BN * KO * HN * WN * 4;
    const size_t SZ_XPAD = (size_t)BN * HP * HP * CLOW * 2;
    const size_t SZ_YPAD = (size_t)BN * HP * HP * CMID * 2;
    float* attn  = (float*)(ws);
    short* xpadc = (short*)(ws + SZ_ATTN);
    short* xpadk = (short*)(ws + SZ_ATTN + SZ_XPAD);
    short* x2    = (short*)(ws + SZ_ATTN);
    float* khp   = (float*)(ws + SZ_ATTN);
    short* ypadc = (short*)(ws + SZ_ATTN + 2 * SZ_XPAD);
    short* ypadk = (short*)(ws + SZ_ATTN + 2 * SZ_XPAD + SZ_YPAD);
    short* w1p   = (short*)(ws + SZ_ATTN + 2 * SZ_XPAD + 2 * SZ_YPAD);
    short* w2p   = (short*)((char*)w1p + (size_t)256 * 1152 * 2);

    hipFuncSetAttribute((const void*)conv2_8ph_kernel,
                        hipFuncAttributeMaxDynamicSharedMemorySize, 131072);

    zero_border_kernel<128><<<(8 * 516 * 16 + 255) / 256, 256, 0, stream>>>(xpadc);
    zero_border_kernel<128><<<(8 * 516 * 16 + 255) / 256, 256, 0, stream>>>(xpadk);
    zero_border_kernel<256><<<(8 * 516 * 32 + 255) / 256, 256, 0, stream>>>(ypadc);
    zero_border_kernel<256><<<(8 * 516 * 32 + 255) / 256, 256, 0, stream>>>(ypadk);

    convert_pad_kernel<<<dim3(1024, 2), 256, 0, stream>>>(cur_low, key_low, xpadc, xpadk);
    pack_w_kernel<128><<<(256 * 1152) / 256, 256, 0, stream>>>(w_red, w1p);
    pack_w_kernel<512><<<(256 * 4608) / 256, 256, 0, stream>>>(w2, w2p);

    conv_gemm_kernel<128, false, true><<<dim3(1024, 2), 256, 0, stream>>>(
        xpadc, nullptr, w1p, b_red, ypadc);
    conv_gemm_kernel<128, false, true><<<dim3(1024, 2), 256, 0, stream>>>(
        xpadk, nullptr, w1p, b_red, ypadk);

    conv2_8ph_kernel<<<512, 512, 131072, stream>>>(ypadc, ypadk, w2p, b2, x2);

    conv3_softmax_kernel<<<512, 256, 0, stream>>>(x2, w3, b3, attn);

    pad_kh_kernel<<<2048, 256, 0, stream>>>(key_high, khp);
    svc2_kernel<<<dim3(2, 1024), 256, 0, stream>>>(khp, attn, out);
}

// Round 4
// 1065.646 us; speedup vs baseline: 1.6273x; 1.1524x over previous
//
#include <hip/hip_runtime.h>
#include <stdint.h>
#include <stddef.h>

#define BN   8
#define HN   128
#define WN   128
#define HP   130
#define CLOW 128
#define CMID 256
#define KO   49

// padded key_high: [b][c][134][140] fp32, khp[b][c][y+3][x+4] = kh[b][c][y][x]
#define KHP_H 134
#define KHP_W 140
#define KHP_PLANE (KHP_H * KHP_W)   // 18760 floats

typedef __attribute__((ext_vector_type(4))) float f32x4;
typedef __attribute__((ext_vector_type(8))) short bf16x8;

typedef __attribute__((address_space(1))) const uint8_t ga_u8;
typedef __attribute__((address_space(3))) uint8_t lds_u8;

__device__ __forceinline__ short f2bf(float f) {
    uint32_t u = __float_as_uint(f);
    u += 0x7fffu + ((u >> 16) & 1u);
    return (short)(u >> 16);
}
__device__ __forceinline__ float bf2f(short s) {
    return __uint_as_float(((uint32_t)(uint16_t)s) << 16);
}
__device__ __forceinline__ void gload16(const void* g, void* l) {
    __builtin_amdgcn_global_load_lds((ga_u8*)g, (lds_u8*)l, 16, 0, 0);
}

// ---------------------------------------------------------------------------
// Zero only the halo cells of a padded [b][130][130][C] bf16 buffer.
// ---------------------------------------------------------------------------
template <int C>
__global__ __launch_bounds__(256) void zero_border_kernel(short* __restrict__ buf) {
    constexpr int GP = C / 8;
    int t = blockIdx.x * 256 + threadIdx.x;
    int cell = t / GP, g = t - cell * GP;
    if (cell >= 8 * 516) return;
    int b = cell / 516, r = cell - b * 516;
    int y, x;
    if (r < 260) { y = (r >= 130) ? 129 : 0; x = (r >= 130) ? (r - 130) : r; }
    else { int j = r - 260; y = 1 + (j >> 1); x = (j & 1) ? 129 : 0; }
    uint4 z = {0u, 0u, 0u, 0u};
    *(uint4*)&buf[(((size_t)b * HP + y) * HP + x) * C + g * 8] = z;
}

// ---------------------------------------------------------------------------
// Convert NCHW fp32 -> zero-padded NHWC bf16 ([b][130][130][128]).
// ---------------------------------------------------------------------------
__global__ __launch_bounds__(256) void convert_pad_kernel(
    const float* __restrict__ src0, const float* __restrict__ src1,
    short* __restrict__ dst0, short* __restrict__ dst1) {
    __shared__ short t[128 * 132];
    const int tid = threadIdx.x;
    const int by = blockIdx.x;
    const int b = by >> 7, y = by & 127;
    const float* src = blockIdx.y ? src1 : src0;
    short* dst = blockIdx.y ? dst1 : dst0;
    for (int k = 0; k < 64; ++k) {
        int i = (k << 8) + tid;
        int c = i >> 7, x = i & 127;
        t[x * 132 + c] = f2bf(src[(((size_t)b * CLOW + c) * HN + y) * WN + x]);
    }
    __syncthreads();
    short* drow = dst + (((size_t)b * HP + (y + 1)) * HP + 1) * CLOW;
    for (int k = 0; k < 64; ++k) {
        int i = (k << 8) + tid;
        int x = i >> 7, c = i & 127;
        drow[x * CLOW + c] = t[x * 132 + c];
    }
}

// ---------------------------------------------------------------------------
// Pack conv weights OIHW fp32 -> tap-inner K order:
// K-tile t (CB channels each): cb = t/9, tap = t%9; wp[cout][t*CB+j],
// cin = cb*CB + j. GEMM B-addressing (row offset = t*CB) is unchanged.
// ---------------------------------------------------------------------------
template <int CIN, int CB>
__global__ __launch_bounds__(256) void pack_w_kernel(
    const float* __restrict__ w, short* __restrict__ wp) {
    constexpr int K = 9 * CIN;
    int i = blockIdx.x * 256 + threadIdx.x;
    if (i >= 256 * K) return;
    int cout = i / K;
    int r = i - cout * K;
    int t = r / CB;
    int j = r - t * CB;
    int cb = t / 9;
    int tap = t - cb * 9;
    int cin = cb * CB + j;
    wp[i] = f2bf(w[((size_t)cout * CIN + cin) * 9 + tap]);
}

// ---------------------------------------------------------------------------
// Conv1 implicit-GEMM (m97-style), tap-inner K order, both images in one
// launch (blockIdx.z selects in/out pair; shared weights stay L2-hot).
// ---------------------------------------------------------------------------
__global__ __launch_bounds__(256) void conv1_kernel(
    const short* __restrict__ in_a, const short* __restrict__ in_b,
    const short* __restrict__ wp, const float* __restrict__ bias,
    short* __restrict__ out_a, short* __restrict__ out_b) {
    constexpr int K = 1152;              // 9 * 128
    constexpr int NK = 36;               // K / 32
    __shared__ short Xs[128 * 32];
    __shared__ short Ws[128 * 32];
    const int tid = threadIdx.x;
    int bx = blockIdx.x;
    bx = (bx & 7) * 128 + (bx >> 3);
    const int b = bx >> 7, y = bx & 127;
    const int cout0 = blockIdx.y * 128;
    const short* in = blockIdx.z ? in_b : in_a;
    short* out = blockIdx.z ? out_b : out_a;
    const int lane = tid & 63, wv = tid >> 6;
    const int wm = wv >> 1, wn = wv & 1;
    const int lr = lane & 15, lk = lane >> 4;

    f32x4 zero = {0.f, 0.f, 0.f, 0.f};
    f32x4 acc[4][4];
    #pragma unroll
    for (int i = 0; i < 4; ++i)
        #pragma unroll
        for (int j = 0; j < 4; ++j) acc[i][j] = zero;

    const int s0 = tid, s1 = tid + 256;
    const int xr0 = s0 >> 2, xr1 = s1 >> 2;
    const int xo0 = ((s0 & 3) ^ ((xr0 >> 1) & 3)) << 3;
    const int xo1 = ((s1 & 3) ^ ((xr1 >> 1) & 3)) << 3;
    const short* wrow0 = wp + (size_t)(cout0 + xr0) * K + xo0;
    const short* wrow1 = wp + (size_t)(cout0 + xr1) * K + xo1;

    for (int kk = 0; kk < NK; ++kk) {
        const int kg = kk * 32;
        const int cb = (kk * 57) >> 9;       // kk/9 for kk<72
        const int tap = kk - cb * 9;
        const int ch0 = cb << 5;             // 32-ch blocks
        const int ky = (tap * 11) >> 5;      // tap/3
        const int kx = tap - ky * 3;
        const short* xrow = in + ((size_t)(b * HP + (y + ky)) * HP + kx) * CLOW + ch0;

        __syncthreads();
        gload16(xrow + xr0 * CLOW + xo0, &Xs[s0 * 8]);
        gload16(xrow + xr1 * CLOW + xo1, &Xs[s1 * 8]);
        gload16(wrow0 + kg, &Ws[s0 * 8]);
        gload16(wrow1 + kg, &Ws[s1 * 8]);
        __syncthreads();

        bf16x8 af[4], bg[4];
        #pragma unroll
        for (int mf = 0; mf < 4; ++mf) {
            int pix = wm * 64 + mf * 16 + lr;
            af[mf] = *(const bf16x8*)&Xs[pix * 32 + ((lk ^ ((pix >> 1) & 3)) << 3)];
        }
        #pragma unroll
        for (int nf = 0; nf < 4; ++nf) {
            int co = wn * 64 + nf * 16 + lr;
            bg[nf] = *(const bf16x8*)&Ws[co * 32 + ((lk ^ ((co >> 1) & 3)) << 3)];
        }
        #pragma unroll
        for (int mf = 0; mf < 4; ++mf)
            #pragma unroll
            for (int nf = 0; nf < 4; ++nf)
                acc[mf][nf] = __builtin_amdgcn_mfma_f32_16x16x32_bf16(
                    af[mf], bg[nf], acc[mf][nf], 0, 0, 0);
    }

    // epilogue: nf-innermost so 4 consecutive stores cover 128B contiguous
    const int prow = lk * 4;
    float bvs[4];
    #pragma unroll
    for (int nf = 0; nf < 4; ++nf) bvs[nf] = bias[cout0 + wn * 64 + nf * 16 + lr];
    #pragma unroll
    for (int mf = 0; mf < 4; ++mf) {
        #pragma unroll
        for (int r = 0; r < 4; ++r) {
            const int pix = wm * 64 + mf * 16 + prow + r;
            short* op = out + ((size_t)(b * HP + (y + 1)) * HP + (pix + 1)) * CMID
                            + cout0 + wn * 64 + lr;
            #pragma unroll
            for (int nf = 0; nf < 4; ++nf)
                op[nf * 16] = f2bf(fmaxf(acc[mf][nf][r] + bvs[nf], 0.f));
        }
    }
}

// ---------------------------------------------------------------------------
// Conv2 as 256x256x(BK=64) 8-phase kernel (T2+T3+T4+T5). Tap-inner K order:
// K-tile t: cb = t/9 (64-ch block), tap = t%9 -> same input rows re-read
// within 1-3 consecutive tiles (L2-hit) instead of 8 tiles apart (HBM).
// ---------------------------------------------------------------------------
__global__ __launch_bounds__(512, 2) void conv2_8ph_kernel(
    const short* __restrict__ in0, const short* __restrict__ in1,
    const short* __restrict__ wp, const float* __restrict__ bias,
    short* __restrict__ out) {
    constexpr int NT = 72;               // 4608 / 64
    extern __shared__ __align__(16) short lds[];   // 131072 B
    const int tid = threadIdx.x;
    int bx = blockIdx.x;
    bx = (bx & 7) * 64 + (bx >> 3);      // XCD swizzle (512 blocks, 8 XCDs)
    const int b = bx >> 6, y0 = (bx & 63) << 1;

    const int lane = tid & 63, wv = tid >> 6;
    const int wm = wv >> 2, wn = wv & 3;
    const int lr = lane & 15, lk = lane >> 4;

    const int rA = tid >> 3, cc = tid & 7;
    const int cs = cc ^ (rA & 7);
    const int pthrA0 = rA * 256 + cs * 8;
    const int pthrA1 = (rA + 64) * 256 + cs * 8;
    const int pthrB0 = rA * 4608 + cs * 8;
    const int pthrB1 = (rA + 64) * 4608 + cs * 8;
    const int dA0 = rA * 64 + cc * 8;
    const int dB0 = rA * 64 + cc * 8;

    const int arow = (wm * 128 + lr) * 64;
    const int brow = (wn * 64 + lr) * 64;
    const int cof0 = ((lk) ^ (lr & 7)) * 8;
    const int cof1 = ((4 + lk) ^ (lr & 7)) * 8;

    f32x4 acc[8][4];
    f32x4 zero = {0.f, 0.f, 0.f, 0.f};
    #pragma unroll
    for (int i = 0; i < 8; ++i)
        #pragma unroll
        for (int j = 0; j < 4; ++j) acc[i][j] = zero;

    auto STAGE2 = [&](int t2, int which, short* bufA, short* bufB) {
        const int cb = (t2 * 57) >> 9;       // t2/9
        const int tap = t2 - cb * 9;
        const int ch0v = cb << 6;            // 64-ch blocks
        const short* src = (ch0v < 256) ? in0 : in1;
        const int ch0 = ch0v & 255;
        const int ky = (tap * 11) >> 5;
        const int kx = tap - ky * 3;
        if (which == 0 || which == 2) {
            const int po = (which == 0) ? pthrA0 : pthrA1;
            const int doff = (which == 0) ? 0 : 64 * 64;
            const short* s0 = src + ((size_t)(b * HP + (y0 + ky)) * HP + kx) * 256 + ch0;
            gload16(s0 + po, bufA + doff + dA0);
            gload16(s0 + (HP * 256) + po, bufA + 128 * 64 + doff + dA0);
        } else {
            const int h2 = (which == 1) ? 0 : 1;
            const short* sb = wp + (size_t)(h2 * 128) * 4608 + t2 * 64;
            short* d = bufB + h2 * 128 * 64 + dB0;
            gload16(sb + pthrB0, d);
            gload16(sb + pthrB1, d + 64 * 64);
        }
    };

    auto LDA = [&](const short* bufA, int mh, bf16x8 (&a)[4][2]) {
        #pragma unroll
        for (int i = 0; i < 4; ++i) {
            const int ro = arow + (mh * 64 + i * 16) * 64;
            a[i][0] = *(const bf16x8*)(bufA + ro + cof0);
            a[i][1] = *(const bf16x8*)(bufA + ro + cof1);
        }
    };
    auto LDB = [&](const short* bufB, int nh, bf16x8 (&bb)[2][2]) {
        #pragma unroll
        for (int j = 0; j < 2; ++j) {
            const int ro = brow + (nh * 32 + j * 16) * 64;
            bb[j][0] = *(const bf16x8*)(bufB + ro + cof0);
            bb[j][1] = *(const bf16x8*)(bufB + ro + cof1);
        }
    };

#define PH_PRE() do { __builtin_amdgcn_sched_barrier(0); \
                      __builtin_amdgcn_s_barrier(); \
                      asm volatile("s_waitcnt lgkmcnt(0)" ::: "memory"); \
                      __builtin_amdgcn_sched_barrier(0); \
                      __builtin_amdgcn_s_setprio(1); } while (0)
#define PH_POST() do { __builtin_amdgcn_s_setprio(0); \
                       __builtin_amdgcn_sched_barrier(0); \
                       __builtin_amdgcn_s_barrier(); } while (0)
#define MFMA_Q(A_, B_, MH, NH) do { \
    _Pragma("unroll") \
    for (int i_ = 0; i_ < 4; ++i_) { \
        _Pragma("unroll") \
        for (int j_ = 0; j_ < 2; ++j_) { \
            acc[(MH)*4+i_][(NH)*2+j_] = __builtin_amdgcn_mfma_f32_16x16x32_bf16( \
                A_[i_][0], B_[j_][0], acc[(MH)*4+i_][(NH)*2+j_], 0, 0, 0); \
            acc[(MH)*4+i_][(NH)*2+j_] = __builtin_amdgcn_mfma_f32_16x16x32_bf16( \
                A_[i_][1], B_[j_][1], acc[(MH)*4+i_][(NH)*2+j_], 0, 0, 0); \
        } \
    } } while (0)

    short* const A0 = lds;
    short* const A1 = lds + 16384;
    short* const B0 = lds + 32768;
    short* const B1 = lds + 49152;

    STAGE2(0, 0, A0, B0); STAGE2(0, 1, A0, B0);
    STAGE2(0, 2, A0, B0); STAGE2(0, 3, A0, B0);
    STAGE2(1, 0, A1, B1); STAGE2(1, 1, A1, B1);
    STAGE2(1, 2, A1, B1); STAGE2(1, 3, A1, B1);
    asm volatile("s_waitcnt vmcnt(8)" ::: "memory");
    __builtin_amdgcn_sched_barrier(0);
    __builtin_amdgcn_s_barrier();

    auto TILE = [&](int t, short* bufA, short* bufB) {
        const int t2 = t + 2;
        const bool st = (t2 < NT);
        bf16x8 ar[4][2], br0[2][2], br1[2][2];
        // phase 0 (mh=0, nh=0)
        LDA(bufA, 0, ar);
        LDB(bufB, 0, br0);
        if (st) STAGE2(t2, 0, bufA, bufB);
        PH_PRE();
        MFMA_Q(ar, br0, 0, 0);
        PH_POST();
        // phase 1 (mh=0, nh=1)
        LDB(bufB, 1, br1);
        if (st) STAGE2(t2, 1, bufA, bufB);
        PH_PRE();
        MFMA_Q(ar, br1, 0, 1);
        PH_POST();
        // phase 2 (mh=1, nh=0)
        LDA(bufA, 1, ar);
        if (st) STAGE2(t2, 2, bufA, bufB);
        PH_PRE();
        MFMA_Q(ar, br0, 1, 0);
        PH_POST();
        // phase 3 (mh=1, nh=1)
        if (st) STAGE2(t2, 3, bufA, bufB);
        PH_PRE();
        MFMA_Q(ar, br1, 1, 1);
        __builtin_amdgcn_s_setprio(0);
        __builtin_amdgcn_sched_barrier(0);
        if (st)                asm volatile("s_waitcnt vmcnt(8)" ::: "memory");
        else if (t == NT - 2)  asm volatile("s_waitcnt vmcnt(0)" ::: "memory");
        __builtin_amdgcn_sched_barrier(0);
        __builtin_amdgcn_s_barrier();
    };

    for (int t = 0; t < NT; t += 2) {
        TILE(t,     A0, B0);
        TILE(t + 1, A1, B1);
    }
#undef PH_PRE
#undef PH_POST
#undef MFMA_Q

    // epilogue: nf-innermost store order (write-combining: 4 stores = 128B run)
    float bvs[4];
    #pragma unroll
    for (int nf = 0; nf < 4; ++nf) bvs[nf] = bias[wn * 64 + nf * 16 + lr];
    #pragma unroll
    for (int mf = 0; mf < 8; ++mf) {
        #pragma unroll
        for (int rr = 0; rr < 4; ++rr) {
            const int p = wm * 128 + mf * 16 + lk * 4 + rr;
            const int y = y0 + (p >> 7), x = p & 127;
            short* op = out + ((size_t)((b * HN + y) * WN + x)) * 256 + wn * 64 + lr;
            #pragma unroll
            for (int nf = 0; nf < 4; ++nf)
                op[nf * 16] = f2bf(fmaxf(acc[mf][nf][rr] + bvs[nf], 0.f));
        }
    }
}

// ---------------------------------------------------------------------------
// 1x1 conv (256 -> 49) + ReLU + softmax (unchanged).
// ---------------------------------------------------------------------------
__global__ __launch_bounds__(256) void conv3_softmax_kernel(
    const short* __restrict__ x2, const float* __restrict__ w3,
    const float* __restrict__ b3, float* __restrict__ attn) {
    const int p = blockIdx.x * 256 + threadIdx.x;
    const int b = p >> 14, hw = p & 16383;
    float acc[KO];
    #pragma unroll
    for (int o = 0; o < KO; ++o) acc[o] = b3[o];
    const short* xp = x2 + (size_t)p * 256;
    #pragma unroll 1
    for (int c0 = 0; c0 < 256; c0 += 8) {
        bf16x8 xv = *(const bf16x8*)&xp[c0];
        float xf[8];
        #pragma unroll
        for (int j = 0; j < 8; ++j) xf[j] = bf2f(xv[j]);
        #pragma unroll
        for (int o = 0; o < KO; ++o) {
            const float* wr = w3 + o * 256 + c0;
            float s = acc[o];
            #pragma unroll
            for (int j = 0; j < 8; ++j) s = fmaf(xf[j], wr[j], s);
            acc[o] = s;
        }
    }
    #pragma unroll
    for (int o = 0; o < KO; ++o) acc[o] = fmaxf(acc[o], 0.f);
    float m = acc[0];
    #pragma unroll
    for (int o = 1; o < KO; ++o) m = fmaxf(m, acc[o]);
    float s = 0.f;
    #pragma unroll
    for (int o = 0; o < KO; ++o) { float e = __expf(acc[o] - m); acc[o] = e; s += e; }
    const float inv = 1.f / s;
    float* ap = attn + (size_t)b * KO * 16384 + hw;
    #pragma unroll
    for (int o = 0; o < KO; ++o) ap[(size_t)o * 16384] = acc[o] * inv;
}

// ---------------------------------------------------------------------------
// Pad key_high NCHW fp32 -> [b][c][134][140] with zero halo.
// ---------------------------------------------------------------------------
__global__ __launch_bounds__(256) void pad_kh_kernel(
    const float* __restrict__ kh, float* __restrict__ khp) {
    const int bc = blockIdx.x;
    const float* src = kh + (size_t)bc * (HN * WN);
    float* dst = khp + (size_t)bc * KHP_PLANE;
    for (int i = threadIdx.x; i < KHP_PLANE; i += 256) {
        int yy = i / KHP_W;
        int xx = i - yy * KHP_W;
        int ys = yy - 3, xs = xx - 4;
        float v = 0.f;
        if ((unsigned)ys < 128u && (unsigned)xs < 128u) v = src[(ys << 7) + xs];
        dst[i] = v;
    }
}

// ---------------------------------------------------------------------------
// SVC v2 (unchanged).
// ---------------------------------------------------------------------------
__global__ __launch_bounds__(256) void svc2_kernel(
    const float* __restrict__ khp, const float* __restrict__ attn,
    float* __restrict__ out) {
    __shared__ float a_s[KO * 64];
    const int tid = threadIdx.x;
    int by = blockIdx.y;
    by = (by & 7) * 128 + (by >> 3);
    const int b = by >> 7, y = by & 127;
    const int x0 = blockIdx.x * 64;

    for (int i = tid; i < KO * 64; i += 256) {
        int o = i >> 6, px = i & 63;
        a_s[i] = attn[(((size_t)b * KO + o) << 14) + (y << 7) + x0 + px];
    }
    __syncthreads();

    const int ci = tid >> 4, pxb = (tid & 15) << 2;
    const float* kb = khp + ((size_t)(b * 256 + ci) * KHP_H + y) * KHP_W + x0 + pxb;
    float* ob = out + (((size_t)b * 256 + ci) << 14) + (y << 7) + x0 + pxb;

    for (int grp = 0; grp < 4; ++grp) {
        f32x4 acc[4];
        f32x4 zero = {0.f, 0.f, 0.f, 0.f};
        #pragma unroll
        for (int k = 0; k < 4; ++k) acc[k] = zero;
        #pragma unroll
        for (int dy = 0; dy < 7; ++dy) {
            f32x4 av[7];
            #pragma unroll
            for (int dx = 0; dx < 7; ++dx)
                av[dx] = *(const f32x4*)&a_s[(dy * 7 + dx) * 64 + pxb];
            #pragma unroll
            for (int k = 0; k < 4; ++k) {
                const float* kr = kb + (size_t)(grp * 64 + k * 16) * KHP_PLANE + dy * KHP_W;
                f32x4 w0 = *(const f32x4*)(kr);
                f32x4 w1 = *(const f32x4*)(kr + 4);
                f32x4 w2 = *(const f32x4*)(kr + 8);
                float w[12] = {w0[0], w0[1], w0[2], w0[3],
                               w1[0], w1[1], w1[2], w1[3],
                               w2[0], w2[1], w2[2], w2[3]};
                #pragma unroll
                for (int dx = 0; dx < 7; ++dx) {
                    #pragma unroll
                    for (int j = 0; j < 4; ++j)
                        acc[k][j] = fmaf(w[dx + j + 1], av[dx][j], acc[k][j]);
                }
            }
        }
        #pragma unroll
        for (int k = 0; k < 4; ++k)
            *(f32x4*)&ob[(size_t)(grp * 64 + k * 16) << 14] = acc[k];
    }
}

// ---------------------------------------------------------------------------
extern "C" void kernel_launch(void* const* d_in, const int* in_sizes, int n_in,
                              void* d_out, int out_size, void* d_ws, size_t ws_size,
                              hipStream_t stream) {
    (void)in_sizes; (void)n_in; (void)out_size; (void)ws_size;
    const float* cur_low  = (const float*)d_in[0];
    const float* key_low  = (const float*)d_in[1];
    const float* key_high = (const float*)d_in[2];
    const float* w_red    = (const float*)d_in[3];
    const float* b_red    = (const float*)d_in[4];
    const float* w2       = (const float*)d_in[5];
    const float* b2       = (const float*)d_in[6];
    const float* w3       = (const float*)d_in[7];
    const float* b3       = (const float*)d_in[8];
    float* out = (float*)d_out;
    char* ws = (char*)d_ws;

    const size_t SZ_ATTN = (size_t)BN * KO * HN * WN * 4;
    const size_t SZ_XPAD = (size_t)BN * HP * HP * CLOW * 2;
    const size_t SZ_YPAD = (size_t)BN * HP * HP * CMID * 2;
    float* attn  = (float*)(ws);
    short* xpadc = (short*)(ws + SZ_ATTN);
    short* xpadk = (short*)(ws + SZ_ATTN + SZ_XPAD);
    short* x2    = (short*)(ws + SZ_ATTN);
    float* khp   = (float*)(ws + SZ_ATTN);
    short* ypadc = (short*)(ws + SZ_ATTN + 2 * SZ_XPAD);
    short* ypadk = (short*)(ws + SZ_ATTN + 2 * SZ_XPAD + SZ_YPAD);
    short* w1p   = (short*)(ws + SZ_ATTN + 2 * SZ_XPAD + 2 * SZ_YPAD);
    short* w2p   = (short*)((char*)w1p + (size_t)256 * 1152 * 2);

    hipFuncSetAttribute((const void*)conv2_8ph_kernel,
                        hipFuncAttributeMaxDynamicSharedMemorySize, 131072);

    zero_border_kernel<128><<<(8 * 516 * 16 + 255) / 256, 256, 0, stream>>>(xpadc);
    zero_border_kernel<128><<<(8 * 516 * 16 + 255) / 256, 256, 0, stream>>>(xpadk);
    zero_border_kernel<256><<<(8 * 516 * 32 + 255) / 256, 256, 0, stream>>>(ypadc);
    zero_border_kernel<256><<<(8 * 516 * 32 + 255) / 256, 256, 0, stream>>>(ypadk);

    convert_pad_kernel<<<dim3(1024, 2), 256, 0, stream>>>(cur_low, key_low, xpadc, xpadk);
    pack_w_kernel<128, 32><<<(256 * 1152) / 256, 256, 0, stream>>>(w_red, w1p);
    pack_w_kernel<512, 64><<<(256 * 4608) / 256, 256, 0, stream>>>(w2, w2p);

    conv1_kernel<<<dim3(1024, 2, 2), 256, 0, stream>>>(
        xpadc, xpadk, w1p, b_red, ypadc, ypadk);

    conv2_8ph_kernel<<<512, 512, 131072, stream>>>(ypadc, ypadk, w2p, b2, x2);

    conv3_softmax_kernel<<<512, 256, 0, stream>>>(x2, w3, b3, attn);

    pad_kh_kernel<<<2048, 256, 0, stream>>>(key_high, khp);
    svc2_kernel<<<dim3(2, 1024), 256, 0, stream>>>(khp, attn, out);
}

// Round 5
// 1011.861 us; speedup vs baseline: 1.7138x; 1.0532x over previous
//
#include <hip/hip_runtime.h>
#include <stdint.h>
#include <stddef.h>

#define BN   8
#define HN   128
#define WN   128
#define HP   130
#define CLOW 128
#define CMID 256
#define KO   49

// padded key_high: [b][c][134][140] fp32, khp[b][c][y+3][x+4] = kh[b][c][y][x]
#define KHP_H 134
#define KHP_W 140
#define KHP_PLANE (KHP_H * KHP_W)   // 18760 floats

typedef __attribute__((ext_vector_type(4))) float f32x4;
typedef __attribute__((ext_vector_type(8))) short bf16x8;

typedef __attribute__((address_space(1))) const uint8_t ga_u8;
typedef __attribute__((address_space(3))) uint8_t lds_u8;

__device__ __forceinline__ short f2bf(float f) {
    uint32_t u = __float_as_uint(f);
    u += 0x7fffu + ((u >> 16) & 1u);
    return (short)(u >> 16);
}
__device__ __forceinline__ float bf2f(short s) {
    return __uint_as_float(((uint32_t)(uint16_t)s) << 16);
}
__device__ __forceinline__ void gload16(const void* g, void* l) {
    __builtin_amdgcn_global_load_lds((ga_u8*)g, (lds_u8*)l, 16, 0, 0);
}

// ---------------------------------------------------------------------------
// Zero only the halo cells of a padded [b][130][130][C] bf16 buffer.
// ---------------------------------------------------------------------------
template <int C>
__global__ __launch_bounds__(256) void zero_border_kernel(short* __restrict__ buf) {
    constexpr int GP = C / 8;
    int t = blockIdx.x * 256 + threadIdx.x;
    int cell = t / GP, g = t - cell * GP;
    if (cell >= 8 * 516) return;
    int b = cell / 516, r = cell - b * 516;
    int y, x;
    if (r < 260) { y = (r >= 130) ? 129 : 0; x = (r >= 130) ? (r - 130) : r; }
    else { int j = r - 260; y = 1 + (j >> 1); x = (j & 1) ? 129 : 0; }
    uint4 z = {0u, 0u, 0u, 0u};
    *(uint4*)&buf[(((size_t)b * HP + y) * HP + x) * C + g * 8] = z;
}

// ---------------------------------------------------------------------------
// Convert NCHW fp32 -> zero-padded NHWC bf16 ([b][130][130][128]).
// ---------------------------------------------------------------------------
__global__ __launch_bounds__(256) void convert_pad_kernel(
    const float* __restrict__ src0, const float* __restrict__ src1,
    short* __restrict__ dst0, short* __restrict__ dst1) {
    __shared__ short t[128 * 132];
    const int tid = threadIdx.x;
    const int by = blockIdx.x;
    const int b = by >> 7, y = by & 127;
    const float* src = blockIdx.y ? src1 : src0;
    short* dst = blockIdx.y ? dst1 : dst0;
    for (int k = 0; k < 64; ++k) {
        int i = (k << 8) + tid;
        int c = i >> 7, x = i & 127;
        t[x * 132 + c] = f2bf(src[(((size_t)b * CLOW + c) * HN + y) * WN + x]);
    }
    __syncthreads();
    short* drow = dst + (((size_t)b * HP + (y + 1)) * HP + 1) * CLOW;
    for (int k = 0; k < 64; ++k) {
        int i = (k << 8) + tid;
        int x = i >> 7, c = i & 127;
        drow[x * CLOW + c] = t[x * 132 + c];
    }
}

// ---------------------------------------------------------------------------
// Pack conv weights OIHW fp32 -> tap-inner K order with CB-channel K-tiles:
// K-tile t: cb = t/9, tap = t%9; wp[cout][t*CB+j], cin = cb*CB + j.
// ---------------------------------------------------------------------------
template <int CIN, int CB>
__global__ __launch_bounds__(256) void pack_w_kernel(
    const float* __restrict__ w, short* __restrict__ wp) {
    constexpr int K = 9 * CIN;
    int i = blockIdx.x * 256 + threadIdx.x;
    if (i >= 256 * K) return;
    int cout = i / K;
    int r = i - cout * K;
    int t = r / CB;
    int j = r - t * CB;
    int cb = t / 9;
    int tap = t - cb * 9;
    int cin = cb * CB + j;
    wp[i] = f2bf(w[((size_t)cout * CIN + cin) * 9 + tap]);
}

// ---------------------------------------------------------------------------
// Unified 3x3-conv 256x256x(BK=64) 8-phase kernel (T2+T3+T4+T5 template).
// CIN=512: dual-source (concat conv2), grid (512,1,1), unpadded NHWC out.
// CIN=128: single-source conv1, blockIdx.z picks image, padded NHWC out.
// Tap-inner K order (cb = t/9, tap = t%9) keeps input re-reads L2-resident.
// M-tile = 2 image rows (256 px), N = 256 couts, 8 waves (2Mx4N), 128KB LDS.
// Lead-2 staging, vmcnt(8) per tile boundary only.
// ---------------------------------------------------------------------------
template <int CIN, bool OPAD>
__global__ __launch_bounds__(512, 2) void conv_8ph_kernel(
    const short* __restrict__ in_a, const short* __restrict__ in_b,
    const short* __restrict__ wp, const float* __restrict__ bias,
    short* __restrict__ out_a, short* __restrict__ out_b) {
    constexpr int K = 9 * CIN;
    constexpr int NT = K / 64;
    constexpr bool DUAL = (CIN == 512);
    constexpr int PST = DUAL ? 256 : CIN;          // per-source pixel ch stride
    extern __shared__ __align__(16) short lds[];   // 131072 B
    const int tid = threadIdx.x;
    int bx = blockIdx.x;
    bx = (bx & 7) * 64 + (bx >> 3);      // XCD swizzle (512 x-blocks, 8 XCDs)
    const int b = bx >> 6, y0 = (bx & 63) << 1;
    const short* inA = DUAL ? in_a : (blockIdx.z ? in_b : in_a);
    const short* inB = DUAL ? in_b : inA;
    short* out = (!DUAL && blockIdx.z) ? out_b : out_a;

    const int lane = tid & 63, wv = tid >> 6;
    const int wm = wv >> 2, wn = wv & 3;
    const int lr = lane & 15, lk = lane >> 4;

    const int rA = tid >> 3, cc = tid & 7;
    const int cs = cc ^ (rA & 7);
    const int pthrA0 = rA * PST + cs * 8;
    const int pthrA1 = (rA + 64) * PST + cs * 8;
    const int pthrB0 = rA * K + cs * 8;
    const int pthrB1 = (rA + 64) * K + cs * 8;
    const int dA0 = rA * 64 + cc * 8;
    const int dB0 = rA * 64 + cc * 8;

    const int arow = (wm * 128 + lr) * 64;
    const int brow = (wn * 64 + lr) * 64;
    const int cof0 = ((lk) ^ (lr & 7)) * 8;
    const int cof1 = ((4 + lk) ^ (lr & 7)) * 8;

    f32x4 acc[8][4];
    f32x4 zero = {0.f, 0.f, 0.f, 0.f};
    #pragma unroll
    for (int i = 0; i < 8; ++i)
        #pragma unroll
        for (int j = 0; j < 4; ++j) acc[i][j] = zero;

    auto STAGE2 = [&](int t2, int which, short* bufA, short* bufB) {
        const int cb = (t2 * 57) >> 9;       // t2/9 for t2<72
        const int tap = t2 - cb * 9;
        const int ch0v = cb << 6;            // 64-ch K-tiles
        const short* src = (!DUAL || ch0v < 256) ? inA : inB;
        const int ch0 = DUAL ? (ch0v & 255) : ch0v;
        const int ky = (tap * 11) >> 5;
        const int kx = tap - ky * 3;
        if (which == 0 || which == 2) {
            const int po = (which == 0) ? pthrA0 : pthrA1;
            const int doff = (which == 0) ? 0 : 64 * 64;
            const short* s0 = src + ((size_t)(b * HP + (y0 + ky)) * HP + kx) * PST + ch0;
            gload16(s0 + po, bufA + doff + dA0);
            gload16(s0 + (HP * PST) + po, bufA + 128 * 64 + doff + dA0);
        } else {
            const int h2 = (which == 1) ? 0 : 1;
            const short* sb = wp + (size_t)(h2 * 128) * K + t2 * 64;
            short* d = bufB + h2 * 128 * 64 + dB0;
            gload16(sb + pthrB0, d);
            gload16(sb + pthrB1, d + 64 * 64);
        }
    };

    auto LDA = [&](const short* bufA, int mh, bf16x8 (&a)[4][2]) {
        #pragma unroll
        for (int i = 0; i < 4; ++i) {
            const int ro = arow + (mh * 64 + i * 16) * 64;
            a[i][0] = *(const bf16x8*)(bufA + ro + cof0);
            a[i][1] = *(const bf16x8*)(bufA + ro + cof1);
        }
    };
    auto LDB = [&](const short* bufB, int nh, bf16x8 (&bb)[2][2]) {
        #pragma unroll
        for (int j = 0; j < 2; ++j) {
            const int ro = brow + (nh * 32 + j * 16) * 64;
            bb[j][0] = *(const bf16x8*)(bufB + ro + cof0);
            bb[j][1] = *(const bf16x8*)(bufB + ro + cof1);
        }
    };

#define PH_PRE() do { __builtin_amdgcn_sched_barrier(0); \
                      __builtin_amdgcn_s_barrier(); \
                      asm volatile("s_waitcnt lgkmcnt(0)" ::: "memory"); \
                      __builtin_amdgcn_sched_barrier(0); \
                      __builtin_amdgcn_s_setprio(1); } while (0)
#define PH_POST() do { __builtin_amdgcn_s_setprio(0); \
                       __builtin_amdgcn_sched_barrier(0); \
                       __builtin_amdgcn_s_barrier(); } while (0)
#define MFMA_Q(A_, B_, MH, NH) do { \
    _Pragma("unroll") \
    for (int i_ = 0; i_ < 4; ++i_) { \
        _Pragma("unroll") \
        for (int j_ = 0; j_ < 2; ++j_) { \
            acc[(MH)*4+i_][(NH)*2+j_] = __builtin_amdgcn_mfma_f32_16x16x32_bf16( \
                A_[i_][0], B_[j_][0], acc[(MH)*4+i_][(NH)*2+j_], 0, 0, 0); \
            acc[(MH)*4+i_][(NH)*2+j_] = __builtin_amdgcn_mfma_f32_16x16x32_bf16( \
                A_[i_][1], B_[j_][1], acc[(MH)*4+i_][(NH)*2+j_], 0, 0, 0); \
        } \
    } } while (0)

    short* const A0 = lds;
    short* const A1 = lds + 16384;
    short* const B0 = lds + 32768;
    short* const B1 = lds + 49152;

    STAGE2(0, 0, A0, B0); STAGE2(0, 1, A0, B0);
    STAGE2(0, 2, A0, B0); STAGE2(0, 3, A0, B0);
    STAGE2(1, 0, A1, B1); STAGE2(1, 1, A1, B1);
    STAGE2(1, 2, A1, B1); STAGE2(1, 3, A1, B1);
    asm volatile("s_waitcnt vmcnt(8)" ::: "memory");
    __builtin_amdgcn_sched_barrier(0);
    __builtin_amdgcn_s_barrier();

    auto TILE = [&](int t, short* bufA, short* bufB) {
        const int t2 = t + 2;
        const bool st = (t2 < NT);
        bf16x8 ar[4][2], br0[2][2], br1[2][2];
        // phase 0 (mh=0, nh=0)
        LDA(bufA, 0, ar);
        LDB(bufB, 0, br0);
        if (st) STAGE2(t2, 0, bufA, bufB);
        PH_PRE();
        MFMA_Q(ar, br0, 0, 0);
        PH_POST();
        // phase 1 (mh=0, nh=1)
        LDB(bufB, 1, br1);
        if (st) STAGE2(t2, 1, bufA, bufB);
        PH_PRE();
        MFMA_Q(ar, br1, 0, 1);
        PH_POST();
        // phase 2 (mh=1, nh=0)
        LDA(bufA, 1, ar);
        if (st) STAGE2(t2, 2, bufA, bufB);
        PH_PRE();
        MFMA_Q(ar, br0, 1, 0);
        PH_POST();
        // phase 3 (mh=1, nh=1)
        if (st) STAGE2(t2, 3, bufA, bufB);
        PH_PRE();
        MFMA_Q(ar, br1, 1, 1);
        __builtin_amdgcn_s_setprio(0);
        __builtin_amdgcn_sched_barrier(0);
        if (st)                asm volatile("s_waitcnt vmcnt(8)" ::: "memory");
        else if (t == NT - 2)  asm volatile("s_waitcnt vmcnt(0)" ::: "memory");
        __builtin_amdgcn_sched_barrier(0);
        __builtin_amdgcn_s_barrier();
    };

    for (int t = 0; t < NT; t += 2) {
        TILE(t,     A0, B0);
        TILE(t + 1, A1, B1);
    }
#undef PH_PRE
#undef PH_POST
#undef MFMA_Q

    // epilogue: nf-innermost store order (write-combining: 4 stores = 128B run)
    float bvs[4];
    #pragma unroll
    for (int nf = 0; nf < 4; ++nf) bvs[nf] = bias[wn * 64 + nf * 16 + lr];
    #pragma unroll
    for (int mf = 0; mf < 8; ++mf) {
        #pragma unroll
        for (int rr = 0; rr < 4; ++rr) {
            const int p = wm * 128 + mf * 16 + lk * 4 + rr;
            const int y = y0 + (p >> 7), x = p & 127;
            short* op;
            if (OPAD)
                op = out + ((size_t)(b * HP + (y + 1)) * HP + (x + 1)) * CMID + wn * 64 + lr;
            else
                op = out + ((size_t)((b * HN + y) * WN + x)) * CMID + wn * 64 + lr;
            #pragma unroll
            for (int nf = 0; nf < 4; ++nf)
                op[nf * 16] = f2bf(fmaxf(acc[mf][nf][rr] + bvs[nf], 0.f));
        }
    }
}

// ---------------------------------------------------------------------------
// 1x1 conv (256 -> 49) + ReLU + softmax (unchanged).
// ---------------------------------------------------------------------------
__global__ __launch_bounds__(256) void conv3_softmax_kernel(
    const short* __restrict__ x2, const float* __restrict__ w3,
    const float* __restrict__ b3, float* __restrict__ attn) {
    const int p = blockIdx.x * 256 + threadIdx.x;
    const int b = p >> 14, hw = p & 16383;
    float acc[KO];
    #pragma unroll
    for (int o = 0; o < KO; ++o) acc[o] = b3[o];
    const short* xp = x2 + (size_t)p * 256;
    #pragma unroll 1
    for (int c0 = 0; c0 < 256; c0 += 8) {
        bf16x8 xv = *(const bf16x8*)&xp[c0];
        float xf[8];
        #pragma unroll
        for (int j = 0; j < 8; ++j) xf[j] = bf2f(xv[j]);
        #pragma unroll
        for (int o = 0; o < KO; ++o) {
            const float* wr = w3 + o * 256 + c0;
            float s = acc[o];
            #pragma unroll
            for (int j = 0; j < 8; ++j) s = fmaf(xf[j], wr[j], s);
            acc[o] = s;
        }
    }
    #pragma unroll
    for (int o = 0; o < KO; ++o) acc[o] = fmaxf(acc[o], 0.f);
    float m = acc[0];
    #pragma unroll
    for (int o = 1; o < KO; ++o) m = fmaxf(m, acc[o]);
    float s = 0.f;
    #pragma unroll
    for (int o = 0; o < KO; ++o) { float e = __expf(acc[o] - m); acc[o] = e; s += e; }
    const float inv = 1.f / s;
    float* ap = attn + (size_t)b * KO * 16384 + hw;
    #pragma unroll
    for (int o = 0; o < KO; ++o) ap[(size_t)o * 16384] = acc[o] * inv;
}

// ---------------------------------------------------------------------------
// Pad key_high NCHW fp32 -> [b][c][134][140] with zero halo.
// ---------------------------------------------------------------------------
__global__ __launch_bounds__(256) void pad_kh_kernel(
    const float* __restrict__ kh, float* __restrict__ khp) {
    const int bc = blockIdx.x;
    const float* src = kh + (size_t)bc * (HN * WN);
    float* dst = khp + (size_t)bc * KHP_PLANE;
    for (int i = threadIdx.x; i < KHP_PLANE; i += 256) {
        int yy = i / KHP_W;
        int xx = i - yy * KHP_W;
        int ys = yy - 3, xs = xx - 4;
        float v = 0.f;
        if ((unsigned)ys < 128u && (unsigned)xs < 128u) v = src[(ys << 7) + xs];
        dst[i] = v;
    }
}

// ---------------------------------------------------------------------------
// SVC v2 (unchanged).
// ---------------------------------------------------------------------------
__global__ __launch_bounds__(256) void svc2_kernel(
    const float* __restrict__ khp, const float* __restrict__ attn,
    float* __restrict__ out) {
    __shared__ float a_s[KO * 64];
    const int tid = threadIdx.x;
    int by = blockIdx.y;
    by = (by & 7) * 128 + (by >> 3);
    const int b = by >> 7, y = by & 127;
    const int x0 = blockIdx.x * 64;

    for (int i = tid; i < KO * 64; i += 256) {
        int o = i >> 6, px = i & 63;
        a_s[i] = attn[(((size_t)b * KO + o) << 14) + (y << 7) + x0 + px];
    }
    __syncthreads();

    const int ci = tid >> 4, pxb = (tid & 15) << 2;
    const float* kb = khp + ((size_t)(b * 256 + ci) * KHP_H + y) * KHP_W + x0 + pxb;
    float* ob = out + (((size_t)b * 256 + ci) << 14) + (y << 7) + x0 + pxb;

    for (int grp = 0; grp < 4; ++grp) {
        f32x4 acc[4];
        f32x4 zero = {0.f, 0.f, 0.f, 0.f};
        #pragma unroll
        for (int k = 0; k < 4; ++k) acc[k] = zero;
        #pragma unroll
        for (int dy = 0; dy < 7; ++dy) {
            f32x4 av[7];
            #pragma unroll
            for (int dx = 0; dx < 7; ++dx)
                av[dx] = *(const f32x4*)&a_s[(dy * 7 + dx) * 64 + pxb];
            #pragma unroll
            for (int k = 0; k < 4; ++k) {
                const float* kr = kb + (size_t)(grp * 64 + k * 16) * KHP_PLANE + dy * KHP_W;
                f32x4 w0 = *(const f32x4*)(kr);
                f32x4 w1 = *(const f32x4*)(kr + 4);
                f32x4 w2 = *(const f32x4*)(kr + 8);
                float w[12] = {w0[0], w0[1], w0[2], w0[3],
                               w1[0], w1[1], w1[2], w1[3],
                               w2[0], w2[1], w2[2], w2[3]};
                #pragma unroll
                for (int dx = 0; dx < 7; ++dx) {
                    #pragma unroll
                    for (int j = 0; j < 4; ++j)
                        acc[k][j] = fmaf(w[dx + j + 1], av[dx][j], acc[k][j]);
                }
            }
        }
        #pragma unroll
        for (int k = 0; k < 4; ++k)
            *(f32x4*)&ob[(size_t)(grp * 64 + k * 16) << 14] = acc[k];
    }
}

// ---------------------------------------------------------------------------
extern "C" void kernel_launch(void* const* d_in, const int* in_sizes, int n_in,
                              void* d_out, int out_size, void* d_ws, size_t ws_size,
                              hipStream_t stream) {
    (void)in_sizes; (void)n_in; (void)out_size; (void)ws_size;
    const float* cur_low  = (const float*)d_in[0];
    const float* key_low  = (const float*)d_in[1];
    const float* key_high = (const float*)d_in[2];
    const float* w_red    = (const float*)d_in[3];
    const float* b_red    = (const float*)d_in[4];
    const float* w2       = (const float*)d_in[5];
    const float* b2       = (const float*)d_in[6];
    const float* w3       = (const float*)d_in[7];
    const float* b3       = (const float*)d_in[8];
    float* out = (float*)d_out;
    char* ws = (char*)d_ws;

    const size_t SZ_ATTN = (size_t)BN * KO * HN * WN * 4;
    const size_t SZ_XPAD = (size_t)BN * HP * HP * CLOW * 2;
    const size_t SZ_YPAD = (size_t)BN * HP * HP * CMID * 2;
    float* attn  = (float*)(ws);
    short* xpadc = (short*)(ws + SZ_ATTN);
    short* xpadk = (short*)(ws + SZ_ATTN + SZ_XPAD);
    short* x2    = (short*)(ws + SZ_ATTN);
    float* khp   = (float*)(ws + SZ_ATTN);
    short* ypadc = (short*)(ws + SZ_ATTN + 2 * SZ_XPAD);
    short* ypadk = (short*)(ws + SZ_ATTN + 2 * SZ_XPAD + SZ_YPAD);
    short* w1p   = (short*)(ws + SZ_ATTN + 2 * SZ_XPAD + 2 * SZ_YPAD);
    short* w2p   = (short*)((char*)w1p + (size_t)256 * 1152 * 2);

    hipFuncSetAttribute((const void*)conv_8ph_kernel<128, true>,
                        hipFuncAttributeMaxDynamicSharedMemorySize, 131072);
    hipFuncSetAttribute((const void*)conv_8ph_kernel<512, false>,
                        hipFuncAttributeMaxDynamicSharedMemorySize, 131072);

    zero_border_kernel<128><<<(8 * 516 * 16 + 255) / 256, 256, 0, stream>>>(xpadc);
    zero_border_kernel<128><<<(8 * 516 * 16 + 255) / 256, 256, 0, stream>>>(xpadk);
    zero_border_kernel<256><<<(8 * 516 * 32 + 255) / 256, 256, 0, stream>>>(ypadc);
    zero_border_kernel<256><<<(8 * 516 * 32 + 255) / 256, 256, 0, stream>>>(ypadk);

    convert_pad_kernel<<<dim3(1024, 2), 256, 0, stream>>>(cur_low, key_low, xpadc, xpadk);
    pack_w_kernel<128, 64><<<(256 * 1152) / 256, 256, 0, stream>>>(w_red, w1p);
    pack_w_kernel<512, 64><<<(256 * 4608) / 256, 256, 0, stream>>>(w2, w2p);

    conv_8ph_kernel<128, true><<<dim3(512, 1, 2), 512, 131072, stream>>>(
        xpadc, xpadk, w1p, b_red, ypadc, ypadk);

    conv_8ph_kernel<512, false><<<dim3(512, 1, 1), 512, 131072, stream>>>(
        ypadc, ypadk, w2p, b2, x2, x2);

    conv3_softmax_kernel<<<512, 256, 0, stream>>>(x2, w3, b3, attn);

    pad_kh_kernel<<<2048, 256, 0, stream>>>(key_high, khp);
    svc2_kernel<<<dim3(2, 1024), 256, 0, stream>>>(khp, attn, out);
}

// Round 6
// 894.478 us; speedup vs baseline: 1.9387x; 1.1312x over previous
//
#include <hip/hip_runtime.h>
#include <stdint.h>
#include <stddef.h>

#define BN   8
#define HN   128
#define WN   128
#define HP   130
#define CLOW 128
#define CMID 256
#define KO   49

// padded key_high (bf16): [b][c][134][144], khb[b][c][y+3][x+4] = kh[b][c][y][x]
#define KHB_H 134
#define KHB_W 144
#define KHB_PLANE (KHB_H * KHB_W)   // 19296 shorts

typedef __attribute__((ext_vector_type(4))) float f32x4;
typedef __attribute__((ext_vector_type(8))) short bf16x8;

typedef __attribute__((address_space(1))) const uint8_t ga_u8;
typedef __attribute__((address_space(3))) uint8_t lds_u8;

__device__ __forceinline__ short f2bf(float f) {
    uint32_t u = __float_as_uint(f);
    u += 0x7fffu + ((u >> 16) & 1u);
    return (short)(u >> 16);
}
__device__ __forceinline__ float bf2f(short s) {
    return __uint_as_float(((uint32_t)(uint16_t)s) << 16);
}
__device__ __forceinline__ void gload16(const void* g, void* l) {
    __builtin_amdgcn_global_load_lds((ga_u8*)g, (lds_u8*)l, 16, 0, 0);
}

// ---------------------------------------------------------------------------
// Zero only the halo cells of a padded [b][130][130][C] bf16 buffer.
// ---------------------------------------------------------------------------
template <int C>
__global__ __launch_bounds__(256) void zero_border_kernel(short* __restrict__ buf) {
    constexpr int GP = C / 8;
    int t = blockIdx.x * 256 + threadIdx.x;
    int cell = t / GP, g = t - cell * GP;
    if (cell >= 8 * 516) return;
    int b = cell / 516, r = cell - b * 516;
    int y, x;
    if (r < 260) { y = (r >= 130) ? 129 : 0; x = (r >= 130) ? (r - 130) : r; }
    else { int j = r - 260; y = 1 + (j >> 1); x = (j & 1) ? 129 : 0; }
    uint4 z = {0u, 0u, 0u, 0u};
    *(uint4*)&buf[(((size_t)b * HP + y) * HP + x) * C + g * 8] = z;
}

// ---------------------------------------------------------------------------
// Convert NCHW fp32 -> zero-padded NHWC bf16 ([b][130][130][128]).
// ---------------------------------------------------------------------------
__global__ __launch_bounds__(256) void convert_pad_kernel(
    const float* __restrict__ src0, const float* __restrict__ src1,
    short* __restrict__ dst0, short* __restrict__ dst1) {
    __shared__ short t[128 * 132];
    const int tid = threadIdx.x;
    const int by = blockIdx.x;
    const int b = by >> 7, y = by & 127;
    const float* src = blockIdx.y ? src1 : src0;
    short* dst = blockIdx.y ? dst1 : dst0;
    for (int k = 0; k < 64; ++k) {
        int i = (k << 8) + tid;
        int c = i >> 7, x = i & 127;
        t[x * 132 + c] = f2bf(src[(((size_t)b * CLOW + c) * HN + y) * WN + x]);
    }
    __syncthreads();
    short* drow = dst + (((size_t)b * HP + (y + 1)) * HP + 1) * CLOW;
    for (int k = 0; k < 64; ++k) {
        int i = (k << 8) + tid;
        int x = i >> 7, c = i & 127;
        drow[x * CLOW + c] = t[x * 132 + c];
    }
}

// ---------------------------------------------------------------------------
// Pack conv weights OIHW fp32 -> tap-inner K order with CB-channel K-tiles:
// K-tile t: cb = t/9, tap = t%9; wp[cout][t*CB+j], cin = cb*CB + j.
// ---------------------------------------------------------------------------
template <int CIN, int CB>
__global__ __launch_bounds__(256) void pack_w_kernel(
    const float* __restrict__ w, short* __restrict__ wp) {
    constexpr int K = 9 * CIN;
    int i = blockIdx.x * 256 + threadIdx.x;
    if (i >= 256 * K) return;
    int cout = i / K;
    int r = i - cout * K;
    int t = r / CB;
    int j = r - t * CB;
    int cb = t / 9;
    int tap = t - cb * 9;
    int cin = cb * CB + j;
    wp[i] = f2bf(w[((size_t)cout * CIN + cin) * 9 + tap]);
}

// ---------------------------------------------------------------------------
// Unified 3x3-conv 256x256x(BK=64) 8-phase kernel (unchanged from round 5).
// ---------------------------------------------------------------------------
template <int CIN, bool OPAD>
__global__ __launch_bounds__(512, 2) void conv_8ph_kernel(
    const short* __restrict__ in_a, const short* __restrict__ in_b,
    const short* __restrict__ wp, const float* __restrict__ bias,
    short* __restrict__ out_a, short* __restrict__ out_b) {
    constexpr int K = 9 * CIN;
    constexpr int NT = K / 64;
    constexpr bool DUAL = (CIN == 512);
    constexpr int PST = DUAL ? 256 : CIN;
    extern __shared__ __align__(16) short lds[];   // 131072 B
    const int tid = threadIdx.x;
    int bx = blockIdx.x;
    bx = (bx & 7) * 64 + (bx >> 3);
    const int b = bx >> 6, y0 = (bx & 63) << 1;
    const short* inA = DUAL ? in_a : (blockIdx.z ? in_b : in_a);
    const short* inB = DUAL ? in_b : inA;
    short* out = (!DUAL && blockIdx.z) ? out_b : out_a;

    const int lane = tid & 63, wv = tid >> 6;
    const int wm = wv >> 2, wn = wv & 3;
    const int lr = lane & 15, lk = lane >> 4;

    const int rA = tid >> 3, cc = tid & 7;
    const int cs = cc ^ (rA & 7);
    const int pthrA0 = rA * PST + cs * 8;
    const int pthrA1 = (rA + 64) * PST + cs * 8;
    const int pthrB0 = rA * K + cs * 8;
    const int pthrB1 = (rA + 64) * K + cs * 8;
    const int dA0 = rA * 64 + cc * 8;
    const int dB0 = rA * 64 + cc * 8;

    const int arow = (wm * 128 + lr) * 64;
    const int brow = (wn * 64 + lr) * 64;
    const int cof0 = ((lk) ^ (lr & 7)) * 8;
    const int cof1 = ((4 + lk) ^ (lr & 7)) * 8;

    f32x4 acc[8][4];
    f32x4 zero = {0.f, 0.f, 0.f, 0.f};
    #pragma unroll
    for (int i = 0; i < 8; ++i)
        #pragma unroll
        for (int j = 0; j < 4; ++j) acc[i][j] = zero;

    auto STAGE2 = [&](int t2, int which, short* bufA, short* bufB) {
        const int cb = (t2 * 57) >> 9;
        const int tap = t2 - cb * 9;
        const int ch0v = cb << 6;
        const short* src = (!DUAL || ch0v < 256) ? inA : inB;
        const int ch0 = DUAL ? (ch0v & 255) : ch0v;
        const int ky = (tap * 11) >> 5;
        const int kx = tap - ky * 3;
        if (which == 0 || which == 2) {
            const int po = (which == 0) ? pthrA0 : pthrA1;
            const int doff = (which == 0) ? 0 : 64 * 64;
            const short* s0 = src + ((size_t)(b * HP + (y0 + ky)) * HP + kx) * PST + ch0;
            gload16(s0 + po, bufA + doff + dA0);
            gload16(s0 + (HP * PST) + po, bufA + 128 * 64 + doff + dA0);
        } else {
            const int h2 = (which == 1) ? 0 : 1;
            const short* sb = wp + (size_t)(h2 * 128) * K + t2 * 64;
            short* d = bufB + h2 * 128 * 64 + dB0;
            gload16(sb + pthrB0, d);
            gload16(sb + pthrB1, d + 64 * 64);
        }
    };

    auto LDA = [&](const short* bufA, int mh, bf16x8 (&a)[4][2]) {
        #pragma unroll
        for (int i = 0; i < 4; ++i) {
            const int ro = arow + (mh * 64 + i * 16) * 64;
            a[i][0] = *(const bf16x8*)(bufA + ro + cof0);
            a[i][1] = *(const bf16x8*)(bufA + ro + cof1);
        }
    };
    auto LDB = [&](const short* bufB, int nh, bf16x8 (&bb)[2][2]) {
        #pragma unroll
        for (int j = 0; j < 2; ++j) {
            const int ro = brow + (nh * 32 + j * 16) * 64;
            bb[j][0] = *(const bf16x8*)(bufB + ro + cof0);
            bb[j][1] = *(const bf16x8*)(bufB + ro + cof1);
        }
    };

#define PH_PRE() do { __builtin_amdgcn_sched_barrier(0); \
                      __builtin_amdgcn_s_barrier(); \
                      asm volatile("s_waitcnt lgkmcnt(0)" ::: "memory"); \
                      __builtin_amdgcn_sched_barrier(0); \
                      __builtin_amdgcn_s_setprio(1); } while (0)
#define PH_POST() do { __builtin_amdgcn_s_setprio(0); \
                       __builtin_amdgcn_sched_barrier(0); \
                       __builtin_amdgcn_s_barrier(); } while (0)
#define MFMA_Q(A_, B_, MH, NH) do { \
    _Pragma("unroll") \
    for (int i_ = 0; i_ < 4; ++i_) { \
        _Pragma("unroll") \
        for (int j_ = 0; j_ < 2; ++j_) { \
            acc[(MH)*4+i_][(NH)*2+j_] = __builtin_amdgcn_mfma_f32_16x16x32_bf16( \
                A_[i_][0], B_[j_][0], acc[(MH)*4+i_][(NH)*2+j_], 0, 0, 0); \
            acc[(MH)*4+i_][(NH)*2+j_] = __builtin_amdgcn_mfma_f32_16x16x32_bf16( \
                A_[i_][1], B_[j_][1], acc[(MH)*4+i_][(NH)*2+j_], 0, 0, 0); \
        } \
    } } while (0)

    short* const A0 = lds;
    short* const A1 = lds + 16384;
    short* const B0 = lds + 32768;
    short* const B1 = lds + 49152;

    STAGE2(0, 0, A0, B0); STAGE2(0, 1, A0, B0);
    STAGE2(0, 2, A0, B0); STAGE2(0, 3, A0, B0);
    STAGE2(1, 0, A1, B1); STAGE2(1, 1, A1, B1);
    STAGE2(1, 2, A1, B1); STAGE2(1, 3, A1, B1);
    asm volatile("s_waitcnt vmcnt(8)" ::: "memory");
    __builtin_amdgcn_sched_barrier(0);
    __builtin_amdgcn_s_barrier();

    auto TILE = [&](int t, short* bufA, short* bufB) {
        const int t2 = t + 2;
        const bool st = (t2 < NT);
        bf16x8 ar[4][2], br0[2][2], br1[2][2];
        LDA(bufA, 0, ar);
        LDB(bufB, 0, br0);
        if (st) STAGE2(t2, 0, bufA, bufB);
        PH_PRE();
        MFMA_Q(ar, br0, 0, 0);
        PH_POST();
        LDB(bufB, 1, br1);
        if (st) STAGE2(t2, 1, bufA, bufB);
        PH_PRE();
        MFMA_Q(ar, br1, 0, 1);
        PH_POST();
        LDA(bufA, 1, ar);
        if (st) STAGE2(t2, 2, bufA, bufB);
        PH_PRE();
        MFMA_Q(ar, br0, 1, 0);
        PH_POST();
        if (st) STAGE2(t2, 3, bufA, bufB);
        PH_PRE();
        MFMA_Q(ar, br1, 1, 1);
        __builtin_amdgcn_s_setprio(0);
        __builtin_amdgcn_sched_barrier(0);
        if (st)                asm volatile("s_waitcnt vmcnt(8)" ::: "memory");
        else if (t == NT - 2)  asm volatile("s_waitcnt vmcnt(0)" ::: "memory");
        __builtin_amdgcn_sched_barrier(0);
        __builtin_amdgcn_s_barrier();
    };

    for (int t = 0; t < NT; t += 2) {
        TILE(t,     A0, B0);
        TILE(t + 1, A1, B1);
    }
#undef PH_PRE
#undef PH_POST
#undef MFMA_Q

    float bvs[4];
    #pragma unroll
    for (int nf = 0; nf < 4; ++nf) bvs[nf] = bias[wn * 64 + nf * 16 + lr];
    #pragma unroll
    for (int mf = 0; mf < 8; ++mf) {
        #pragma unroll
        for (int rr = 0; rr < 4; ++rr) {
            const int p = wm * 128 + mf * 16 + lk * 4 + rr;
            const int y = y0 + (p >> 7), x = p & 127;
            short* op;
            if (OPAD)
                op = out + ((size_t)(b * HP + (y + 1)) * HP + (x + 1)) * CMID + wn * 64 + lr;
            else
                op = out + ((size_t)((b * HN + y) * WN + x)) * CMID + wn * 64 + lr;
            #pragma unroll
            for (int nf = 0; nf < 4; ++nf)
                op[nf * 16] = f2bf(fmaxf(acc[mf][nf][rr] + bvs[nf], 0.f));
        }
    }
}

// ---------------------------------------------------------------------------
// 1x1 conv (256 -> 49) + ReLU + softmax (unchanged).
// ---------------------------------------------------------------------------
__global__ __launch_bounds__(256) void conv3_softmax_kernel(
    const short* __restrict__ x2, const float* __restrict__ w3,
    const float* __restrict__ b3, float* __restrict__ attn) {
    const int p = blockIdx.x * 256 + threadIdx.x;
    const int b = p >> 14, hw = p & 16383;
    float acc[KO];
    #pragma unroll
    for (int o = 0; o < KO; ++o) acc[o] = b3[o];
    const short* xp = x2 + (size_t)p * 256;
    #pragma unroll 1
    for (int c0 = 0; c0 < 256; c0 += 8) {
        bf16x8 xv = *(const bf16x8*)&xp[c0];
        float xf[8];
        #pragma unroll
        for (int j = 0; j < 8; ++j) xf[j] = bf2f(xv[j]);
        #pragma unroll
        for (int o = 0; o < KO; ++o) {
            const float* wr = w3 + o * 256 + c0;
            float s = acc[o];
            #pragma unroll
            for (int j = 0; j < 8; ++j) s = fmaf(xf[j], wr[j], s);
            acc[o] = s;
        }
    }
    #pragma unroll
    for (int o = 0; o < KO; ++o) acc[o] = fmaxf(acc[o], 0.f);
    float m = acc[0];
    #pragma unroll
    for (int o = 1; o < KO; ++o) m = fmaxf(m, acc[o]);
    float s = 0.f;
    #pragma unroll
    for (int o = 0; o < KO; ++o) { float e = __expf(acc[o] - m); acc[o] = e; s += e; }
    const float inv = 1.f / s;
    float* ap = attn + (size_t)b * KO * 16384 + hw;
    #pragma unroll
    for (int o = 0; o < KO; ++o) ap[(size_t)o * 16384] = acc[o] * inv;
}

// ---------------------------------------------------------------------------
// Pad key_high NCHW fp32 -> bf16 [b][c][134][144] with zero halo
// (khb[b][c][y+3][x+4] = kh[b][c][y][x]); 16B-aligned vector stores.
// ---------------------------------------------------------------------------
__global__ __launch_bounds__(256) void pad_kh_kernel(
    const float* __restrict__ kh, short* __restrict__ khb) {
    const int bc = blockIdx.x;
    const float* src = kh + (size_t)bc * (HN * WN);
    short* dst = khb + (size_t)bc * KHB_PLANE;
    for (int i = threadIdx.x; i < KHB_H * (KHB_W / 8); i += 256) {
        int yy = i / (KHB_W / 8);
        int g = i - yy * (KHB_W / 8);
        int ys = yy - 3;
        bf16x8 v;
        #pragma unroll
        for (int t = 0; t < 8; ++t) {
            int xs = g * 8 + t - 4;
            float f = 0.f;
            if ((unsigned)ys < 128u && (unsigned)xs < 128u) f = src[(ys << 7) + xs];
            v[t] = f2bf(f);
        }
        *(bf16x8*)&dst[yy * KHB_W + g * 8] = v;
    }
}

// ---------------------------------------------------------------------------
// SVC v3: dy-outer / channel-inner, bf16 kh, 8 px per thread.
// Block = (b, y, 64-px xseg); thread = (ci 0..31, pg 0..7). Per dy: attn row
// (14 x f32x4) loaded once into regs, reused by 8 channels (ci + 32*c);
// per (dy, ch): one 16-bf16 window (2 x 16B loads) -> 56 static FMAs.
// 28 B/px-ch global traffic (3x less than v2), 98 ds_b128/thread.
// ---------------------------------------------------------------------------
__global__ __launch_bounds__(256) void svc3_kernel(
    const short* __restrict__ khb, const float* __restrict__ attn,
    float* __restrict__ out) {
    __shared__ float a_s[KO * 64];
    const int tid = threadIdx.x;
    int by = blockIdx.y;
    by = (by & 7) * 128 + (by >> 3);       // XCD swizzle: XCD i -> batch i
    const int b = by >> 7, y = by & 127;
    const int x0 = blockIdx.x * 64;

    for (int i = tid; i < KO * 64; i += 256) {
        int o = i >> 6, px = i & 63;
        a_s[i] = attn[(((size_t)b * KO + o) << 14) + (y << 7) + x0 + px];
    }
    __syncthreads();

    const int ci = tid >> 3;               // 0..31
    const int pg = tid & 7;                // 0..7
    const int p0 = x0 + pg * 8;

    float acc[8][8];
    #pragma unroll
    for (int c = 0; c < 8; ++c)
        #pragma unroll
        for (int j = 0; j < 8; ++j) acc[c][j] = 0.f;

    // khb row y corresponds to kh row y-3 (dy=0); khb x = kh x + 4.
    // Window regs win[0..15] = khb x in [p0, p0+16) = kh x in [p0-4, p0+12).
    // out px p0+j needs kh x = p0+j+dx-3 -> win index j+dx+1 in [1,14].
    const short* kbase = khb + (((size_t)b * 256 + ci) * KHB_H + y) * KHB_W + p0;

    #pragma unroll 1
    for (int dy = 0; dy < 7; ++dy) {
        f32x4 av[14];
        #pragma unroll
        for (int dx = 0; dx < 7; ++dx) {
            av[dx * 2]     = *(const f32x4*)&a_s[(dy * 7 + dx) * 64 + pg * 8];
            av[dx * 2 + 1] = *(const f32x4*)&a_s[(dy * 7 + dx) * 64 + pg * 8 + 4];
        }
        const short* krow = kbase + dy * KHB_W;
        #pragma unroll
        for (int c = 0; c < 8; ++c) {
            const short* kp = krow + (size_t)c * 32 * KHB_PLANE;
            bf16x8 k0 = *(const bf16x8*)(kp);
            bf16x8 k1 = *(const bf16x8*)(kp + 8);
            float win[16];
            #pragma unroll
            for (int t = 0; t < 8; ++t) { win[t] = bf2f(k0[t]); win[t + 8] = bf2f(k1[t]); }
            #pragma unroll
            for (int dx = 0; dx < 7; ++dx) {
                #pragma unroll
                for (int j = 0; j < 8; ++j)
                    acc[c][j] = fmaf(win[j + dx + 1], av[dx * 2 + (j >> 2)][j & 3],
                                     acc[c][j]);
            }
        }
    }

    #pragma unroll
    for (int c = 0; c < 8; ++c) {
        float* op = out + (((size_t)b * 256 + ci + c * 32) << 14) + (y << 7) + p0;
        f32x4 r0 = {acc[c][0], acc[c][1], acc[c][2], acc[c][3]};
        f32x4 r1 = {acc[c][4], acc[c][5], acc[c][6], acc[c][7]};
        *(f32x4*)op = r0;
        *(f32x4*)(op + 4) = r1;
    }
}

// ---------------------------------------------------------------------------
extern "C" void kernel_launch(void* const* d_in, const int* in_sizes, int n_in,
                              void* d_out, int out_size, void* d_ws, size_t ws_size,
                              hipStream_t stream) {
    (void)in_sizes; (void)n_in; (void)out_size; (void)ws_size;
    const float* cur_low  = (const float*)d_in[0];
    const float* key_low  = (const float*)d_in[1];
    const float* key_high = (const float*)d_in[2];
    const float* w_red    = (const float*)d_in[3];
    const float* b_red    = (const float*)d_in[4];
    const float* w2       = (const float*)d_in[5];
    const float* b2       = (const float*)d_in[6];
    const float* w3       = (const float*)d_in[7];
    const float* b3       = (const float*)d_in[8];
    float* out = (float*)d_out;
    char* ws = (char*)d_ws;

    const size_t SZ_ATTN = (size_t)BN * KO * HN * WN * 4;
    const size_t SZ_XPAD = (size_t)BN * HP * HP * CLOW * 2;
    const size_t SZ_YPAD = (size_t)BN * HP * HP * CMID * 2;
    float* attn  = (float*)(ws);
    short* xpadc = (short*)(ws + SZ_ATTN);
    short* xpadk = (short*)(ws + SZ_ATTN + SZ_XPAD);
    short* x2    = (short*)(ws + SZ_ATTN);
    short* khb   = (short*)(ws + SZ_ATTN);   // bf16 khb reuses x2 region (79 MB)
    short* ypadc = (short*)(ws + SZ_ATTN + 2 * SZ_XPAD);
    short* ypadk = (short*)(ws + SZ_ATTN + 2 * SZ_XPAD + SZ_YPAD);
    short* w1p   = (short*)(ws + SZ_ATTN + 2 * SZ_XPAD + 2 * SZ_YPAD);
    short* w2p   = (short*)((char*)w1p + (size_t)256 * 1152 * 2);

    hipFuncSetAttribute((const void*)conv_8ph_kernel<128, true>,
                        hipFuncAttributeMaxDynamicSharedMemorySize, 131072);
    hipFuncSetAttribute((const void*)conv_8ph_kernel<512, false>,
                        hipFuncAttributeMaxDynamicSharedMemorySize, 131072);

    zero_border_kernel<128><<<(8 * 516 * 16 + 255) / 256, 256, 0, stream>>>(xpadc);
    zero_border_kernel<128><<<(8 * 516 * 16 + 255) / 256, 256, 0, stream>>>(xpadk);
    zero_border_kernel<256><<<(8 * 516 * 32 + 255) / 256, 256, 0, stream>>>(ypadc);
    zero_border_kernel<256><<<(8 * 516 * 32 + 255) / 256, 256, 0, stream>>>(ypadk);

    convert_pad_kernel<<<dim3(1024, 2), 256, 0, stream>>>(cur_low, key_low, xpadc, xpadk);
    pack_w_kernel<128, 64><<<(256 * 1152) / 256, 256, 0, stream>>>(w_red, w1p);
    pack_w_kernel<512, 64><<<(256 * 4608) / 256, 256, 0, stream>>>(w2, w2p);

    conv_8ph_kernel<128, true><<<dim3(512, 1, 2), 512, 131072, stream>>>(
        xpadc, xpadk, w1p, b_red, ypadc, ypadk);

    conv_8ph_kernel<512, false><<<dim3(512, 1, 1), 512, 131072, stream>>>(
        ypadc, ypadk, w2p, b2, x2, x2);

    conv3_softmax_kernel<<<512, 256, 0, stream>>>(x2, w3, b3, attn);

    pad_kh_kernel<<<2048, 256, 0, stream>>>(key_high, khb);
    svc3_kernel<<<dim3(2, 1024), 256, 0, stream>>>(khb, attn, out);
}

// Round 7
// 844.715 us; speedup vs baseline: 2.0529x; 1.0589x over previous
//
#include <hip/hip_runtime.h>
#include <stdint.h>
#include <stddef.h>

#define BN   8
#define HN   128
#define WN   128
#define HP   130
#define CLOW 128
#define CMID 256
#define KO   49

// padded key_high (bf16): [b][c][134][144], khb[b][c][y+3][x+4] = kh[b][c][y][x]
#define KHB_H 134
#define KHB_W 144
#define KHB_PLANE (KHB_H * KHB_W)   // 19296 shorts

typedef __attribute__((ext_vector_type(4))) float f32x4;
typedef __attribute__((ext_vector_type(8))) short bf16x8;

typedef __attribute__((address_space(1))) const uint8_t ga_u8;
typedef __attribute__((address_space(3))) uint8_t lds_u8;

__device__ __forceinline__ short f2bf(float f) {
    uint32_t u = __float_as_uint(f);
    u += 0x7fffu + ((u >> 16) & 1u);
    return (short)(u >> 16);
}
__device__ __forceinline__ float bf2f(short s) {
    return __uint_as_float(((uint32_t)(uint16_t)s) << 16);
}
__device__ __forceinline__ void gload16(const void* g, void* l) {
    __builtin_amdgcn_global_load_lds((ga_u8*)g, (lds_u8*)l, 16, 0, 0);
}

// ---------------------------------------------------------------------------
// Zero halo cells of all four padded [b][130][130][C] bf16 buffers in one
// launch. blockIdx.y picks buffer (0,1: C=128; 2,3: C=256).
// ---------------------------------------------------------------------------
__global__ __launch_bounds__(256) void zero_border_all_kernel(
    short* __restrict__ b0, short* __restrict__ b1,
    short* __restrict__ b2, short* __restrict__ b3) {
    const int which = blockIdx.y;
    short* buf = (which == 0) ? b0 : (which == 1) ? b1 : (which == 2) ? b2 : b3;
    const int gsh = (which < 2) ? 4 : 5;           // groups per cell = C/8
    const int C = (which < 2) ? 128 : 256;
    int t = blockIdx.x * 256 + threadIdx.x;
    int cell = t >> gsh, g = t & ((1 << gsh) - 1);
    if (cell >= 8 * 516) return;
    int b = cell / 516, r = cell - b * 516;
    int y, x;
    if (r < 260) { y = (r >= 130) ? 129 : 0; x = (r >= 130) ? (r - 130) : r; }
    else { int j = r - 260; y = 1 + (j >> 1); x = (j & 1) ? 129 : 0; }
    uint4 z = {0u, 0u, 0u, 0u};
    *(uint4*)&buf[(((size_t)b * HP + y) * HP + x) * C + g * 8] = z;
}

// ---------------------------------------------------------------------------
// Convert NCHW fp32 -> zero-padded NHWC bf16 ([b][130][130][128]).
// ---------------------------------------------------------------------------
__global__ __launch_bounds__(256) void convert_pad_kernel(
    const float* __restrict__ src0, const float* __restrict__ src1,
    short* __restrict__ dst0, short* __restrict__ dst1) {
    __shared__ short t[128 * 132];
    const int tid = threadIdx.x;
    const int by = blockIdx.x;
    const int b = by >> 7, y = by & 127;
    const float* src = blockIdx.y ? src1 : src0;
    short* dst = blockIdx.y ? dst1 : dst0;
    for (int k = 0; k < 64; ++k) {
        int i = (k << 8) + tid;
        int c = i >> 7, x = i & 127;
        t[x * 132 + c] = f2bf(src[(((size_t)b * CLOW + c) * HN + y) * WN + x]);
    }
    __syncthreads();
    short* drow = dst + (((size_t)b * HP + (y + 1)) * HP + 1) * CLOW;
    for (int k = 0; k < 64; ++k) {
        int i = (k << 8) + tid;
        int x = i >> 7, c = i & 127;
        drow[x * CLOW + c] = t[x * 132 + c];
    }
}

// ---------------------------------------------------------------------------
// Pack both conv weight tensors, tap-inner K order, CB=64 channel K-tiles,
// in one launch. i < 256*1152 -> w_red; else w2.
// ---------------------------------------------------------------------------
__global__ __launch_bounds__(256) void pack_w_both_kernel(
    const float* __restrict__ w1, short* __restrict__ wp1,
    const float* __restrict__ w2, short* __restrict__ wp2) {
    int i = blockIdx.x * 256 + threadIdx.x;
    const float* w; short* wp; int CIN, K;
    if (i < 256 * 1152) { w = w1; wp = wp1; CIN = 128; K = 1152; }
    else { i -= 256 * 1152; if (i >= 256 * 4608) return;
           w = w2; wp = wp2; CIN = 512; K = 4608; }
    int cout = i / K;
    int r = i - cout * K;
    int t = r >> 6;                  // CB = 64
    int j = r & 63;
    int cb = t / 9;
    int tap = t - cb * 9;
    int cin = cb * 64 + j;
    wp[i + cout * 0] = f2bf(w[((size_t)cout * CIN + cin) * 9 + tap]);
}

// ---------------------------------------------------------------------------
// Unified 3x3-conv 256x256x(BK=64) 8-phase kernel (T2+T3+T4+T5 template).
// FUSE (conv2 only): instead of writing x2, the epilogue runs the 1x1 conv
// (256->49) + ReLU + softmax in-block via an LDS transpose of the output
// tile, writing attn directly. Math is bit-identical to the old two-kernel
// path (LDS holds the same bf16 values x2 held).
// ---------------------------------------------------------------------------
template <int CIN, bool OPAD, bool FUSE>
__global__ __launch_bounds__(512, 2) void conv_8ph_kernel(
    const short* __restrict__ in_a, const short* __restrict__ in_b,
    const short* __restrict__ wp, const float* __restrict__ bias,
    short* __restrict__ out_a, short* __restrict__ out_b,
    const float* __restrict__ w3, const float* __restrict__ b3,
    float* __restrict__ attn) {
    constexpr int K = 9 * CIN;
    constexpr int NT = K / 64;
    constexpr bool DUAL = (CIN == 512);
    constexpr int PST = DUAL ? 256 : CIN;
    extern __shared__ __align__(16) short lds[];   // 131072 B
    const int tid = threadIdx.x;
    int bx = blockIdx.x;
    bx = (bx & 7) * 64 + (bx >> 3);
    const int b = bx >> 6, y0 = (bx & 63) << 1;
    const short* inA = DUAL ? in_a : (blockIdx.z ? in_b : in_a);
    const short* inB = DUAL ? in_b : inA;
    short* out = (!DUAL && blockIdx.z) ? out_b : out_a;

    const int lane = tid & 63, wv = tid >> 6;
    const int wm = wv >> 2, wn = wv & 3;
    const int lr = lane & 15, lk = lane >> 4;

    const int rA = tid >> 3, cc = tid & 7;
    const int cs = cc ^ (rA & 7);
    const int pthrA0 = rA * PST + cs * 8;
    const int pthrA1 = (rA + 64) * PST + cs * 8;
    const int pthrB0 = rA * K + cs * 8;
    const int pthrB1 = (rA + 64) * K + cs * 8;
    const int dA0 = rA * 64 + cc * 8;
    const int dB0 = rA * 64 + cc * 8;

    const int arow = (wm * 128 + lr) * 64;
    const int brow = (wn * 64 + lr) * 64;
    const int cof0 = ((lk) ^ (lr & 7)) * 8;
    const int cof1 = ((4 + lk) ^ (lr & 7)) * 8;

    f32x4 acc[8][4];
    f32x4 zero = {0.f, 0.f, 0.f, 0.f};
    #pragma unroll
    for (int i = 0; i < 8; ++i)
        #pragma unroll
        for (int j = 0; j < 4; ++j) acc[i][j] = zero;

    auto STAGE2 = [&](int t2, int which, short* bufA, short* bufB) {
        const int cb = (t2 * 57) >> 9;
        const int tap = t2 - cb * 9;
        const int ch0v = cb << 6;
        const short* src = (!DUAL || ch0v < 256) ? inA : inB;
        const int ch0 = DUAL ? (ch0v & 255) : ch0v;
        const int ky = (tap * 11) >> 5;
        const int kx = tap - ky * 3;
        if (which == 0 || which == 2) {
            const int po = (which == 0) ? pthrA0 : pthrA1;
            const int doff = (which == 0) ? 0 : 64 * 64;
            const short* s0 = src + ((size_t)(b * HP + (y0 + ky)) * HP + kx) * PST + ch0;
            gload16(s0 + po, bufA + doff + dA0);
            gload16(s0 + (HP * PST) + po, bufA + 128 * 64 + doff + dA0);
        } else {
            const int h2 = (which == 1) ? 0 : 1;
            const short* sb = wp + (size_t)(h2 * 128) * K + t2 * 64;
            short* d = bufB + h2 * 128 * 64 + dB0;
            gload16(sb + pthrB0, d);
            gload16(sb + pthrB1, d + 64 * 64);
        }
    };

    auto LDA = [&](const short* bufA, int mh, bf16x8 (&a)[4][2]) {
        #pragma unroll
        for (int i = 0; i < 4; ++i) {
            const int ro = arow + (mh * 64 + i * 16) * 64;
            a[i][0] = *(const bf16x8*)(bufA + ro + cof0);
            a[i][1] = *(const bf16x8*)(bufA + ro + cof1);
        }
    };
    auto LDB = [&](const short* bufB, int nh, bf16x8 (&bb)[2][2]) {
        #pragma unroll
        for (int j = 0; j < 2; ++j) {
            const int ro = brow + (nh * 32 + j * 16) * 64;
            bb[j][0] = *(const bf16x8*)(bufB + ro + cof0);
            bb[j][1] = *(const bf16x8*)(bufB + ro + cof1);
        }
    };

#define PH_PRE() do { __builtin_amdgcn_sched_barrier(0); \
                      __builtin_amdgcn_s_barrier(); \
                      asm volatile("s_waitcnt lgkmcnt(0)" ::: "memory"); \
                      __builtin_amdgcn_sched_barrier(0); \
                      __builtin_amdgcn_s_setprio(1); } while (0)
#define PH_POST() do { __builtin_amdgcn_s_setprio(0); \
                       __builtin_amdgcn_sched_barrier(0); \
                       __builtin_amdgcn_s_barrier(); } while (0)
#define MFMA_Q(A_, B_, MH, NH) do { \
    _Pragma("unroll") \
    for (int i_ = 0; i_ < 4; ++i_) { \
        _Pragma("unroll") \
        for (int j_ = 0; j_ < 2; ++j_) { \
            acc[(MH)*4+i_][(NH)*2+j_] = __builtin_amdgcn_mfma_f32_16x16x32_bf16( \
                A_[i_][0], B_[j_][0], acc[(MH)*4+i_][(NH)*2+j_], 0, 0, 0); \
            acc[(MH)*4+i_][(NH)*2+j_] = __builtin_amdgcn_mfma_f32_16x16x32_bf16( \
                A_[i_][1], B_[j_][1], acc[(MH)*4+i_][(NH)*2+j_], 0, 0, 0); \
        } \
    } } while (0)

    short* const A0 = lds;
    short* const A1 = lds + 16384;
    short* const B0 = lds + 32768;
    short* const B1 = lds + 49152;

    STAGE2(0, 0, A0, B0); STAGE2(0, 1, A0, B0);
    STAGE2(0, 2, A0, B0); STAGE2(0, 3, A0, B0);
    STAGE2(1, 0, A1, B1); STAGE2(1, 1, A1, B1);
    STAGE2(1, 2, A1, B1); STAGE2(1, 3, A1, B1);
    asm volatile("s_waitcnt vmcnt(8)" ::: "memory");
    __builtin_amdgcn_sched_barrier(0);
    __builtin_amdgcn_s_barrier();

    auto TILE = [&](int t, short* bufA, short* bufB) {
        const int t2 = t + 2;
        const bool st = (t2 < NT);
        bf16x8 ar[4][2], br0[2][2], br1[2][2];
        LDA(bufA, 0, ar);
        LDB(bufB, 0, br0);
        if (st) STAGE2(t2, 0, bufA, bufB);
        PH_PRE();
        MFMA_Q(ar, br0, 0, 0);
        PH_POST();
        LDB(bufB, 1, br1);
        if (st) STAGE2(t2, 1, bufA, bufB);
        PH_PRE();
        MFMA_Q(ar, br1, 0, 1);
        PH_POST();
        LDA(bufA, 1, ar);
        if (st) STAGE2(t2, 2, bufA, bufB);
        PH_PRE();
        MFMA_Q(ar, br0, 1, 0);
        PH_POST();
        if (st) STAGE2(t2, 3, bufA, bufB);
        PH_PRE();
        MFMA_Q(ar, br1, 1, 1);
        __builtin_amdgcn_s_setprio(0);
        __builtin_amdgcn_sched_barrier(0);
        if (st)                asm volatile("s_waitcnt vmcnt(8)" ::: "memory");
        else if (t == NT - 2)  asm volatile("s_waitcnt vmcnt(0)" ::: "memory");
        __builtin_amdgcn_sched_barrier(0);
        __builtin_amdgcn_s_barrier();
    };

    for (int t = 0; t < NT; t += 2) {
        TILE(t,     A0, B0);
        TILE(t + 1, A1, B1);
    }
#undef PH_PRE
#undef PH_POST
#undef MFMA_Q

    float bvs[4];
    #pragma unroll
    for (int nf = 0; nf < 4; ++nf) bvs[nf] = bias[wn * 64 + nf * 16 + lr];

    if constexpr (!FUSE) {
        // plain epilogue: bias+ReLU -> NHWC bf16, nf-innermost stores
        #pragma unroll
        for (int mf = 0; mf < 8; ++mf) {
            #pragma unroll
            for (int rr = 0; rr < 4; ++rr) {
                const int p = wm * 128 + mf * 16 + lk * 4 + rr;
                const int y = y0 + (p >> 7), x = p & 127;
                short* op;
                if (OPAD)
                    op = out + ((size_t)(b * HP + (y + 1)) * HP + (x + 1)) * CMID + wn * 64 + lr;
                else
                    op = out + ((size_t)((b * HN + y) * WN + x)) * CMID + wn * 64 + lr;
                #pragma unroll
                for (int nf = 0; nf < 4; ++nf)
                    op[nf * 16] = f2bf(fmaxf(acc[mf][nf][rr] + bvs[nf], 0.f));
            }
        }
    } else {
        // fused 1x1 conv + softmax epilogue.
        // 1) bias+ReLU+cvt -> LDS [px][256ch], chunk-XOR swizzled:
        //    phys(px,ch) = px*256 + (((ch>>3)^px)&31)*8 + (ch&7)
        #pragma unroll
        for (int nf = 0; nf < 4; ++nf) {
            #pragma unroll
            for (int mf = 0; mf < 8; ++mf) {
                #pragma unroll
                for (int rr = 0; rr < 4; ++rr) {
                    const int pxw = wm * 128 + mf * 16 + lk * 4 + rr;
                    const int ch = wn * 64 + nf * 16 + lr;
                    const int phys = pxw * 256 + ((((ch >> 3) ^ pxw) & 31) << 3) + (ch & 7);
                    lds[phys] = f2bf(fmaxf(acc[mf][nf][rr] + bvs[nf], 0.f));
                }
            }
        }
        __syncthreads();
        // 2) half-channel 49-dot per thread: px = tid&255, h = tid>>8
        const int px = tid & 255, h = tid >> 8;
        float z[KO];
        #pragma unroll
        for (int o = 0; o < KO; ++o) z[o] = h ? 0.f : b3[o];
        #pragma unroll 1
        for (int c8 = 0; c8 < 16; ++c8) {
            const int chunk = h * 16 + c8;
            bf16x8 v = *(const bf16x8*)&lds[px * 256 + (((chunk ^ px) & 31) << 3)];
            float xf[8];
            #pragma unroll
            for (int j = 0; j < 8; ++j) xf[j] = bf2f(v[j]);
            const float* wr = w3 + h * 128 + c8 * 8;
            #pragma unroll
            for (int o = 0; o < KO; ++o) {
                float s = z[o];
                #pragma unroll
                for (int j = 0; j < 8; ++j) s = fmaf(xf[j], wr[o * 256 + j], s);
                z[o] = s;
            }
        }
        __syncthreads();
        // 3) cross-half reduce via LDS zbuf [o][px] (50176 B, reuses lds)
        float* zb = (float*)lds;
        if (h) {
            #pragma unroll
            for (int o = 0; o < KO; ++o) zb[o * 256 + px] = z[o];
        }
        __syncthreads();
        if (!h) {
            #pragma unroll
            for (int o = 0; o < KO; ++o) z[o] = fmaxf(z[o] + zb[o * 256 + px], 0.f);
            float m = z[0];
            #pragma unroll
            for (int o = 1; o < KO; ++o) m = fmaxf(m, z[o]);
            float ssum = 0.f;
            #pragma unroll
            for (int o = 0; o < KO; ++o) { float e = __expf(z[o] - m); z[o] = e; ssum += e; }
            const float inv = 1.f / ssum;
            const int gy = y0 + (px >> 7), gx = px & 127;
            float* ap = attn + (((size_t)b * KO) << 14) + (gy << 7) + gx;
            #pragma unroll
            for (int o = 0; o < KO; ++o) ap[(size_t)o << 14] = z[o] * inv;
        }
    }
}

// ---------------------------------------------------------------------------
// Pad key_high NCHW fp32 -> bf16 [b][c][134][144] with zero halo.
// ---------------------------------------------------------------------------
__global__ __launch_bounds__(256) void pad_kh_kernel(
    const float* __restrict__ kh, short* __restrict__ khb) {
    const int bc = blockIdx.x;
    const float* src = kh + (size_t)bc * (HN * WN);
    short* dst = khb + (size_t)bc * KHB_PLANE;
    for (int i = threadIdx.x; i < KHB_H * (KHB_W / 8); i += 256) {
        int yy = i / (KHB_W / 8);
        int g = i - yy * (KHB_W / 8);
        int ys = yy - 3;
        bf16x8 v;
        #pragma unroll
        for (int t = 0; t < 8; ++t) {
            int xs = g * 8 + t - 4;
            float f = 0.f;
            if ((unsigned)ys < 128u && (unsigned)xs < 128u) f = src[(ys << 7) + xs];
            v[t] = f2bf(f);
        }
        *(bf16x8*)&dst[yy * KHB_W + g * 8] = v;
    }
}

// ---------------------------------------------------------------------------
// SVC v3 (unchanged from round 6).
// ---------------------------------------------------------------------------
__global__ __launch_bounds__(256) void svc3_kernel(
    const short* __restrict__ khb, const float* __restrict__ attn,
    float* __restrict__ out) {
    __shared__ float a_s[KO * 64];
    const int tid = threadIdx.x;
    int by = blockIdx.y;
    by = (by & 7) * 128 + (by >> 3);
    const int b = by >> 7, y = by & 127;
    const int x0 = blockIdx.x * 64;

    for (int i = tid; i < KO * 64; i += 256) {
        int o = i >> 6, px = i & 63;
        a_s[i] = attn[(((size_t)b * KO + o) << 14) + (y << 7) + x0 + px];
    }
    __syncthreads();

    const int ci = tid >> 3;
    const int pg = tid & 7;
    const int p0 = x0 + pg * 8;

    float acc[8][8];
    #pragma unroll
    for (int c = 0; c < 8; ++c)
        #pragma unroll
        for (int j = 0; j < 8; ++j) acc[c][j] = 0.f;

    const short* kbase = khb + (((size_t)b * 256 + ci) * KHB_H + y) * KHB_W + p0;

    #pragma unroll 1
    for (int dy = 0; dy < 7; ++dy) {
        f32x4 av[14];
        #pragma unroll
        for (int dx = 0; dx < 7; ++dx) {
            av[dx * 2]     = *(const f32x4*)&a_s[(dy * 7 + dx) * 64 + pg * 8];
            av[dx * 2 + 1] = *(const f32x4*)&a_s[(dy * 7 + dx) * 64 + pg * 8 + 4];
        }
        const short* krow = kbase + dy * KHB_W;
        #pragma unroll
        for (int c = 0; c < 8; ++c) {
            const short* kp = krow + (size_t)c * 32 * KHB_PLANE;
            bf16x8 k0 = *(const bf16x8*)(kp);
            bf16x8 k1 = *(const bf16x8*)(kp + 8);
            float win[16];
            #pragma unroll
            for (int t = 0; t < 8; ++t) { win[t] = bf2f(k0[t]); win[t + 8] = bf2f(k1[t]); }
            #pragma unroll
            for (int dx = 0; dx < 7; ++dx) {
                #pragma unroll
                for (int j = 0; j < 8; ++j)
                    acc[c][j] = fmaf(win[j + dx + 1], av[dx * 2 + (j >> 2)][j & 3],
                                     acc[c][j]);
            }
        }
    }

    #pragma unroll
    for (int c = 0; c < 8; ++c) {
        float* op = out + (((size_t)b * 256 + ci + c * 32) << 14) + (y << 7) + p0;
        f32x4 r0 = {acc[c][0], acc[c][1], acc[c][2], acc[c][3]};
        f32x4 r1 = {acc[c][4], acc[c][5], acc[c][6], acc[c][7]};
        *(f32x4*)op = r0;
        *(f32x4*)(op + 4) = r1;
    }
}

// ---------------------------------------------------------------------------
extern "C" void kernel_launch(void* const* d_in, const int* in_sizes, int n_in,
                              void* d_out, int out_size, void* d_ws, size_t ws_size,
                              hipStream_t stream) {
    (void)in_sizes; (void)n_in; (void)out_size; (void)ws_size;
    const float* cur_low  = (const float*)d_in[0];
    const float* key_low  = (const float*)d_in[1];
    const float* key_high = (const float*)d_in[2];
    const float* w_red    = (const float*)d_in[3];
    const float* b_red    = (const float*)d_in[4];
    const float* w2       = (const float*)d_in[5];
    const float* b2       = (const float*)d_in[6];
    const float* w3       = (const float*)d_in[7];
    const float* b3       = (const float*)d_in[8];
    float* out = (float*)d_out;
    char* ws = (char*)d_ws;

    const size_t SZ_ATTN = (size_t)BN * KO * HN * WN * 4;
    const size_t SZ_XPAD = (size_t)BN * HP * HP * CLOW * 2;
    const size_t SZ_YPAD = (size_t)BN * HP * HP * CMID * 2;
    float* attn  = (float*)(ws);
    short* xpadc = (short*)(ws + SZ_ATTN);
    short* xpadk = (short*)(ws + SZ_ATTN + SZ_XPAD);
    short* khb   = (short*)(ws + SZ_ATTN);   // live only after conv2 (xpads/ypadc-head dead)
    short* ypadc = (short*)(ws + SZ_ATTN + 2 * SZ_XPAD);
    short* ypadk = (short*)(ws + SZ_ATTN + 2 * SZ_XPAD + SZ_YPAD);
    short* w1p   = (short*)(ws + SZ_ATTN + 2 * SZ_XPAD + 2 * SZ_YPAD);
    short* w2p   = (short*)((char*)w1p + (size_t)256 * 1152 * 2);

    hipFuncSetAttribute((const void*)conv_8ph_kernel<128, true, false>,
                        hipFuncAttributeMaxDynamicSharedMemorySize, 131072);
    hipFuncSetAttribute((const void*)conv_8ph_kernel<512, false, true>,
                        hipFuncAttributeMaxDynamicSharedMemorySize, 131072);

    zero_border_all_kernel<<<dim3(516, 4), 256, 0, stream>>>(xpadc, xpadk, ypadc, ypadk);
    convert_pad_kernel<<<dim3(1024, 2), 256, 0, stream>>>(cur_low, key_low, xpadc, xpadk);
    pack_w_both_kernel<<<(256 * (1152 + 4608) + 255) / 256, 256, 0, stream>>>(
        w_red, w1p, w2, w2p);

    conv_8ph_kernel<128, true, false><<<dim3(512, 1, 2), 512, 131072, stream>>>(
        xpadc, xpadk, w1p, b_red, ypadc, ypadk, nullptr, nullptr, nullptr);

    conv_8ph_kernel<512, false, true><<<dim3(512, 1, 1), 512, 131072, stream>>>(
        ypadc, ypadk, w2p, b2, nullptr, nullptr, w3, b3, attn);

    pad_kh_kernel<<<2048, 256, 0, stream>>>(key_high, khb);
    svc3_kernel<<<dim3(2, 1024), 256, 0, stream>>>(khb, attn, out);
}

// Round 8
// 733.254 us; speedup vs baseline: 2.3649x; 1.1520x over previous
//
#include <hip/hip_runtime.h>
#include <stdint.h>
#include <stddef.h>

#define BN   8
#define HN   128
#define WN   128
#define HP   130
#define CLOW 128
#define CMID 256
#define KO   49

// padded key_high (bf16): [b][c][134][144], khb[b][c][y+3][x+4] = kh[b][c][y][x]
#define KHB_H 134
#define KHB_W 144
#define KHB_PLANE (KHB_H * KHB_W)   // 19296 shorts

typedef __attribute__((ext_vector_type(4))) float f32x4;
typedef __attribute__((ext_vector_type(8))) short bf16x8;

typedef __attribute__((address_space(1))) const uint8_t ga_u8;
typedef __attribute__((address_space(3))) uint8_t lds_u8;

__device__ __forceinline__ short f2bf(float f) {
    uint32_t u = __float_as_uint(f);
    u += 0x7fffu + ((u >> 16) & 1u);
    return (short)(u >> 16);
}
__device__ __forceinline__ float bf2f(short s) {
    return __uint_as_float(((uint32_t)(uint16_t)s) << 16);
}
__device__ __forceinline__ void gload16(const void* g, void* l) {
    __builtin_amdgcn_global_load_lds((ga_u8*)g, (lds_u8*)l, 16, 0, 0);
}

// ---------------------------------------------------------------------------
// Zero halo cells of all four padded [b][130][130][C] bf16 buffers in one
// launch. blockIdx.y picks buffer (0,1: C=128; 2,3: C=256).
// ---------------------------------------------------------------------------
__global__ __launch_bounds__(256) void zero_border_all_kernel(
    short* __restrict__ b0, short* __restrict__ b1,
    short* __restrict__ b2, short* __restrict__ b3) {
    const int which = blockIdx.y;
    short* buf = (which == 0) ? b0 : (which == 1) ? b1 : (which == 2) ? b2 : b3;
    const int gsh = (which < 2) ? 4 : 5;           // groups per cell = C/8
    const int C = (which < 2) ? 128 : 256;
    int t = blockIdx.x * 256 + threadIdx.x;
    int cell = t >> gsh, g = t & ((1 << gsh) - 1);
    if (cell >= 8 * 516) return;
    int b = cell / 516, r = cell - b * 516;
    int y, x;
    if (r < 260) { y = (r >= 130) ? 129 : 0; x = (r >= 130) ? (r - 130) : r; }
    else { int j = r - 260; y = 1 + (j >> 1); x = (j & 1) ? 129 : 0; }
    uint4 z = {0u, 0u, 0u, 0u};
    *(uint4*)&buf[(((size_t)b * HP + y) * HP + x) * C + g * 8] = z;
}

// ---------------------------------------------------------------------------
// Convert NCHW fp32 -> zero-padded NHWC bf16 ([b][130][130][128]).
// ---------------------------------------------------------------------------
__global__ __launch_bounds__(256) void convert_pad_kernel(
    const float* __restrict__ src0, const float* __restrict__ src1,
    short* __restrict__ dst0, short* __restrict__ dst1) {
    __shared__ short t[128 * 132];
    const int tid = threadIdx.x;
    const int by = blockIdx.x;
    const int b = by >> 7, y = by & 127;
    const float* src = blockIdx.y ? src1 : src0;
    short* dst = blockIdx.y ? dst1 : dst0;
    for (int k = 0; k < 64; ++k) {
        int i = (k << 8) + tid;
        int c = i >> 7, x = i & 127;
        t[x * 132 + c] = f2bf(src[(((size_t)b * CLOW + c) * HN + y) * WN + x]);
    }
    __syncthreads();
    short* drow = dst + (((size_t)b * HP + (y + 1)) * HP + 1) * CLOW;
    for (int k = 0; k < 64; ++k) {
        int i = (k << 8) + tid;
        int x = i >> 7, c = i & 127;
        drow[x * CLOW + c] = t[x * 132 + c];
    }
}

// ---------------------------------------------------------------------------
// Pack all weights in one launch: w_red/w2 -> tap-inner K order (CB=64);
// w3 -> bf16 [64][256] (rows 49..63 zero).
// ---------------------------------------------------------------------------
__global__ __launch_bounds__(256) void pack_w_all_kernel(
    const float* __restrict__ w1, short* __restrict__ wp1,
    const float* __restrict__ w2, short* __restrict__ wp2,
    const float* __restrict__ w3, short* __restrict__ wp3) {
    int i = blockIdx.x * 256 + threadIdx.x;
    if (i < 256 * 1152 + 256 * 4608) {
        const float* w; short* wp; int CIN, K;
        if (i < 256 * 1152) { w = w1; wp = wp1; CIN = 128; K = 1152; }
        else { i -= 256 * 1152; w = w2; wp = wp2; CIN = 512; K = 4608; }
        int cout = i / K;
        int r = i - cout * K;
        int t = r >> 6;                  // CB = 64
        int j = r & 63;
        int cb = t / 9;
        int tap = t - cb * 9;
        int cin = cb * 64 + j;
        wp[i] = f2bf(w[((size_t)cout * CIN + cin) * 9 + tap]);
    } else {
        int j = i - (256 * 1152 + 256 * 4608);
        if (j >= 64 * 256) return;
        int o = j >> 8, ch = j & 255;
        wp3[j] = (o < KO) ? f2bf(w3[o * 256 + ch]) : (short)0;
    }
}

// ---------------------------------------------------------------------------
// Unified 3x3-conv 256x256x(BK=64) 8-phase kernel (T2+T3+T4+T5 template).
// FUSE (conv2 only): MFMA-based fused 1x1(256->49)+ReLU+softmax epilogue.
// After the K-loop, LDS is repartitioned: Xh 64KB ([128px][256ch] bf16, swz),
// W3s 32KB ([64o][256ch] bf16, swz), zbuf 32KB ([128px][64o] f32, swz).
// Two rounds over px-halves; conv output values are bit-identical to the
// old x2 path; w3 is bf16 (pre-packed).
// ---------------------------------------------------------------------------
template <int CIN, bool OPAD, bool FUSE>
__global__ __launch_bounds__(512, 2) void conv_8ph_kernel(
    const short* __restrict__ in_a, const short* __restrict__ in_b,
    const short* __restrict__ wp, const float* __restrict__ bias,
    short* __restrict__ out_a, short* __restrict__ out_b,
    const short* __restrict__ w3p, const float* __restrict__ b3,
    float* __restrict__ attn) {
    constexpr int K = 9 * CIN;
    constexpr int NT = K / 64;
    constexpr bool DUAL = (CIN == 512);
    constexpr int PST = DUAL ? 256 : CIN;
    extern __shared__ __align__(16) short lds[];   // 131072 B
    const int tid = threadIdx.x;
    int bx = blockIdx.x;
    bx = (bx & 7) * 64 + (bx >> 3);
    const int b = bx >> 6, y0 = (bx & 63) << 1;
    const short* inA = DUAL ? in_a : (blockIdx.z ? in_b : in_a);
    const short* inB = DUAL ? in_b : inA;
    short* out = (!DUAL && blockIdx.z) ? out_b : out_a;

    const int lane = tid & 63, wv = tid >> 6;
    const int wm = wv >> 2, wn = wv & 3;
    const int lr = lane & 15, lk = lane >> 4;

    const int rA = tid >> 3, cc = tid & 7;
    const int cs = cc ^ (rA & 7);
    const int pthrA0 = rA * PST + cs * 8;
    const int pthrA1 = (rA + 64) * PST + cs * 8;
    const int pthrB0 = rA * K + cs * 8;
    const int pthrB1 = (rA + 64) * K + cs * 8;
    const int dA0 = rA * 64 + cc * 8;
    const int dB0 = rA * 64 + cc * 8;

    const int arow = (wm * 128 + lr) * 64;
    const int brow = (wn * 64 + lr) * 64;
    const int cof0 = ((lk) ^ (lr & 7)) * 8;
    const int cof1 = ((4 + lk) ^ (lr & 7)) * 8;

    f32x4 acc[8][4];
    f32x4 zero = {0.f, 0.f, 0.f, 0.f};
    #pragma unroll
    for (int i = 0; i < 8; ++i)
        #pragma unroll
        for (int j = 0; j < 4; ++j) acc[i][j] = zero;

    auto STAGE2 = [&](int t2, int which, short* bufA, short* bufB) {
        const int cb = (t2 * 57) >> 9;
        const int tap = t2 - cb * 9;
        const int ch0v = cb << 6;
        const short* src = (!DUAL || ch0v < 256) ? inA : inB;
        const int ch0 = DUAL ? (ch0v & 255) : ch0v;
        const int ky = (tap * 11) >> 5;
        const int kx = tap - ky * 3;
        if (which == 0 || which == 2) {
            const int po = (which == 0) ? pthrA0 : pthrA1;
            const int doff = (which == 0) ? 0 : 64 * 64;
            const short* s0 = src + ((size_t)(b * HP + (y0 + ky)) * HP + kx) * PST + ch0;
            gload16(s0 + po, bufA + doff + dA0);
            gload16(s0 + (HP * PST) + po, bufA + 128 * 64 + doff + dA0);
        } else {
            const int h2 = (which == 1) ? 0 : 1;
            const short* sb = wp + (size_t)(h2 * 128) * K + t2 * 64;
            short* d = bufB + h2 * 128 * 64 + dB0;
            gload16(sb + pthrB0, d);
            gload16(sb + pthrB1, d + 64 * 64);
        }
    };

    auto LDA = [&](const short* bufA, int mh, bf16x8 (&a)[4][2]) {
        #pragma unroll
        for (int i = 0; i < 4; ++i) {
            const int ro = arow + (mh * 64 + i * 16) * 64;
            a[i][0] = *(const bf16x8*)(bufA + ro + cof0);
            a[i][1] = *(const bf16x8*)(bufA + ro + cof1);
        }
    };
    auto LDB = [&](const short* bufB, int nh, bf16x8 (&bb)[2][2]) {
        #pragma unroll
        for (int j = 0; j < 2; ++j) {
            const int ro = brow + (nh * 32 + j * 16) * 64;
            bb[j][0] = *(const bf16x8*)(bufB + ro + cof0);
            bb[j][1] = *(const bf16x8*)(bufB + ro + cof1);
        }
    };

#define PH_PRE() do { __builtin_amdgcn_sched_barrier(0); \
                      __builtin_amdgcn_s_barrier(); \
                      asm volatile("s_waitcnt lgkmcnt(0)" ::: "memory"); \
                      __builtin_amdgcn_sched_barrier(0); \
                      __builtin_amdgcn_s_setprio(1); } while (0)
#define PH_POST() do { __builtin_amdgcn_s_setprio(0); \
                       __builtin_amdgcn_sched_barrier(0); \
                       __builtin_amdgcn_s_barrier(); } while (0)
#define MFMA_Q(A_, B_, MH, NH) do { \
    _Pragma("unroll") \
    for (int i_ = 0; i_ < 4; ++i_) { \
        _Pragma("unroll") \
        for (int j_ = 0; j_ < 2; ++j_) { \
            acc[(MH)*4+i_][(NH)*2+j_] = __builtin_amdgcn_mfma_f32_16x16x32_bf16( \
                A_[i_][0], B_[j_][0], acc[(MH)*4+i_][(NH)*2+j_], 0, 0, 0); \
            acc[(MH)*4+i_][(NH)*2+j_] = __builtin_amdgcn_mfma_f32_16x16x32_bf16( \
                A_[i_][1], B_[j_][1], acc[(MH)*4+i_][(NH)*2+j_], 0, 0, 0); \
        } \
    } } while (0)

    short* const A0 = lds;
    short* const A1 = lds + 16384;
    short* const B0 = lds + 32768;
    short* const B1 = lds + 49152;

    STAGE2(0, 0, A0, B0); STAGE2(0, 1, A0, B0);
    STAGE2(0, 2, A0, B0); STAGE2(0, 3, A0, B0);
    STAGE2(1, 0, A1, B1); STAGE2(1, 1, A1, B1);
    STAGE2(1, 2, A1, B1); STAGE2(1, 3, A1, B1);
    asm volatile("s_waitcnt vmcnt(8)" ::: "memory");
    __builtin_amdgcn_sched_barrier(0);
    __builtin_amdgcn_s_barrier();

    auto TILE = [&](int t, short* bufA, short* bufB) {
        const int t2 = t + 2;
        const bool st = (t2 < NT);
        bf16x8 ar[4][2], br0[2][2], br1[2][2];
        LDA(bufA, 0, ar);
        LDB(bufB, 0, br0);
        if (st) STAGE2(t2, 0, bufA, bufB);
        PH_PRE();
        MFMA_Q(ar, br0, 0, 0);
        PH_POST();
        LDB(bufB, 1, br1);
        if (st) STAGE2(t2, 1, bufA, bufB);
        PH_PRE();
        MFMA_Q(ar, br1, 0, 1);
        PH_POST();
        LDA(bufA, 1, ar);
        if (st) STAGE2(t2, 2, bufA, bufB);
        PH_PRE();
        MFMA_Q(ar, br0, 1, 0);
        PH_POST();
        if (st) STAGE2(t2, 3, bufA, bufB);
        PH_PRE();
        MFMA_Q(ar, br1, 1, 1);
        __builtin_amdgcn_s_setprio(0);
        __builtin_amdgcn_sched_barrier(0);
        if (st)                asm volatile("s_waitcnt vmcnt(8)" ::: "memory");
        else if (t == NT - 2)  asm volatile("s_waitcnt vmcnt(0)" ::: "memory");
        __builtin_amdgcn_sched_barrier(0);
        __builtin_amdgcn_s_barrier();
    };

    for (int t = 0; t < NT; t += 2) {
        TILE(t,     A0, B0);
        TILE(t + 1, A1, B1);
    }
#undef PH_PRE
#undef PH_POST
#undef MFMA_Q

    float bvs[4];
    #pragma unroll
    for (int nf = 0; nf < 4; ++nf) bvs[nf] = bias[wn * 64 + nf * 16 + lr];

    if constexpr (!FUSE) {
        // plain epilogue: bias+ReLU -> NHWC bf16, nf-innermost stores
        #pragma unroll
        for (int mf = 0; mf < 8; ++mf) {
            #pragma unroll
            for (int rr = 0; rr < 4; ++rr) {
                const int p = wm * 128 + mf * 16 + lk * 4 + rr;
                const int y = y0 + (p >> 7), x = p & 127;
                short* op;
                if (OPAD)
                    op = out + ((size_t)(b * HP + (y + 1)) * HP + (x + 1)) * CMID + wn * 64 + lr;
                else
                    op = out + ((size_t)((b * HN + y) * WN + x)) * CMID + wn * 64 + lr;
                #pragma unroll
                for (int nf = 0; nf < 4; ++nf)
                    op[nf * 16] = f2bf(fmaxf(acc[mf][nf][rr] + bvs[nf], 0.f));
            }
        }
    } else {
        // ---- MFMA-based fused 1x1(256->49) + ReLU + softmax epilogue ----
        short* const Xh   = lds;                        // [128px][256ch] bf16 swz
        short* const W3s  = lds + 32768;                // [64o][256ch] bf16 swz
        float* const zbuf = (float*)(lds + 49152);      // [128px][64o] f32 swz

        // stage w3p -> W3s (LDS linear dest, inverse-swizzled global source)
        #pragma unroll
        for (int sweep = 0; sweep < 4; ++sweep) {
            const int s = sweep * 512 + wv * 64 + lane;
            const int o = s >> 5, c = s & 31;
            gload16(w3p + o * 256 + ((c ^ (o & 7)) << 3), W3s + s * 8);
        }

        const int oo = wn * 16 + lr;                    // this lane's output idx
        const float b3v = (oo < KO) ? b3[oo] : 0.f;

        #pragma unroll 1
        for (int r = 0; r < 2; ++r) {
            // 1) waves wm==r deposit their px-half as bf16 (bias+ReLU), swz
            if (wm == r) {
                #pragma unroll
                for (int nf = 0; nf < 4; ++nf) {
                    const int ch = wn * 64 + nf * 16 + lr;
                    const int ck = ch >> 3, el = ch & 7;
                    #pragma unroll
                    for (int mf = 0; mf < 8; ++mf) {
                        #pragma unroll
                        for (int rr = 0; rr < 4; ++rr) {
                            const int px = mf * 16 + lk * 4 + rr;
                            Xh[px * 256 + ((ck ^ (px & 7)) << 3) + el] =
                                f2bf(fmaxf(acc[mf][nf][rr] + bvs[nf], 0.f));
                        }
                    }
                }
            }
            __syncthreads();
            // 2) GEMM [128px x 256ch] x [64o x 256ch]^T, C init = b3
            f32x4 a2[4];
            #pragma unroll
            for (int m = 0; m < 4; ++m) {
                a2[m][0] = b3v; a2[m][1] = b3v; a2[m][2] = b3v; a2[m][3] = b3v;
            }
            #pragma unroll
            for (int ks = 0; ks < 8; ++ks) {
                const bf16x8 bfr =
                    *(const bf16x8*)&W3s[oo * 256 + (((ks * 4 + lk) ^ (oo & 7)) << 3)];
                #pragma unroll
                for (int m = 0; m < 4; ++m) {
                    const int px = wm * 64 + m * 16 + lr;
                    const bf16x8 afr =
                        *(const bf16x8*)&Xh[px * 256 + (((ks * 4 + lk) ^ (px & 7)) << 3)];
                    a2[m] = __builtin_amdgcn_mfma_f32_16x16x32_bf16(afr, bfr, a2[m], 0, 0, 0);
                }
            }
            // 3) D -> zbuf (o-swizzled rows)
            #pragma unroll
            for (int m = 0; m < 4; ++m) {
                #pragma unroll
                for (int r2 = 0; r2 < 4; ++r2) {
                    const int px = wm * 64 + m * 16 + lk * 4 + r2;
                    zbuf[px * 64 + (oo ^ ((px & 7) << 3))] = a2[m][r2];
                }
            }
            __syncthreads();
            // 4) relu + softmax per pixel, store attn (coalesced per o)
            if (tid < 128) {
                const int px = tid;
                const float* zr = &zbuf[px * 64];
                const int sw = (px & 7) << 3;
                float zz[49];
                #pragma unroll
                for (int q = 0; q < 12; ++q) {
                    f32x4 v = *(const f32x4*)&zr[(q * 4) ^ sw];
                    zz[q * 4 + 0] = fmaxf(v[0], 0.f);
                    zz[q * 4 + 1] = fmaxf(v[1], 0.f);
                    zz[q * 4 + 2] = fmaxf(v[2], 0.f);
                    zz[q * 4 + 3] = fmaxf(v[3], 0.f);
                }
                zz[48] = fmaxf(zr[48 ^ sw], 0.f);
                float mx = zz[0];
                #pragma unroll
                for (int o = 1; o < KO; ++o) mx = fmaxf(mx, zz[o]);
                float ssum = 0.f;
                #pragma unroll
                for (int o = 0; o < KO; ++o) { float e = __expf(zz[o] - mx); zz[o] = e; ssum += e; }
                const float inv = 1.f / ssum;
                float* ap = attn + (((size_t)b * KO) << 14) + ((size_t)(y0 + r) << 7) + px;
                #pragma unroll
                for (int o = 0; o < KO; ++o) ap[(size_t)o << 14] = zz[o] * inv;
            }
            if (r == 0) __syncthreads();   // zbuf/Xh safe to overwrite in round 1
        }
    }
}

// ---------------------------------------------------------------------------
// Pad key_high NCHW fp32 -> bf16 [b][c][134][144] with zero halo.
// ---------------------------------------------------------------------------
__global__ __launch_bounds__(256) void pad_kh_kernel(
    const float* __restrict__ kh, short* __restrict__ khb) {
    const int bc = blockIdx.x;
    const float* src = kh + (size_t)bc * (HN * WN);
    short* dst = khb + (size_t)bc * KHB_PLANE;
    for (int i = threadIdx.x; i < KHB_H * (KHB_W / 8); i += 256) {
        int yy = i / (KHB_W / 8);
        int g = i - yy * (KHB_W / 8);
        int ys = yy - 3;
        bf16x8 v;
        #pragma unroll
        for (int t = 0; t < 8; ++t) {
            int xs = g * 8 + t - 4;
            float f = 0.f;
            if ((unsigned)ys < 128u && (unsigned)xs < 128u) f = src[(ys << 7) + xs];
            v[t] = f2bf(f);
        }
        *(bf16x8*)&dst[yy * KHB_W + g * 8] = v;
    }
}

// ---------------------------------------------------------------------------
// SVC v3 (unchanged).
// ---------------------------------------------------------------------------
__global__ __launch_bounds__(256) void svc3_kernel(
    const short* __restrict__ khb, const float* __restrict__ attn,
    float* __restrict__ out) {
    __shared__ float a_s[KO * 64];
    const int tid = threadIdx.x;
    int by = blockIdx.y;
    by = (by & 7) * 128 + (by >> 3);
    const int b = by >> 7, y = by & 127;
    const int x0 = blockIdx.x * 64;

    for (int i = tid; i < KO * 64; i += 256) {
        int o = i >> 6, px = i & 63;
        a_s[i] = attn[(((size_t)b * KO + o) << 14) + (y << 7) + x0 + px];
    }
    __syncthreads();

    const int ci = tid >> 3;
    const int pg = tid & 7;
    const int p0 = x0 + pg * 8;

    float acc[8][8];
    #pragma unroll
    for (int c = 0; c < 8; ++c)
        #pragma unroll
        for (int j = 0; j < 8; ++j) acc[c][j] = 0.f;

    const short* kbase = khb + (((size_t)b * 256 + ci) * KHB_H + y) * KHB_W + p0;

    #pragma unroll 1
    for (int dy = 0; dy < 7; ++dy) {
        f32x4 av[14];
        #pragma unroll
        for (int dx = 0; dx < 7; ++dx) {
            av[dx * 2]     = *(const f32x4*)&a_s[(dy * 7 + dx) * 64 + pg * 8];
            av[dx * 2 + 1] = *(const f32x4*)&a_s[(dy * 7 + dx) * 64 + pg * 8 + 4];
        }
        const short* krow = kbase + dy * KHB_W;
        #pragma unroll
        for (int c = 0; c < 8; ++c) {
            const short* kp = krow + (size_t)c * 32 * KHB_PLANE;
            bf16x8 k0 = *(const bf16x8*)(kp);
            bf16x8 k1 = *(const bf16x8*)(kp + 8);
            float win[16];
            #pragma unroll
            for (int t = 0; t < 8; ++t) { win[t] = bf2f(k0[t]); win[t + 8] = bf2f(k1[t]); }
            #pragma unroll
            for (int dx = 0; dx < 7; ++dx) {
                #pragma unroll
                for (int j = 0; j < 8; ++j)
                    acc[c][j] = fmaf(win[j + dx + 1], av[dx * 2 + (j >> 2)][j & 3],
                                     acc[c][j]);
            }
        }
    }

    #pragma unroll
    for (int c = 0; c < 8; ++c) {
        float* op = out + (((size_t)b * 256 + ci + c * 32) << 14) + (y << 7) + p0;
        f32x4 r0 = {acc[c][0], acc[c][1], acc[c][2], acc[c][3]};
        f32x4 r1 = {acc[c][4], acc[c][5], acc[c][6], acc[c][7]};
        *(f32x4*)op = r0;
        *(f32x4*)(op + 4) = r1;
    }
}

// ---------------------------------------------------------------------------
extern "C" void kernel_launch(void* const* d_in, const int* in_sizes, int n_in,
                              void* d_out, int out_size, void* d_ws, size_t ws_size,
                              hipStream_t stream) {
    (void)in_sizes; (void)n_in; (void)out_size; (void)ws_size;
    const float* cur_low  = (const float*)d_in[0];
    const float* key_low  = (const float*)d_in[1];
    const float* key_high = (const float*)d_in[2];
    const float* w_red    = (const float*)d_in[3];
    const float* b_red    = (const float*)d_in[4];
    const float* w2       = (const float*)d_in[5];
    const float* b2       = (const float*)d_in[6];
    const float* w3       = (const float*)d_in[7];
    const float* b3       = (const float*)d_in[8];
    float* out = (float*)d_out;
    char* ws = (char*)d_ws;

    const size_t SZ_ATTN = (size_t)BN * KO * HN * WN * 4;
    const size_t SZ_XPAD = (size_t)BN * HP * HP * CLOW * 2;
    const size_t SZ_YPAD = (size_t)BN * HP * HP * CMID * 2;
    float* attn  = (float*)(ws);
    short* xpadc = (short*)(ws + SZ_ATTN);
    short* xpadk = (short*)(ws + SZ_ATTN + SZ_XPAD);
    short* khb   = (short*)(ws + SZ_ATTN);   // live only after conv2 (xpads dead)
    short* ypadc = (short*)(ws + SZ_ATTN + 2 * SZ_XPAD);
    short* ypadk = (short*)(ws + SZ_ATTN + 2 * SZ_XPAD + SZ_YPAD);
    short* w1p   = (short*)(ws + SZ_ATTN + 2 * SZ_XPAD + 2 * SZ_YPAD);
    short* w2p   = (short*)((char*)w1p + (size_t)256 * 1152 * 2);
    // w3p (32 KB) lives in the d_out tail: written by pack, read by conv2f,
    // then fully overwritten by svc3's output. Deterministic each call.
    short* w3p   = (short*)((char*)d_out + (size_t)134217728 - 32768);

    hipFuncSetAttribute((const void*)conv_8ph_kernel<128, true, false>,
                        hipFuncAttributeMaxDynamicSharedMemorySize, 131072);
    hipFuncSetAttribute((const void*)conv_8ph_kernel<512, false, true>,
                        hipFuncAttributeMaxDynamicSharedMemorySize, 131072);

    zero_border_all_kernel<<<dim3(516, 4), 256, 0, stream>>>(xpadc, xpadk, ypadc, ypadk);
    convert_pad_kernel<<<dim3(1024, 2), 256, 0, stream>>>(cur_low, key_low, xpadc, xpadk);
    pack_w_all_kernel<<<(256 * (1152 + 4608) + 64 * 256 + 255) / 256, 256, 0, stream>>>(
        w_red, w1p, w2, w2p, w3, w3p);

    conv_8ph_kernel<128, true, false><<<dim3(512, 1, 2), 512, 131072, stream>>>(
        xpadc, xpadk, w1p, b_red, ypadc, ypadk, nullptr, nullptr, nullptr);

    conv_8ph_kernel<512, false, true><<<dim3(512, 1, 1), 512, 131072, stream>>>(
        ypadc, ypadk, w2p, b2, nullptr, nullptr, w3p, b3, attn);

    pad_kh_kernel<<<2048, 256, 0, stream>>>(key_high, khb);
    svc3_kernel<<<dim3(2, 1024), 256, 0, stream>>>(khb, attn, out);
}

// Round 9
// 675.478 us; speedup vs baseline: 2.5672x; 1.0855x over previous
//
#include <hip/hip_runtime.h>
#include <stdint.h>
#include <stddef.h>

#define BN   8
#define HN   128
#define WN   128
#define HP   130
#define CLOW 128
#define CMID 256
#define KO   49

// padded key_high (bf16): [b][c][134][144], khb[b][c][y+3][x+4] = kh[b][c][y][x]
#define KHB_H 134
#define KHB_W 144
#define KHB_PLANE (KHB_H * KHB_W)   // 19296 shorts

typedef __attribute__((ext_vector_type(4))) float f32x4;
typedef __attribute__((ext_vector_type(8))) short bf16x8;

typedef __attribute__((address_space(1))) const uint8_t ga_u8;
typedef __attribute__((address_space(3))) uint8_t lds_u8;

__device__ __forceinline__ short f2bf(float f) {
    uint32_t u = __float_as_uint(f);
    u += 0x7fffu + ((u >> 16) & 1u);
    return (short)(u >> 16);
}
__device__ __forceinline__ float bf2f(short s) {
    return __uint_as_float(((uint32_t)(uint16_t)s) << 16);
}
__device__ __forceinline__ void gload16(const void* g, void* l) {
    __builtin_amdgcn_global_load_lds((ga_u8*)g, (lds_u8*)l, 16, 0, 0);
}

// ---------------------------------------------------------------------------
// Zero halo cells of all four padded [b][130][130][C] bf16 buffers in one
// launch. blockIdx.y picks buffer (0,1: C=128; 2,3: C=256).
// ---------------------------------------------------------------------------
__global__ __launch_bounds__(256) void zero_border_all_kernel(
    short* __restrict__ b0, short* __restrict__ b1,
    short* __restrict__ b2, short* __restrict__ b3) {
    const int which = blockIdx.y;
    short* buf = (which == 0) ? b0 : (which == 1) ? b1 : (which == 2) ? b2 : b3;
    const int gsh = (which < 2) ? 4 : 5;           // groups per cell = C/8
    const int C = (which < 2) ? 128 : 256;
    int t = blockIdx.x * 256 + threadIdx.x;
    int cell = t >> gsh, g = t & ((1 << gsh) - 1);
    if (cell >= 8 * 516) return;
    int b = cell / 516, r = cell - b * 516;
    int y, x;
    if (r < 260) { y = (r >= 130) ? 129 : 0; x = (r >= 130) ? (r - 130) : r; }
    else { int j = r - 260; y = 1 + (j >> 1); x = (j & 1) ? 129 : 0; }
    uint4 z = {0u, 0u, 0u, 0u};
    *(uint4*)&buf[(((size_t)b * HP + y) * HP + x) * C + g * 8] = z;
}

// ---------------------------------------------------------------------------
// Convert NCHW fp32 -> zero-padded NHWC bf16 ([b][130][130][128]).
// ---------------------------------------------------------------------------
__global__ __launch_bounds__(256) void convert_pad_kernel(
    const float* __restrict__ src0, const float* __restrict__ src1,
    short* __restrict__ dst0, short* __restrict__ dst1) {
    __shared__ short t[128 * 132];
    const int tid = threadIdx.x;
    const int by = blockIdx.x;
    const int b = by >> 7, y = by & 127;
    const float* src = blockIdx.y ? src1 : src0;
    short* dst = blockIdx.y ? dst1 : dst0;
    for (int k = 0; k < 64; ++k) {
        int i = (k << 8) + tid;
        int c = i >> 7, x = i & 127;
        t[x * 132 + c] = f2bf(src[(((size_t)b * CLOW + c) * HN + y) * WN + x]);
    }
    __syncthreads();
    short* drow = dst + (((size_t)b * HP + (y + 1)) * HP + 1) * CLOW;
    for (int k = 0; k < 64; ++k) {
        int i = (k << 8) + tid;
        int x = i >> 7, c = i & 127;
        drow[x * CLOW + c] = t[x * 132 + c];
    }
}

// ---------------------------------------------------------------------------
// Pack all weights in one launch: w_red/w2 -> tap-inner K order (CB=64);
// w3 -> bf16 [64][256] (rows 49..63 zero).
// ---------------------------------------------------------------------------
__global__ __launch_bounds__(256) void pack_w_all_kernel(
    const float* __restrict__ w1, short* __restrict__ wp1,
    const float* __restrict__ w2, short* __restrict__ wp2,
    const float* __restrict__ w3, short* __restrict__ wp3) {
    int i = blockIdx.x * 256 + threadIdx.x;
    if (i < 256 * 1152 + 256 * 4608) {
        const float* w; short* wp; int CIN, K;
        if (i < 256 * 1152) { w = w1; wp = wp1; CIN = 128; K = 1152; }
        else { i -= 256 * 1152; w = w2; wp = wp2; CIN = 512; K = 4608; }
        int cout = i / K;
        int r = i - cout * K;
        int t = r >> 6;                  // CB = 64
        int j = r & 63;
        int cb = t / 9;
        int tap = t - cb * 9;
        int cin = cb * 64 + j;
        wp[i] = f2bf(w[((size_t)cout * CIN + cin) * 9 + tap]);
    } else {
        int j = i - (256 * 1152 + 256 * 4608);
        if (j >= 64 * 256) return;
        int o = j >> 8, ch = j & 255;
        wp3[j] = (o < KO) ? f2bf(w3[o * 256 + ch]) : (short)0;
    }
}

// ---------------------------------------------------------------------------
// Unified 3x3-conv 256x256x(BK=64) 8-phase kernel (T2+T3+T4+T5 template).
// FUSE (conv2 only): MFMA-based fused 1x1(256->49[+b3]) epilogue writing
// fp32 logits z[pix][64] (coalesced). Softmax runs in a separate tiny
// kernel. Conv values bit-identical to the old x2 path; w3 is bf16.
// ---------------------------------------------------------------------------
template <int CIN, bool OPAD, bool FUSE>
__global__ __launch_bounds__(512, 2) void conv_8ph_kernel(
    const short* __restrict__ in_a, const short* __restrict__ in_b,
    const short* __restrict__ wp, const float* __restrict__ bias,
    short* __restrict__ out_a, short* __restrict__ out_b,
    const short* __restrict__ w3p, const float* __restrict__ b3,
    float* __restrict__ z) {
    constexpr int K = 9 * CIN;
    constexpr int NT = K / 64;
    constexpr bool DUAL = (CIN == 512);
    constexpr int PST = DUAL ? 256 : CIN;
    extern __shared__ __align__(16) short lds[];   // 131072 B
    const int tid = threadIdx.x;
    int bx = blockIdx.x;
    bx = (bx & 7) * 64 + (bx >> 3);
    const int b = bx >> 6, y0 = (bx & 63) << 1;
    const short* inA = DUAL ? in_a : (blockIdx.z ? in_b : in_a);
    const short* inB = DUAL ? in_b : inA;
    short* out = (!DUAL && blockIdx.z) ? out_b : out_a;

    const int lane = tid & 63, wv = tid >> 6;
    const int wm = wv >> 2, wn = wv & 3;
    const int lr = lane & 15, lk = lane >> 4;

    const int rA = tid >> 3, cc = tid & 7;
    const int cs = cc ^ (rA & 7);
    const int pthrA0 = rA * PST + cs * 8;
    const int pthrA1 = (rA + 64) * PST + cs * 8;
    const int pthrB0 = rA * K + cs * 8;
    const int pthrB1 = (rA + 64) * K + cs * 8;
    const int dA0 = rA * 64 + cc * 8;
    const int dB0 = rA * 64 + cc * 8;

    const int arow = (wm * 128 + lr) * 64;
    const int brow = (wn * 64 + lr) * 64;
    const int cof0 = ((lk) ^ (lr & 7)) * 8;
    const int cof1 = ((4 + lk) ^ (lr & 7)) * 8;

    f32x4 acc[8][4];
    f32x4 zero = {0.f, 0.f, 0.f, 0.f};
    #pragma unroll
    for (int i = 0; i < 8; ++i)
        #pragma unroll
        for (int j = 0; j < 4; ++j) acc[i][j] = zero;

    auto STAGE2 = [&](int t2, int which, short* bufA, short* bufB) {
        const int cb = (t2 * 57) >> 9;
        const int tap = t2 - cb * 9;
        const int ch0v = cb << 6;
        const short* src = (!DUAL || ch0v < 256) ? inA : inB;
        const int ch0 = DUAL ? (ch0v & 255) : ch0v;
        const int ky = (tap * 11) >> 5;
        const int kx = tap - ky * 3;
        if (which == 0 || which == 2) {
            const int po = (which == 0) ? pthrA0 : pthrA1;
            const int doff = (which == 0) ? 0 : 64 * 64;
            const short* s0 = src + ((size_t)(b * HP + (y0 + ky)) * HP + kx) * PST + ch0;
            gload16(s0 + po, bufA + doff + dA0);
            gload16(s0 + (HP * PST) + po, bufA + 128 * 64 + doff + dA0);
        } else {
            const int h2 = (which == 1) ? 0 : 1;
            const short* sb = wp + (size_t)(h2 * 128) * K + t2 * 64;
            short* d = bufB + h2 * 128 * 64 + dB0;
            gload16(sb + pthrB0, d);
            gload16(sb + pthrB1, d + 64 * 64);
        }
    };

    auto LDA = [&](const short* bufA, int mh, bf16x8 (&a)[4][2]) {
        #pragma unroll
        for (int i = 0; i < 4; ++i) {
            const int ro = arow + (mh * 64 + i * 16) * 64;
            a[i][0] = *(const bf16x8*)(bufA + ro + cof0);
            a[i][1] = *(const bf16x8*)(bufA + ro + cof1);
        }
    };
    auto LDB = [&](const short* bufB, int nh, bf16x8 (&bb)[2][2]) {
        #pragma unroll
        for (int j = 0; j < 2; ++j) {
            const int ro = brow + (nh * 32 + j * 16) * 64;
            bb[j][0] = *(const bf16x8*)(bufB + ro + cof0);
            bb[j][1] = *(const bf16x8*)(bufB + ro + cof1);
        }
    };

#define PH_PRE() do { __builtin_amdgcn_sched_barrier(0); \
                      __builtin_amdgcn_s_barrier(); \
                      asm volatile("s_waitcnt lgkmcnt(0)" ::: "memory"); \
                      __builtin_amdgcn_sched_barrier(0); \
                      __builtin_amdgcn_s_setprio(1); } while (0)
#define PH_POST() do { __builtin_amdgcn_s_setprio(0); \
                       __builtin_amdgcn_sched_barrier(0); \
                       __builtin_amdgcn_s_barrier(); } while (0)
#define MFMA_Q(A_, B_, MH, NH) do { \
    _Pragma("unroll") \
    for (int i_ = 0; i_ < 4; ++i_) { \
        _Pragma("unroll") \
        for (int j_ = 0; j_ < 2; ++j_) { \
            acc[(MH)*4+i_][(NH)*2+j_] = __builtin_amdgcn_mfma_f32_16x16x32_bf16( \
                A_[i_][0], B_[j_][0], acc[(MH)*4+i_][(NH)*2+j_], 0, 0, 0); \
            acc[(MH)*4+i_][(NH)*2+j_] = __builtin_amdgcn_mfma_f32_16x16x32_bf16( \
                A_[i_][1], B_[j_][1], acc[(MH)*4+i_][(NH)*2+j_], 0, 0, 0); \
        } \
    } } while (0)

    short* const A0 = lds;
    short* const A1 = lds + 16384;
    short* const B0 = lds + 32768;
    short* const B1 = lds + 49152;

    STAGE2(0, 0, A0, B0); STAGE2(0, 1, A0, B0);
    STAGE2(0, 2, A0, B0); STAGE2(0, 3, A0, B0);
    STAGE2(1, 0, A1, B1); STAGE2(1, 1, A1, B1);
    STAGE2(1, 2, A1, B1); STAGE2(1, 3, A1, B1);
    asm volatile("s_waitcnt vmcnt(8)" ::: "memory");
    __builtin_amdgcn_sched_barrier(0);
    __builtin_amdgcn_s_barrier();

    auto TILE = [&](int t, short* bufA, short* bufB) {
        const int t2 = t + 2;
        const bool st = (t2 < NT);
        bf16x8 ar[4][2], br0[2][2], br1[2][2];
        LDA(bufA, 0, ar);
        LDB(bufB, 0, br0);
        if (st) STAGE2(t2, 0, bufA, bufB);
        PH_PRE();
        MFMA_Q(ar, br0, 0, 0);
        PH_POST();
        LDB(bufB, 1, br1);
        if (st) STAGE2(t2, 1, bufA, bufB);
        PH_PRE();
        MFMA_Q(ar, br1, 0, 1);
        PH_POST();
        LDA(bufA, 1, ar);
        if (st) STAGE2(t2, 2, bufA, bufB);
        PH_PRE();
        MFMA_Q(ar, br0, 1, 0);
        PH_POST();
        if (st) STAGE2(t2, 3, bufA, bufB);
        PH_PRE();
        MFMA_Q(ar, br1, 1, 1);
        __builtin_amdgcn_s_setprio(0);
        __builtin_amdgcn_sched_barrier(0);
        if (st)                asm volatile("s_waitcnt vmcnt(8)" ::: "memory");
        else if (t == NT - 2)  asm volatile("s_waitcnt vmcnt(0)" ::: "memory");
        __builtin_amdgcn_sched_barrier(0);
        __builtin_amdgcn_s_barrier();
    };

    for (int t = 0; t < NT; t += 2) {
        TILE(t,     A0, B0);
        TILE(t + 1, A1, B1);
    }
#undef PH_PRE
#undef PH_POST
#undef MFMA_Q

    float bvs[4];
    #pragma unroll
    for (int nf = 0; nf < 4; ++nf) bvs[nf] = bias[wn * 64 + nf * 16 + lr];

    if constexpr (!FUSE) {
        // plain epilogue: bias+ReLU -> NHWC bf16, nf-innermost stores
        #pragma unroll
        for (int mf = 0; mf < 8; ++mf) {
            #pragma unroll
            for (int rr = 0; rr < 4; ++rr) {
                const int p = wm * 128 + mf * 16 + lk * 4 + rr;
                const int y = y0 + (p >> 7), x = p & 127;
                short* op;
                if (OPAD)
                    op = out + ((size_t)(b * HP + (y + 1)) * HP + (x + 1)) * CMID + wn * 64 + lr;
                else
                    op = out + ((size_t)((b * HN + y) * WN + x)) * CMID + wn * 64 + lr;
                #pragma unroll
                for (int nf = 0; nf < 4; ++nf)
                    op[nf * 16] = f2bf(fmaxf(acc[mf][nf][rr] + bvs[nf], 0.f));
            }
        }
    } else {
        // ---- MFMA 1x1(256->49) epilogue: logits -> z[pix][64] fp32 ----
        short* const Xh  = lds;                        // [128px][256ch] bf16 swz
        short* const W3s = lds + 32768;                // [64o][256ch] bf16 swz

        // stage w3p -> W3s (LDS linear dest, inverse-swizzled global source)
        #pragma unroll
        for (int sweep = 0; sweep < 4; ++sweep) {
            const int s = sweep * 512 + tid;
            const int o = s >> 5, c = s & 31;
            gload16(w3p + o * 256 + ((c ^ (o & 7)) << 3), W3s + s * 8);
        }

        const int oo = wn * 16 + lr;                    // this lane's output idx
        const float b3v = (oo < KO) ? b3[oo] : 0.f;

        #pragma unroll 1
        for (int r = 0; r < 2; ++r) {
            // 1) waves wm==r deposit their px-half as bf16 (bias+ReLU), swz
            if (wm == r) {
                #pragma unroll
                for (int nf = 0; nf < 4; ++nf) {
                    const int ch = wn * 64 + nf * 16 + lr;
                    const int ck = ch >> 3, el = ch & 7;
                    #pragma unroll
                    for (int mf = 0; mf < 8; ++mf) {
                        #pragma unroll
                        for (int rr = 0; rr < 4; ++rr) {
                            const int px = mf * 16 + lk * 4 + rr;
                            Xh[px * 256 + ((ck ^ (px & 7)) << 3) + el] =
                                f2bf(fmaxf(acc[mf][nf][rr] + bvs[nf], 0.f));
                        }
                    }
                }
            }
            __syncthreads();
            // 2) GEMM [128px x 256ch] x [64o x 256ch]^T, C init = b3
            f32x4 a2[4];
            #pragma unroll
            for (int m = 0; m < 4; ++m) {
                a2[m][0] = b3v; a2[m][1] = b3v; a2[m][2] = b3v; a2[m][3] = b3v;
            }
            #pragma unroll
            for (int ks = 0; ks < 8; ++ks) {
                const bf16x8 bfr =
                    *(const bf16x8*)&W3s[oo * 256 + (((ks * 4 + lk) ^ (oo & 7)) << 3)];
                #pragma unroll
                for (int m = 0; m < 4; ++m) {
                    const int px = wm * 64 + m * 16 + lr;
                    const bf16x8 afr =
                        *(const bf16x8*)&Xh[px * 256 + (((ks * 4 + lk) ^ (px & 7)) << 3)];
                    a2[m] = __builtin_amdgcn_mfma_f32_16x16x32_bf16(afr, bfr, a2[m], 0, 0, 0);
                }
            }
            // 3) D -> z (coalesced 64B runs: lr->oo consecutive)
            float* zp = z + ((size_t)(b * 16384 + (y0 + r) * 128)) * 64;
            #pragma unroll
            for (int m = 0; m < 4; ++m) {
                #pragma unroll
                for (int r2 = 0; r2 < 4; ++r2) {
                    const int px = wm * 64 + m * 16 + lk * 4 + r2;
                    zp[px * 64 + oo] = a2[m][r2];
                }
            }
            if (r == 0) __syncthreads();   // all Xh reads done before re-deposit
        }
    }
}

// ---------------------------------------------------------------------------
// ReLU + softmax over z[pix][64] (first 49 valid) -> attn[b][49][16384].
// Contiguous 196B reads per thread; coalesced per-o stores.
// ---------------------------------------------------------------------------
__global__ __launch_bounds__(256) void softmax3_kernel(
    const float* __restrict__ z, float* __restrict__ attn) {
    const int p = blockIdx.x * 256 + threadIdx.x;   // 131072 pixels
    const int b = p >> 14, hw = p & 16383;
    const float* zp = z + (size_t)p * 64;
    float zz[KO];
    #pragma unroll
    for (int q = 0; q < 12; ++q) {
        f32x4 v = *(const f32x4*)&zp[q * 4];
        zz[q * 4 + 0] = fmaxf(v[0], 0.f);
        zz[q * 4 + 1] = fmaxf(v[1], 0.f);
        zz[q * 4 + 2] = fmaxf(v[2], 0.f);
        zz[q * 4 + 3] = fmaxf(v[3], 0.f);
    }
    zz[48] = fmaxf(zp[48], 0.f);
    float m = zz[0];
    #pragma unroll
    for (int o = 1; o < KO; ++o) m = fmaxf(m, zz[o]);
    float s = 0.f;
    #pragma unroll
    for (int o = 0; o < KO; ++o) { float e = __expf(zz[o] - m); zz[o] = e; s += e; }
    const float inv = 1.f / s;
    float* ap = attn + (((size_t)b * KO) << 14) + hw;
    #pragma unroll
    for (int o = 0; o < KO; ++o) ap[(size_t)o << 14] = zz[o] * inv;
}

// ---------------------------------------------------------------------------
// Pad key_high NCHW fp32 -> bf16 [b][c][134][144] with zero halo.
// ---------------------------------------------------------------------------
__global__ __launch_bounds__(256) void pad_kh_kernel(
    const float* __restrict__ kh, short* __restrict__ khb) {
    const int bc = blockIdx.x;
    const float* src = kh + (size_t)bc * (HN * WN);
    short* dst = khb + (size_t)bc * KHB_PLANE;
    for (int i = threadIdx.x; i < KHB_H * (KHB_W / 8); i += 256) {
        int yy = i / (KHB_W / 8);
        int g = i - yy * (KHB_W / 8);
        int ys = yy - 3;
        bf16x8 v;
        #pragma unroll
        for (int t = 0; t < 8; ++t) {
            int xs = g * 8 + t - 4;
            float f = 0.f;
            if ((unsigned)ys < 128u && (unsigned)xs < 128u) f = src[(ys << 7) + xs];
            v[t] = f2bf(f);
        }
        *(bf16x8*)&dst[yy * KHB_W + g * 8] = v;
    }
}

// ---------------------------------------------------------------------------
// SVC v3 (unchanged).
// ---------------------------------------------------------------------------
__global__ __launch_bounds__(256) void svc3_kernel(
    const short* __restrict__ khb, const float* __restrict__ attn,
    float* __restrict__ out) {
    __shared__ float a_s[KO * 64];
    const int tid = threadIdx.x;
    int by = blockIdx.y;
    by = (by & 7) * 128 + (by >> 3);
    const int b = by >> 7, y = by & 127;
    const int x0 = blockIdx.x * 64;

    for (int i = tid; i < KO * 64; i += 256) {
        int o = i >> 6, px = i & 63;
        a_s[i] = attn[(((size_t)b * KO + o) << 14) + (y << 7) + x0 + px];
    }
    __syncthreads();

    const int ci = tid >> 3;
    const int pg = tid & 7;
    const int p0 = x0 + pg * 8;

    float acc[8][8];
    #pragma unroll
    for (int c = 0; c < 8; ++c)
        #pragma unroll
        for (int j = 0; j < 8; ++j) acc[c][j] = 0.f;

    const short* kbase = khb + (((size_t)b * 256 + ci) * KHB_H + y) * KHB_W + p0;

    #pragma unroll 1
    for (int dy = 0; dy < 7; ++dy) {
        f32x4 av[14];
        #pragma unroll
        for (int dx = 0; dx < 7; ++dx) {
            av[dx * 2]     = *(const f32x4*)&a_s[(dy * 7 + dx) * 64 + pg * 8];
            av[dx * 2 + 1] = *(const f32x4*)&a_s[(dy * 7 + dx) * 64 + pg * 8 + 4];
        }
        const short* krow = kbase + dy * KHB_W;
        #pragma unroll
        for (int c = 0; c < 8; ++c) {
            const short* kp = krow + (size_t)c * 32 * KHB_PLANE;
            bf16x8 k0 = *(const bf16x8*)(kp);
            bf16x8 k1 = *(const bf16x8*)(kp + 8);
            float win[16];
            #pragma unroll
            for (int t = 0; t < 8; ++t) { win[t] = bf2f(k0[t]); win[t + 8] = bf2f(k1[t]); }
            #pragma unroll
            for (int dx = 0; dx < 7; ++dx) {
                #pragma unroll
                for (int j = 0; j < 8; ++j)
                    acc[c][j] = fmaf(win[j + dx + 1], av[dx * 2 + (j >> 2)][j & 3],
                                     acc[c][j]);
            }
        }
    }

    #pragma unroll
    for (int c = 0; c < 8; ++c) {
        float* op = out + (((size_t)b * 256 + ci + c * 32) << 14) + (y << 7) + p0;
        f32x4 r0 = {acc[c][0], acc[c][1], acc[c][2], acc[c][3]};
        f32x4 r1 = {acc[c][4], acc[c][5], acc[c][6], acc[c][7]};
        *(f32x4*)op = r0;
        *(f32x4*)(op + 4) = r1;
    }
}

// ---------------------------------------------------------------------------
extern "C" void kernel_launch(void* const* d_in, const int* in_sizes, int n_in,
                              void* d_out, int out_size, void* d_ws, size_t ws_size,
                              hipStream_t stream) {
    (void)in_sizes; (void)n_in; (void)out_size; (void)ws_size;
    const float* cur_low  = (const float*)d_in[0];
    const float* key_low  = (const float*)d_in[1];
    const float* key_high = (const float*)d_in[2];
    const float* w_red    = (const float*)d_in[3];
    const float* b_red    = (const float*)d_in[4];
    const float* w2       = (const float*)d_in[5];
    const float* b2       = (const float*)d_in[6];
    const float* w3       = (const float*)d_in[7];
    const float* b3       = (const float*)d_in[8];
    float* out = (float*)d_out;
    char* ws = (char*)d_ws;

    const size_t SZ_ATTN = (size_t)BN * KO * HN * WN * 4;
    const size_t SZ_XPAD = (size_t)BN * HP * HP * CLOW * 2;
    const size_t SZ_YPAD = (size_t)BN * HP * HP * CMID * 2;
    float* attn  = (float*)(ws);
    short* xpadc = (short*)(ws + SZ_ATTN);
    short* xpadk = (short*)(ws + SZ_ATTN + SZ_XPAD);
    // z (33.5 MB): written by conv2f (xpads dead), read by softmax3,
    // then overwritten by khb. khb (79 MB): written by pad_kh after conv2f
    // (overlaps xpads + head of ypadc, all dead by then).
    float* z     = (float*)(ws + SZ_ATTN);
    short* khb   = (short*)(ws + SZ_ATTN);
    short* ypadc = (short*)(ws + SZ_ATTN + 2 * SZ_XPAD);
    short* ypadk = (short*)(ws + SZ_ATTN + 2 * SZ_XPAD + SZ_YPAD);
    short* w1p   = (short*)(ws + SZ_ATTN + 2 * SZ_XPAD + 2 * SZ_YPAD);
    short* w2p   = (short*)((char*)w1p + (size_t)256 * 1152 * 2);
    // w3p (32 KB) in the d_out tail: written by pack, read by conv2f,
    // then fully overwritten by svc3's output. Deterministic each call.
    short* w3p   = (short*)((char*)d_out + (size_t)134217728 - 32768);

    hipFuncSetAttribute((const void*)conv_8ph_kernel<128, true, false>,
                        hipFuncAttributeMaxDynamicSharedMemorySize, 131072);
    hipFuncSetAttribute((const void*)conv_8ph_kernel<512, false, true>,
                        hipFuncAttributeMaxDynamicSharedMemorySize, 131072);

    zero_border_all_kernel<<<dim3(516, 4), 256, 0, stream>>>(xpadc, xpadk, ypadc, ypadk);
    convert_pad_kernel<<<dim3(1024, 2), 256, 0, stream>>>(cur_low, key_low, xpadc, xpadk);
    pack_w_all_kernel<<<(256 * (1152 + 4608) + 64 * 256 + 255) / 256, 256, 0, stream>>>(
        w_red, w1p, w2, w2p, w3, w3p);

    conv_8ph_kernel<128, true, false><<<dim3(512, 1, 2), 512, 131072, stream>>>(
        xpadc, xpadk, w1p, b_red, ypadc, ypadk, nullptr, nullptr, nullptr);

    conv_8ph_kernel<512, false, true><<<dim3(512, 1, 1), 512, 131072, stream>>>(
        ypadc, ypadk, w2p, b2, nullptr, nullptr, w3p, b3, z);

    softmax3_kernel<<<512, 256, 0, stream>>>(z, attn);

    pad_kh_kernel<<<2048, 256, 0, stream>>>(key_high, khb);
    svc3_kernel<<<dim3(2, 1024), 256, 0, stream>>>(khb, attn, out);
}

// Round 10
// 654.513 us; speedup vs baseline: 2.6495x; 1.0320x over previous
//
#include <hip/hip_runtime.h>
#include <stdint.h>
#include <stddef.h>

#define BN   8
#define HN   128
#define WN   128
#define HP   130
#define CLOW 128
#define CMID 256
#define KO   49

// padded key_high (bf16): [b][c][134][144], khb[b][c][y+3][x+4] = kh[b][c][y][x]
#define KHB_H 134
#define KHB_W 144
#define KHB_PLANE (KHB_H * KHB_W)   // 19296 shorts

typedef __attribute__((ext_vector_type(4))) float f32x4;
typedef __attribute__((ext_vector_type(8))) short bf16x8;

typedef __attribute__((address_space(1))) const uint8_t ga_u8;
typedef __attribute__((address_space(3))) uint8_t lds_u8;

__device__ __forceinline__ short f2bf(float f) {
    uint32_t u = __float_as_uint(f);
    u += 0x7fffu + ((u >> 16) & 1u);
    return (short)(u >> 16);
}
__device__ __forceinline__ float bf2f(short s) {
    return __uint_as_float(((uint32_t)(uint16_t)s) << 16);
}
__device__ __forceinline__ void gload16(const void* g, void* l) {
    __builtin_amdgcn_global_load_lds((ga_u8*)g, (lds_u8*)l, 16, 0, 0);
}

// ---------------------------------------------------------------------------
// Zero halo cells of all four padded [b][130][130][C] bf16 buffers in one
// launch. blockIdx.y picks buffer (0,1: C=128; 2,3: C=256).
// ---------------------------------------------------------------------------
__global__ __launch_bounds__(256) void zero_border_all_kernel(
    short* __restrict__ b0, short* __restrict__ b1,
    short* __restrict__ b2, short* __restrict__ b3) {
    const int which = blockIdx.y;
    short* buf = (which == 0) ? b0 : (which == 1) ? b1 : (which == 2) ? b2 : b3;
    const int gsh = (which < 2) ? 4 : 5;           // groups per cell = C/8
    const int C = (which < 2) ? 128 : 256;
    int t = blockIdx.x * 256 + threadIdx.x;
    int cell = t >> gsh, g = t & ((1 << gsh) - 1);
    if (cell >= 8 * 516) return;
    int b = cell / 516, r = cell - b * 516;
    int y, x;
    if (r < 260) { y = (r >= 130) ? 129 : 0; x = (r >= 130) ? (r - 130) : r; }
    else { int j = r - 260; y = 1 + (j >> 1); x = (j & 1) ? 129 : 0; }
    uint4 z = {0u, 0u, 0u, 0u};
    *(uint4*)&buf[(((size_t)b * HP + y) * HP + x) * C + g * 8] = z;
}

// ---------------------------------------------------------------------------
// Convert NCHW fp32 -> zero-padded NHWC bf16 ([b][130][130][128]).
// Vectorized: float4 global reads, bf16x8 global stores; LDS tile stride 136
// shorts (272 B = 16-aligned rows, <=4-way banks).
// ---------------------------------------------------------------------------
__global__ __launch_bounds__(256) void convert_pad_kernel(
    const float* __restrict__ src0, const float* __restrict__ src1,
    short* __restrict__ dst0, short* __restrict__ dst1) {
    __shared__ short t[128 * 136];
    const int tid = threadIdx.x;
    const int by = blockIdx.x;
    const int b = by >> 7, y = by & 127;
    const float* src = blockIdx.y ? src1 : src0;
    short* dst = blockIdx.y ? dst1 : dst0;
    #pragma unroll
    for (int k = 0; k < 16; ++k) {
        int slot = k * 256 + tid;          // 4096 float4 slots
        int c = slot >> 5, xg = slot & 31;
        f32x4 v = *(const f32x4*)&src[(((size_t)b * CLOW + c) * HN + y) * WN + xg * 4];
        #pragma unroll
        for (int j = 0; j < 4; ++j) t[(xg * 4 + j) * 136 + c] = f2bf(v[j]);
    }
    __syncthreads();
    short* drow = dst + (((size_t)b * HP + (y + 1)) * HP + 1) * CLOW;
    #pragma unroll
    for (int k = 0; k < 8; ++k) {
        int slot = k * 256 + tid;          // 2048 bf16x8 slots
        int x = slot >> 4, cg = slot & 15;
        *(bf16x8*)&drow[x * CLOW + cg * 8] = *(const bf16x8*)&t[x * 136 + cg * 8];
    }
}

// ---------------------------------------------------------------------------
// Pack all weights in one launch: w_red/w2 -> tap-inner K order (CB=64);
// w3 -> bf16 [64][256] (rows 49..63 zero).
// ---------------------------------------------------------------------------
__global__ __launch_bounds__(256) void pack_w_all_kernel(
    const float* __restrict__ w1, short* __restrict__ wp1,
    const float* __restrict__ w2, short* __restrict__ wp2,
    const float* __restrict__ w3, short* __restrict__ wp3) {
    int i = blockIdx.x * 256 + threadIdx.x;
    if (i < 256 * 1152 + 256 * 4608) {
        const float* w; short* wp; int CIN, K;
        if (i < 256 * 1152) { w = w1; wp = wp1; CIN = 128; K = 1152; }
        else { i -= 256 * 1152; w = w2; wp = wp2; CIN = 512; K = 4608; }
        int cout = i / K;
        int r = i - cout * K;
        int t = r >> 6;                  // CB = 64
        int j = r & 63;
        int cb = t / 9;
        int tap = t - cb * 9;
        int cin = cb * 64 + j;
        wp[i] = f2bf(w[((size_t)cout * CIN + cin) * 9 + tap]);
    } else {
        int j = i - (256 * 1152 + 256 * 4608);
        if (j >= 64 * 256) return;
        int o = j >> 8, ch = j & 255;
        wp3[j] = (o < KO) ? f2bf(w3[o * 256 + ch]) : (short)0;
    }
}

// ---------------------------------------------------------------------------
// Unified 3x3-conv 256x256x(BK=64) 8-phase kernel (T2+T3+T4+T5 template).
// ph0 issues ALL B reads (br0+br1) and waits lgkmcnt(4) only (br1 overlaps
// ph0's MFMA); ph1 waits lgkmcnt(0) with zero new reads.
// FUSE (conv2 only): MFMA-based fused 1x1(256->49[+b3]) epilogue writing
// fp32 logits z[pix][64] (coalesced); softmax runs fused in svc4.
// ---------------------------------------------------------------------------
template <int CIN, bool OPAD, bool FUSE>
__global__ __launch_bounds__(512, 2) void conv_8ph_kernel(
    const short* __restrict__ in_a, const short* __restrict__ in_b,
    const short* __restrict__ wp, const float* __restrict__ bias,
    short* __restrict__ out_a, short* __restrict__ out_b,
    const short* __restrict__ w3p, const float* __restrict__ b3,
    float* __restrict__ z) {
    constexpr int K = 9 * CIN;
    constexpr int NT = K / 64;
    constexpr bool DUAL = (CIN == 512);
    constexpr int PST = DUAL ? 256 : CIN;
    extern __shared__ __align__(16) short lds[];   // 131072 B
    const int tid = threadIdx.x;
    int bx = blockIdx.x;
    bx = (bx & 7) * 64 + (bx >> 3);
    const int b = bx >> 6, y0 = (bx & 63) << 1;
    const short* inA = DUAL ? in_a : (blockIdx.z ? in_b : in_a);
    const short* inB = DUAL ? in_b : inA;
    short* out = (!DUAL && blockIdx.z) ? out_b : out_a;

    const int lane = tid & 63, wv = tid >> 6;
    const int wm = wv >> 2, wn = wv & 3;
    const int lr = lane & 15, lk = lane >> 4;

    const int rA = tid >> 3, cc = tid & 7;
    const int cs = cc ^ (rA & 7);
    const int pthrA0 = rA * PST + cs * 8;
    const int pthrA1 = (rA + 64) * PST + cs * 8;
    const int pthrB0 = rA * K + cs * 8;
    const int pthrB1 = (rA + 64) * K + cs * 8;
    const int dA0 = rA * 64 + cc * 8;
    const int dB0 = rA * 64 + cc * 8;

    const int arow = (wm * 128 + lr) * 64;
    const int brow = (wn * 64 + lr) * 64;
    const int cof0 = ((lk) ^ (lr & 7)) * 8;
    const int cof1 = ((4 + lk) ^ (lr & 7)) * 8;

    f32x4 acc[8][4];
    f32x4 zero = {0.f, 0.f, 0.f, 0.f};
    #pragma unroll
    for (int i = 0; i < 8; ++i)
        #pragma unroll
        for (int j = 0; j < 4; ++j) acc[i][j] = zero;

    auto STAGE2 = [&](int t2, int which, short* bufA, short* bufB) {
        const int cb = (t2 * 57) >> 9;
        const int tap = t2 - cb * 9;
        const int ch0v = cb << 6;
        const short* src = (!DUAL || ch0v < 256) ? inA : inB;
        const int ch0 = DUAL ? (ch0v & 255) : ch0v;
        const int ky = (tap * 11) >> 5;
        const int kx = tap - ky * 3;
        if (which == 0 || which == 2) {
            const int po = (which == 0) ? pthrA0 : pthrA1;
            const int doff = (which == 0) ? 0 : 64 * 64;
            const short* s0 = src + ((size_t)(b * HP + (y0 + ky)) * HP + kx) * PST + ch0;
            gload16(s0 + po, bufA + doff + dA0);
            gload16(s0 + (HP * PST) + po, bufA + 128 * 64 + doff + dA0);
        } else {
            const int h2 = (which == 1) ? 0 : 1;
            const short* sb = wp + (size_t)(h2 * 128) * K + t2 * 64;
            short* d = bufB + h2 * 128 * 64 + dB0;
            gload16(sb + pthrB0, d);
            gload16(sb + pthrB1, d + 64 * 64);
        }
    };

    auto LDA = [&](const short* bufA, int mh, bf16x8 (&a)[4][2]) {
        #pragma unroll
        for (int i = 0; i < 4; ++i) {
            const int ro = arow + (mh * 64 + i * 16) * 64;
            a[i][0] = *(const bf16x8*)(bufA + ro + cof0);
            a[i][1] = *(const bf16x8*)(bufA + ro + cof1);
        }
    };
    auto LDB = [&](const short* bufB, int nh, bf16x8 (&bb)[2][2]) {
        #pragma unroll
        for (int j = 0; j < 2; ++j) {
            const int ro = brow + (nh * 32 + j * 16) * 64;
            bb[j][0] = *(const bf16x8*)(bufB + ro + cof0);
            bb[j][1] = *(const bf16x8*)(bufB + ro + cof1);
        }
    };

#define PH_PRE4() do { __builtin_amdgcn_sched_barrier(0); \
                       __builtin_amdgcn_s_barrier(); \
                       asm volatile("s_waitcnt lgkmcnt(4)" ::: "memory"); \
                       __builtin_amdgcn_sched_barrier(0); \
                       __builtin_amdgcn_s_setprio(1); } while (0)
#define PH_PRE() do { __builtin_amdgcn_sched_barrier(0); \
                      __builtin_amdgcn_s_barrier(); \
                      asm volatile("s_waitcnt lgkmcnt(0)" ::: "memory"); \
                      __builtin_amdgcn_sched_barrier(0); \
                      __builtin_amdgcn_s_setprio(1); } while (0)
#define PH_POST() do { __builtin_amdgcn_s_setprio(0); \
                       __builtin_amdgcn_sched_barrier(0); \
                       __builtin_amdgcn_s_barrier(); } while (0)
#define MFMA_Q(A_, B_, MH, NH) do { \
    _Pragma("unroll") \
    for (int i_ = 0; i_ < 4; ++i_) { \
        _Pragma("unroll") \
        for (int j_ = 0; j_ < 2; ++j_) { \
            acc[(MH)*4+i_][(NH)*2+j_] = __builtin_amdgcn_mfma_f32_16x16x32_bf16( \
                A_[i_][0], B_[j_][0], acc[(MH)*4+i_][(NH)*2+j_], 0, 0, 0); \
            acc[(MH)*4+i_][(NH)*2+j_] = __builtin_amdgcn_mfma_f32_16x16x32_bf16( \
                A_[i_][1], B_[j_][1], acc[(MH)*4+i_][(NH)*2+j_], 0, 0, 0); \
        } \
    } } while (0)

    short* const A0 = lds;
    short* const A1 = lds + 16384;
    short* const B0 = lds + 32768;
    short* const B1 = lds + 49152;

    STAGE2(0, 0, A0, B0); STAGE2(0, 1, A0, B0);
    STAGE2(0, 2, A0, B0); STAGE2(0, 3, A0, B0);
    STAGE2(1, 0, A1, B1); STAGE2(1, 1, A1, B1);
    STAGE2(1, 2, A1, B1); STAGE2(1, 3, A1, B1);
    asm volatile("s_waitcnt vmcnt(8)" ::: "memory");
    __builtin_amdgcn_sched_barrier(0);
    __builtin_amdgcn_s_barrier();

    auto TILE = [&](int t, short* bufA, short* bufB) {
        const int t2 = t + 2;
        const bool st = (t2 < NT);
        bf16x8 ar[4][2], br0[2][2], br1[2][2];
        // phase 0 (mh=0, nh=0): issue A(mh0)+B(nh0)+B(nh1); wait first 12 only
        LDA(bufA, 0, ar);
        LDB(bufB, 0, br0);
        LDB(bufB, 1, br1);
        if (st) STAGE2(t2, 0, bufA, bufB);
        PH_PRE4();
        MFMA_Q(ar, br0, 0, 0);
        PH_POST();
        // phase 1 (mh=0, nh=1): no new reads; br1 already resident
        if (st) STAGE2(t2, 1, bufA, bufB);
        PH_PRE();
        MFMA_Q(ar, br1, 0, 1);
        PH_POST();
        // phase 2 (mh=1, nh=0)
        LDA(bufA, 1, ar);
        if (st) STAGE2(t2, 2, bufA, bufB);
        PH_PRE();
        MFMA_Q(ar, br0, 1, 0);
        PH_POST();
        // phase 3 (mh=1, nh=1)
        if (st) STAGE2(t2, 3, bufA, bufB);
        PH_PRE();
        MFMA_Q(ar, br1, 1, 1);
        __builtin_amdgcn_s_setprio(0);
        __builtin_amdgcn_sched_barrier(0);
        if (st)                asm volatile("s_waitcnt vmcnt(8)" ::: "memory");
        else if (t == NT - 2)  asm volatile("s_waitcnt vmcnt(0)" ::: "memory");
        __builtin_amdgcn_sched_barrier(0);
        __builtin_amdgcn_s_barrier();
    };

    for (int t = 0; t < NT; t += 2) {
        TILE(t,     A0, B0);
        TILE(t + 1, A1, B1);
    }
#undef PH_PRE4
#undef PH_PRE
#undef PH_POST
#undef MFMA_Q

    float bvs[4];
    #pragma unroll
    for (int nf = 0; nf < 4; ++nf) bvs[nf] = bias[wn * 64 + nf * 16 + lr];

    if constexpr (!FUSE) {
        // plain epilogue: bias+ReLU -> NHWC bf16, nf-innermost stores
        #pragma unroll
        for (int mf = 0; mf < 8; ++mf) {
            #pragma unroll
            for (int rr = 0; rr < 4; ++rr) {
                const int p = wm * 128 + mf * 16 + lk * 4 + rr;
                const int y = y0 + (p >> 7), x = p & 127;
                short* op;
                if (OPAD)
                    op = out + ((size_t)(b * HP + (y + 1)) * HP + (x + 1)) * CMID + wn * 64 + lr;
                else
                    op = out + ((size_t)((b * HN + y) * WN + x)) * CMID + wn * 64 + lr;
                #pragma unroll
                for (int nf = 0; nf < 4; ++nf)
                    op[nf * 16] = f2bf(fmaxf(acc[mf][nf][rr] + bvs[nf], 0.f));
            }
        }
    } else {
        // ---- MFMA 1x1(256->49) epilogue: logits -> z[pix][64] fp32 ----
        short* const Xh  = lds;                        // [128px][256ch] bf16 swz
        short* const W3s = lds + 32768;                // [64o][256ch] bf16 swz

        // stage w3p -> W3s (LDS linear dest, inverse-swizzled global source)
        #pragma unroll
        for (int sweep = 0; sweep < 4; ++sweep) {
            const int s = sweep * 512 + tid;
            const int o = s >> 5, c = s & 31;
            gload16(w3p + o * 256 + ((c ^ (o & 7)) << 3), W3s + s * 8);
        }

        const int oo = wn * 16 + lr;                    // this lane's output idx
        const float b3v = (oo < KO) ? b3[oo] : 0.f;

        #pragma unroll 1
        for (int r = 0; r < 2; ++r) {
            // 1) waves wm==r deposit their px-half as bf16 (bias+ReLU), swz
            if (wm == r) {
                #pragma unroll
                for (int nf = 0; nf < 4; ++nf) {
                    const int ch = wn * 64 + nf * 16 + lr;
                    const int ck = ch >> 3, el = ch & 7;
                    #pragma unroll
                    for (int mf = 0; mf < 8; ++mf) {
                        #pragma unroll
                        for (int rr = 0; rr < 4; ++rr) {
                            const int px = mf * 16 + lk * 4 + rr;
                            Xh[px * 256 + ((ck ^ (px & 7)) << 3) + el] =
                                f2bf(fmaxf(acc[mf][nf][rr] + bvs[nf], 0.f));
                        }
                    }
                }
            }
            __syncthreads();
            // 2) GEMM [128px x 256ch] x [64o x 256ch]^T, C init = b3
            f32x4 a2[4];
            #pragma unroll
            for (int m = 0; m < 4; ++m) {
                a2[m][0] = b3v; a2[m][1] = b3v; a2[m][2] = b3v; a2[m][3] = b3v;
            }
            #pragma unroll
            for (int ks = 0; ks < 8; ++ks) {
                const bf16x8 bfr =
                    *(const bf16x8*)&W3s[oo * 256 + (((ks * 4 + lk) ^ (oo & 7)) << 3)];
                #pragma unroll
                for (int m = 0; m < 4; ++m) {
                    const int px = wm * 64 + m * 16 + lr;
                    const bf16x8 afr =
                        *(const bf16x8*)&Xh[px * 256 + (((ks * 4 + lk) ^ (px & 7)) << 3)];
                    a2[m] = __builtin_amdgcn_mfma_f32_16x16x32_bf16(afr, bfr, a2[m], 0, 0, 0);
                }
            }
            // 3) D -> z (coalesced 64B runs: lr->oo consecutive)
            float* zp = z + ((size_t)(b * 16384 + (y0 + r) * 128)) * 64;
            #pragma unroll
            for (int m = 0; m < 4; ++m) {
                #pragma unroll
                for (int r2 = 0; r2 < 4; ++r2) {
                    const int px = wm * 64 + m * 16 + lk * 4 + r2;
                    zp[px * 64 + oo] = a2[m][r2];
                }
            }
            if (r == 0) __syncthreads();   // all Xh reads done before re-deposit
        }
    }
}

// ---------------------------------------------------------------------------
// Pad key_high NCHW fp32 -> bf16 [b][c][134][144] with zero halo.
// ---------------------------------------------------------------------------
__global__ __launch_bounds__(256) void pad_kh_kernel(
    const float* __restrict__ kh, short* __restrict__ khb) {
    const int bc = blockIdx.x;
    const float* src = kh + (size_t)bc * (HN * WN);
    short* dst = khb + (size_t)bc * KHB_PLANE;
    for (int i = threadIdx.x; i < KHB_H * (KHB_W / 8); i += 256) {
        int yy = i / (KHB_W / 8);
        int g = i - yy * (KHB_W / 8);
        int ys = yy - 3;
        bf16x8 v;
        #pragma unroll
        for (int t = 0; t < 8; ++t) {
            int xs = g * 8 + t - 4;
            float f = 0.f;
            if ((unsigned)ys < 128u && (unsigned)xs < 128u) f = src[(ys << 7) + xs];
            v[t] = f2bf(f);
        }
        *(bf16x8*)&dst[yy * KHB_W + g * 8] = v;
    }
}

// ---------------------------------------------------------------------------
// SVC v4: fused softmax (from z logits) + spatially-variant conv.
// Softmax: 4 lanes per pixel, each handles 16 of 64 o-slots (o>=49 masked
// to -1e30), shfl_xor(1,2) reduce for max/sum, normalized weights written
// to a_s[o][px]. All arrays statically indexed. Rest identical to svc3.
// ---------------------------------------------------------------------------
__global__ __launch_bounds__(256) void svc4_kernel(
    const float* __restrict__ z, const short* __restrict__ khb,
    float* __restrict__ out) {
    __shared__ float a_s[KO * 64];
    const int tid = threadIdx.x;
    int by = blockIdx.y;
    by = (by & 7) * 128 + (by >> 3);
    const int b = by >> 7, y = by & 127;
    const int x0 = blockIdx.x * 64;

    {
        const int px = tid >> 2, l = tid & 3;
        const float* zp = z + ((size_t)(b * 16384 + (y << 7) + x0 + px)) * 64 + l * 16;
        float v[16];
        #pragma unroll
        for (int q = 0; q < 4; ++q) {
            f32x4 t4 = *(const f32x4*)&zp[q * 4];
            v[q * 4 + 0] = fmaxf(t4[0], 0.f);
            v[q * 4 + 1] = fmaxf(t4[1], 0.f);
            v[q * 4 + 2] = fmaxf(t4[2], 0.f);
            v[q * 4 + 3] = fmaxf(t4[3], 0.f);
        }
        // mask invalid o (l==3 has only o=48 valid)
        #pragma unroll
        for (int j = 1; j < 16; ++j) if (l == 3) v[j] = -1e30f;
        float m = v[0];
        #pragma unroll
        for (int j = 1; j < 16; ++j) m = fmaxf(m, v[j]);
        m = fmaxf(m, __shfl_xor(m, 1, 64));
        m = fmaxf(m, __shfl_xor(m, 2, 64));
        float s = 0.f;
        #pragma unroll
        for (int j = 0; j < 16; ++j) { v[j] = __expf(v[j] - m); s += v[j]; }
        s += __shfl_xor(s, 1, 64);
        s += __shfl_xor(s, 2, 64);
        const float inv = 1.f / s;
        #pragma unroll
        for (int j = 0; j < 16; ++j) {
            const int o = l * 16 + j;
            if (o < KO) a_s[o * 64 + px] = v[j] * inv;
        }
    }
    __syncthreads();

    const int ci = tid >> 3;
    const int pg = tid & 7;
    const int p0 = x0 + pg * 8;

    float acc[8][8];
    #pragma unroll
    for (int c = 0; c < 8; ++c)
        #pragma unroll
        for (int j = 0; j < 8; ++j) acc[c][j] = 0.f;

    const short* kbase = khb + (((size_t)b * 256 + ci) * KHB_H + y) * KHB_W + p0;

    #pragma unroll 1
    for (int dy = 0; dy < 7; ++dy) {
        f32x4 av[14];
        #pragma unroll
        for (int dx = 0; dx < 7; ++dx) {
            av[dx * 2]     = *(const f32x4*)&a_s[(dy * 7 + dx) * 64 + pg * 8];
            av[dx * 2 + 1] = *(const f32x4*)&a_s[(dy * 7 + dx) * 64 + pg * 8 + 4];
        }
        const short* krow = kbase + dy * KHB_W;
        #pragma unroll
        for (int c = 0; c < 8; ++c) {
            const short* kp = krow + (size_t)c * 32 * KHB_PLANE;
            bf16x8 k0 = *(const bf16x8*)(kp);
            bf16x8 k1 = *(const bf16x8*)(kp + 8);
            float win[16];
            #pragma unroll
            for (int t = 0; t < 8; ++t) { win[t] = bf2f(k0[t]); win[t + 8] = bf2f(k1[t]); }
            #pragma unroll
            for (int dx = 0; dx < 7; ++dx) {
                #pragma unroll
                for (int j = 0; j < 8; ++j)
                    acc[c][j] = fmaf(win[j + dx + 1], av[dx * 2 + (j >> 2)][j & 3],
                                     acc[c][j]);
            }
        }
    }

    #pragma unroll
    for (int c = 0; c < 8; ++c) {
        float* op = out + (((size_t)b * 256 + ci + c * 32) << 14) + (y << 7) + p0;
        f32x4 r0 = {acc[c][0], acc[c][1], acc[c][2], acc[c][3]};
        f32x4 r1 = {acc[c][4], acc[c][5], acc[c][6], acc[c][7]};
        *(f32x4*)op = r0;
        *(f32x4*)(op + 4) = r1;
    }
}

// ---------------------------------------------------------------------------
extern "C" void kernel_launch(void* const* d_in, const int* in_sizes, int n_in,
                              void* d_out, int out_size, void* d_ws, size_t ws_size,
                              hipStream_t stream) {
    (void)in_sizes; (void)n_in; (void)out_size; (void)ws_size;
    const float* cur_low  = (const float*)d_in[0];
    const float* key_low  = (const float*)d_in[1];
    const float* key_high = (const float*)d_in[2];
    const float* w_red    = (const float*)d_in[3];
    const float* b_red    = (const float*)d_in[4];
    const float* w2       = (const float*)d_in[5];
    const float* b2       = (const float*)d_in[6];
    const float* w3       = (const float*)d_in[7];
    const float* b3       = (const float*)d_in[8];
    float* out = (float*)d_out;
    char* ws = (char*)d_ws;

    // Workspace (lifetime-overlapped, ~211 MB):
    //   xpadc @ 0, xpadk @ 34.6M        (convert -> conv1)
    //   ypadc @ 69.2M, ypadk @ 138.4M   (conv1 -> conv2)
    //   weights @ 207.7M
    //   z   @ 0      (33.6M; conv2f -> svc4; overlays dead xpads)
    //   khb @ 69.2M  (79.0M; pad_kh -> svc4; overlays dead ypadc)
    const size_t SZ_XPAD = (size_t)BN * HP * HP * CLOW * 2;
    const size_t SZ_YPAD = (size_t)BN * HP * HP * CMID * 2;
    short* xpadc = (short*)(ws);
    short* xpadk = (short*)(ws + SZ_XPAD);
    short* ypadc = (short*)(ws + 2 * SZ_XPAD);
    short* ypadk = (short*)(ws + 2 * SZ_XPAD + SZ_YPAD);
    short* w1p   = (short*)(ws + 2 * SZ_XPAD + 2 * SZ_YPAD);
    short* w2p   = w1p + (size_t)256 * 1152;
    float* z     = (float*)(ws);
    short* khb   = (short*)(ws + 2 * SZ_XPAD);
    // w3p (32 KB) in the d_out tail: written by pack, read by conv2f,
    // then fully overwritten by svc4's output. Deterministic each call.
    short* w3p   = (short*)((char*)d_out + (size_t)134217728 - 32768);

    hipFuncSetAttribute((const void*)conv_8ph_kernel<128, true, false>,
                        hipFuncAttributeMaxDynamicSharedMemorySize, 131072);
    hipFuncSetAttribute((const void*)conv_8ph_kernel<512, false, true>,
                        hipFuncAttributeMaxDynamicSharedMemorySize, 131072);

    zero_border_all_kernel<<<dim3(516, 4), 256, 0, stream>>>(xpadc, xpadk, ypadc, ypadk);
    convert_pad_kernel<<<dim3(1024, 2), 256, 0, stream>>>(cur_low, key_low, xpadc, xpadk);
    pack_w_all_kernel<<<(256 * (1152 + 4608) + 64 * 256 + 255) / 256, 256, 0, stream>>>(
        w_red, w1p, w2, w2p, w3, w3p);

    conv_8ph_kernel<128, true, false><<<dim3(512, 1, 2), 512, 131072, stream>>>(
        xpadc, xpadk, w1p, b_red, ypadc, ypadk, nullptr, nullptr, nullptr);

    conv_8ph_kernel<512, false, true><<<dim3(512, 1, 1), 512, 131072, stream>>>(
        ypadc, ypadk, w2p, b2, nullptr, nullptr, w3p, b3, z);

    pad_kh_kernel<<<2048, 256, 0, stream>>>(key_high, khb);
    svc4_kernel<<<dim3(2, 1024), 256, 0, stream>>>(z, khb, out);
}